// Round 2
// baseline (4126.595 us; speedup 1.0000x reference)
//
#include <hip/hip_runtime.h>
#include <stdint.h>

#define TPB 128

__device__ __forceinline__ float sigf(float x){
  return __builtin_amdgcn_rcpf(1.0f + __expf(-x));
}
__device__ __forceinline__ float tanh_f(float x){
  return 1.0f - 2.0f*__builtin_amdgcn_rcpf(1.0f + __expf(2.0f*x));
}

// ---------------- CSR build ----------------
__global__ void k_deg(const int* __restrict__ dst, int* __restrict__ deg, int E){
  int i = blockIdx.x*256 + threadIdx.x;
  if (i < E) atomicAdd(&deg[dst[i]], 1);
}

__global__ __launch_bounds__(256) void k_scan1(const int* __restrict__ deg, int* __restrict__ indptr,
                                               int* __restrict__ bsum, int N){
  __shared__ int s[256];
  int tid = threadIdx.x;
  int i = blockIdx.x*256 + tid;
  int v = (i < N) ? deg[i] : 0;
  s[tid] = v; __syncthreads();
  for (int off=1; off<256; off<<=1){
    int t = (tid>=off) ? s[tid-off] : 0;
    __syncthreads();
    s[tid] += t;
    __syncthreads();
  }
  if (i < N) indptr[i] = s[tid] - v;      // block-local exclusive
  if (tid == 255) bsum[blockIdx.x] = s[255];
}

__global__ __launch_bounds__(512) void k_scan2(const int* __restrict__ bsum, int* __restrict__ boffs,
                                               int* __restrict__ indptr, int nb, int N){
  __shared__ int s[512];
  int tid = threadIdx.x;
  int v = (tid < nb) ? bsum[tid] : 0;
  s[tid] = v; __syncthreads();
  for (int off=1; off<512; off<<=1){
    int t = (tid>=off) ? s[tid-off] : 0;
    __syncthreads();
    s[tid] += t;
    __syncthreads();
  }
  boffs[tid] = s[tid] - v;
  if (tid == nb-1) indptr[N] = s[tid];
}

__global__ __launch_bounds__(256) void k_scan3(int* __restrict__ indptr, const int* __restrict__ boffs, int N){
  int i = blockIdx.x*256 + threadIdx.x;
  if (i < N) indptr[i] += boffs[blockIdx.x];
}

__global__ void k_fill(const int* __restrict__ src, const int* __restrict__ dst,
                       const int* __restrict__ indptr, int* __restrict__ fill,
                       int* __restrict__ col, int E){
  int i = blockIdx.x*256 + threadIdx.x;
  if (i < E){
    int d = dst[i];
    int r = atomicAdd(&fill[d], 1);
    col[indptr[d] + r] = src[i];
  }
}

// ---------------- aggregation: z[n] = h[n] + sum_{neighbors} h[src] ----------------
template<int F>
__global__ __launch_bounds__(256) void k_agg(const float* __restrict__ h, const int* __restrict__ indptr,
                                             const int* __restrict__ col, float* __restrict__ z, int N){
  constexpr int TPN = F/4;          // threads per node
  constexpr int NPB = 256/TPN;      // nodes per block
  int n = blockIdx.x*NPB + threadIdx.x/TPN;
  int lane = threadIdx.x % TPN;
  if (n >= N) return;
  const float4* hv = (const float4*)h;
  float4 acc = hv[(size_t)n*TPN + lane];
  int s = indptr[n], e = indptr[n+1];
  for (int p = s; p < e; ++p){
    int c = col[p];
    float4 x = hv[(size_t)c*TPN + lane];
    acc.x += x.x; acc.y += x.y; acc.z += x.z; acc.w += x.w;
  }
  ((float4*)z)[(size_t)n*TPN + lane] = acc;
}

// ---------------- generic f32 GEMM: out[n][j] = act(sum_k A[n][k]*W[j][k] + b[j]) ----------------
__global__ __launch_bounds__(TPB) void k_gemm(const float* __restrict__ A, const float* __restrict__ W,
                                              const float* __restrict__ bias, float* __restrict__ out,
                                              int K, int JC, int act, int N){
  extern __shared__ float sm[];
  float* As = sm;                       // [K][68]
  float* Ws = sm + (size_t)K*68;        // [K][34]
  const int tid = threadIdx.x;
  const int tx = tid & 15, ty = tid >> 4;
  const int nb = blockIdx.x * 64;
  const int kq = K >> 2;
  for (int it = 0, idx = tid; it < (kq >> 1); ++it, idx += TPB){
    int nl = idx & 63, kk = idx >> 6;
    int k4 = kk << 2;
    int n = nb + nl;
    float4 v = make_float4(0.f,0.f,0.f,0.f);
    if (n < N) v = *(const float4*)(A + (size_t)n*K + k4);
    As[(size_t)(k4+0)*68 + nl] = v.x;
    As[(size_t)(k4+1)*68 + nl] = v.y;
    As[(size_t)(k4+2)*68 + nl] = v.z;
    As[(size_t)(k4+3)*68 + nl] = v.w;
  }
  const int ncc = JC >> 5;
  for (int cc = 0; cc < ncc; ++cc){
    __syncthreads();
    for (int it = 0, idx = tid; it < (kq >> 2); ++it, idx += TPB){
      int cl = idx & 31, kk = idx >> 5;
      int k4 = kk << 2;
      int j = (cc << 5) + cl;
      float4 v = *(const float4*)(W + (size_t)j*K + k4);
      Ws[(size_t)(k4+0)*34 + cl] = v.x;
      Ws[(size_t)(k4+1)*34 + cl] = v.y;
      Ws[(size_t)(k4+2)*34 + cl] = v.z;
      Ws[(size_t)(k4+3)*34 + cl] = v.w;
    }
    __syncthreads();
    float4 acc0 = make_float4(0,0,0,0), acc1 = acc0, acc2 = acc0, acc3 = acc0;
    #pragma unroll 4
    for (int k = 0; k < K; ++k){
      float4 a = *(const float4*)(As + (size_t)k*68 + (tx<<2));
      float2 w01 = *(const float2*)(Ws + (size_t)k*34 + (ty<<2));
      float2 w23 = *(const float2*)(Ws + (size_t)k*34 + (ty<<2) + 2);
      acc0.x = fmaf(a.x, w01.x, acc0.x); acc0.y = fmaf(a.x, w01.y, acc0.y);
      acc0.z = fmaf(a.x, w23.x, acc0.z); acc0.w = fmaf(a.x, w23.y, acc0.w);
      acc1.x = fmaf(a.y, w01.x, acc1.x); acc1.y = fmaf(a.y, w01.y, acc1.y);
      acc1.z = fmaf(a.y, w23.x, acc1.z); acc1.w = fmaf(a.y, w23.y, acc1.w);
      acc2.x = fmaf(a.z, w01.x, acc2.x); acc2.y = fmaf(a.z, w01.y, acc2.y);
      acc2.z = fmaf(a.z, w23.x, acc2.z); acc2.w = fmaf(a.z, w23.y, acc2.w);
      acc3.x = fmaf(a.w, w01.x, acc3.x); acc3.y = fmaf(a.w, w01.y, acc3.y);
      acc3.z = fmaf(a.w, w23.x, acc3.z); acc3.w = fmaf(a.w, w23.y, acc3.w);
    }
    int j0 = (cc << 5) + (ty << 2);
    float4 b4 = make_float4(0,0,0,0);
    if (bias) b4 = *(const float4*)(bias + j0);
    float4 r[4] = {acc0, acc1, acc2, acc3};
    #pragma unroll
    for (int i = 0; i < 4; ++i){
      int n = nb + (tx<<2) + i;
      if (n < N){
        float4 o;
        o.x = r[i].x + b4.x; o.y = r[i].y + b4.y; o.z = r[i].z + b4.z; o.w = r[i].w + b4.w;
        if (act){
          o.x = fmaxf(o.x, 0.f); o.y = fmaxf(o.y, 0.f);
          o.z = fmaxf(o.z, 0.f); o.w = fmaxf(o.w, 0.f);
        }
        *(float4*)(out + (size_t)n*JC + j0) = o;
      }
    }
  }
}

// ---------------- LSTM weight/bias prepack ----------------
// Wp[(j*4+g)*160 + k] = k<64 ? Wih[(g*96+j)*64+k] : Whh[(g*96+j)*96+k-64]
__global__ __launch_bounds__(256) void k_packW(const float* __restrict__ Wih, const float* __restrict__ Whh,
                                               float* __restrict__ Wp){
  int idx = blockIdx.x*256 + threadIdx.x;
  if (idx >= 384*160) return;
  int R = idx/160, kk = idx - R*160;
  int j = R>>2, g = R&3;
  int row = g*96 + j;
  float v = (kk<64) ? Wih[row*64+kk] : Whh[row*96 + (kk-64)];
  Wp[idx] = v;
}

__global__ __launch_bounds__(128) void k_packB(const float* __restrict__ bih, const float* __restrict__ bhh,
                                               float4* __restrict__ Bp){
  int j = blockIdx.x*128 + threadIdx.x;
  if (j >= 96) return;
  Bp[j] = make_float4(bih[j]+bhh[j], bih[96+j]+bhh[96+j],
                      bih[192+j]+bhh[192+j], bih[288+j]+bhh[288+j]);
}

// ---------------- fused LSTM step, SGPR-streamed weights ----------------
// 256 thr = 4 waves = 2 pairs x (2 K-half waves). Each wave-pair owns 64 nodes.
// ph=0 wave: k in [0,KH) ; ph=1 wave: k in [KH,2*KH). Weights via uniform s_loads.
// Partial gate sums exchanged through 8KB double-buffered LDS, 1 barrier/chunk.
// h,c stored transposed [96][N] for coalesced epilogue access.
template<int FIRST>
__global__ __launch_bounds__(256,4) void k_lstm2(const float* __restrict__ seq,
                                                 float* __restrict__ hbuf, float* __restrict__ cbuf,
                                                 const float* __restrict__ Wp, const float4* __restrict__ Bp,
                                                 const float* __restrict__ Watt, const float* __restrict__ batt,
                                                 float* __restrict__ alphaT, int initA, int woff, int N){
  constexpr int KH = FIRST ? 32 : 80;
  __shared__ float sEx[2][2][8][64];
  __shared__ float sAl[2][2][64];
  const int tid  = threadIdx.x;
  const int lane = tid & 63;
  const int wave = tid >> 6;
  const int pair = wave >> 1;
  const int ph   = wave & 1;
  const int phs  = __builtin_amdgcn_readfirstlane(ph);
  const int n = blockIdx.x*128 + pair*64 + lane;
  const bool ok = n < N;

  float x[KH];
  if (ok){
    if (FIRST){
      const float4* s4 = (const float4*)(seq + (size_t)n*64 + ph*32);
      #pragma unroll
      for (int i=0;i<8;++i){
        float4 v = s4[i];
        x[i*4+0]=v.x; x[i*4+1]=v.y; x[i*4+2]=v.z; x[i*4+3]=v.w;
      }
    } else {
      if (ph == 0){
        const float4* s4 = (const float4*)(seq + (size_t)n*64);
        #pragma unroll
        for (int i=0;i<16;++i){
          float4 v = s4[i];
          x[i*4+0]=v.x; x[i*4+1]=v.y; x[i*4+2]=v.z; x[i*4+3]=v.w;
        }
        #pragma unroll
        for (int j=0;j<16;++j) x[64+j] = hbuf[(size_t)j*N + n];
      } else {
        #pragma unroll
        for (int j=0;j<80;++j) x[j] = hbuf[(size_t)(16+j)*N + n];
      }
    }
  } else {
    #pragma unroll
    for (int k=0;k<KH;++k) x[k] = 0.f;
  }

  float aAcc = 0.f;
  const float wb0 = batt[0];
  for (int jc = 0; jc < 24; ++jc){
    const float* wr = Wp + (size_t)(jc*16)*160 + phs*KH;
    float acc[16];
    #pragma unroll
    for (int r=0;r<16;++r) acc[r]=0.f;
    // k-blocked: contiguous 16-wide weight runs (s_load_dwordx16) + 16 parallel chains
    #pragma unroll
    for (int kb=0; kb<KH; kb+=16){
      #pragma unroll
      for (int r=0;r<16;++r){
        #pragma unroll
        for (int k=0;k<16;++k)
          acc[r] = fmaf(x[kb+k], wr[r*160 + kb + k], acc[r]);
      }
    }
    const int buf = jc & 1;
    #pragma unroll
    for (int jj=0;jj<2;++jj){
      const int jlw = (ph^1)*2 + jj;       // rows our partner will epilogue
      #pragma unroll
      for (int g=0; g<4; ++g)
        sEx[buf][pair][jj*4+g][lane] = acc[jlw*4+g];
    }
    __syncthreads();
    #pragma unroll
    for (int jj=0;jj<2;++jj){
      const int j = jc*4 + ph*2 + jj;
      const int rb = (ph*2+jj)*4;
      float4 b = Bp[j];
      float gi = acc[rb+0] + sEx[buf][pair][jj*4+0][lane] + b.x;
      float gf = acc[rb+1] + sEx[buf][pair][jj*4+1][lane] + b.y;
      float gg = acc[rb+2] + sEx[buf][pair][jj*4+2][lane] + b.z;
      float go = acc[rb+3] + sEx[buf][pair][jj*4+3][lane] + b.w;
      float cp = (FIRST || !ok) ? 0.f : cbuf[(size_t)j*N + n];
      float c  = sigf(gf)*cp + sigf(gi)*tanh_f(gg);
      float h  = sigf(go)*tanh_f(c);
      if (ok){
        cbuf[(size_t)j*N + n] = c;
        hbuf[(size_t)j*N + n] = h;
      }
      aAcc = fmaf(h, Watt[woff + j], aAcc);
    }
  }
  sAl[pair][ph][lane] = aAcc;
  __syncthreads();
  if (ph == 0 && ok){
    float s = aAcc + sAl[pair][1][lane];
    if (initA) alphaT[n] = wb0 + s;
    else       alphaT[n] += s;
  }
}

// ---------------- JK softmax + xjk + Wlin + Wfc1 + leaky ----------------
__global__ __launch_bounds__(256) void k_jk(const float* __restrict__ alpha,
                                            const float* __restrict__ h1, const float* __restrict__ h2,
                                            const float* __restrict__ h3,
                                            const float* __restrict__ Wlin, const float* __restrict__ blin,
                                            const float* __restrict__ Wfc1, const float* __restrict__ bfc1,
                                            float* __restrict__ vout, int N){
  __shared__ float sWl[64*65];
  __shared__ float sX[4][64];
  __shared__ float sR[4][64];
  int tid = threadIdx.x;
  for (int idx = tid; idx < 1024; idx += 256){
    int j = idx >> 4;
    int c4 = (idx & 15) << 2;
    float4 v = *(const float4*)(Wlin + (size_t)j*64 + c4);
    sWl[j*65 + c4+0] = v.x; sWl[j*65 + c4+1] = v.y;
    sWl[j*65 + c4+2] = v.z; sWl[j*65 + c4+3] = v.w;
  }
  int ln = tid >> 6, j = tid & 63;
  int n = blockIdx.x*4 + ln;
  bool ok = n < N;
  float xj = 0.f;
  if (ok){
    float a0 = alpha[n], a1 = alpha[(size_t)N + n], a2 = alpha[(size_t)2*N + n];
    float m = fmaxf(a0, fmaxf(a1, a2));
    float e0 = __expf(a0-m), e1 = __expf(a1-m), e2 = __expf(a2-m);
    float inv = __builtin_amdgcn_rcpf(e0+e1+e2);
    float w0 = e0*inv, w1 = e1*inv, w2 = e2*inv;
    xj = w0*h1[(size_t)n*64 + j] + w1*h2[(size_t)n*64 + j] + w2*h3[(size_t)n*64 + j];
  }
  sX[ln][j] = xj;
  __syncthreads();
  float acc = blin[j];
  #pragma unroll 8
  for (int c = 0; c < 64; ++c) acc = fmaf(sX[ln][c], sWl[j*65 + c], acc);
  sR[ln][j] = acc * Wfc1[j];
  __syncthreads();
  #pragma unroll
  for (int off = 32; off > 0; off >>= 1){
    if (j < off) sR[ln][j] += sR[ln][j + off];
    __syncthreads();
  }
  if (j == 0 && ok){
    float vv = sR[ln][0] + bfc1[0];
    vout[n] = vv >= 0.f ? vv : 0.01f*vv;
  }
}

// ---------------- final dot (deterministic two-stage, f64 accum) ----------------
__global__ __launch_bounds__(256) void k_final1(const float* __restrict__ w, const float* __restrict__ v,
                                                double* __restrict__ part, int N){
  __shared__ double sd[256];
  int tid = threadIdx.x;
  double a = 0.0;
  for (int i = blockIdx.x*256 + tid; i < N; i += 256*256)
    a += (double)(w[i] * v[i]);
  sd[tid] = a; __syncthreads();
  for (int off = 128; off > 0; off >>= 1){
    if (tid < off) sd[tid] += sd[tid + off];
    __syncthreads();
  }
  if (tid == 0) part[blockIdx.x] = sd[0];
}

__global__ __launch_bounds__(256) void k_final2(const double* __restrict__ part, const float* __restrict__ bfc2,
                                                float* __restrict__ out){
  __shared__ double sd[256];
  int tid = threadIdx.x;
  sd[tid] = part[tid]; __syncthreads();
  for (int off = 128; off > 0; off >>= 1){
    if (tid < off) sd[tid] += sd[tid + off];
    __syncthreads();
  }
  if (tid == 0) out[0] = (float)(sd[0] + (double)bfc2[0]);
}

// ---------------- host ----------------
extern "C" void kernel_launch(void* const* d_in, const int* in_sizes, int n_in,
                              void* d_out, int out_size, void* d_ws, size_t ws_size,
                              hipStream_t stream){
  const float* x    = (const float*)d_in[0];
  const int*   ei   = (const int*)d_in[1];
  const float* W0a  = (const float*)d_in[2];
  const float* b0a  = (const float*)d_in[3];
  const float* W0b  = (const float*)d_in[4];
  const float* b0b  = (const float*)d_in[5];
  const float* W1a  = (const float*)d_in[6];
  const float* b1a  = (const float*)d_in[7];
  const float* W1b  = (const float*)d_in[8];
  const float* b1b  = (const float*)d_in[9];
  const float* W2a  = (const float*)d_in[10];
  const float* b2a  = (const float*)d_in[11];
  const float* W2b  = (const float*)d_in[12];
  const float* b2b  = (const float*)d_in[13];
  const float* Wih_f = (const float*)d_in[14];
  const float* Whh_f = (const float*)d_in[15];
  const float* bih_f = (const float*)d_in[16];
  const float* bhh_f = (const float*)d_in[17];
  const float* Wih_b = (const float*)d_in[18];
  const float* Whh_b = (const float*)d_in[19];
  const float* bih_b = (const float*)d_in[20];
  const float* bhh_b = (const float*)d_in[21];
  const float* Watt = (const float*)d_in[22];
  const float* batt = (const float*)d_in[23];
  const float* Wlin = (const float*)d_in[24];
  const float* blin = (const float*)d_in[25];
  const float* Wfc1 = (const float*)d_in[26];
  const float* bfc1 = (const float*)d_in[27];
  const float* Wfc2 = (const float*)d_in[28];
  const float* bfc2 = (const float*)d_in[29];
  float* out = (float*)d_out;

  const int N = in_sizes[0] / 128;
  const int E = in_sizes[1] / 2;
  const int* src = ei;
  const int* dst = ei + E;

  uint8_t* w8 = (uint8_t*)d_ws;
  size_t off = 0;
  auto alloc = [&](size_t bytes) -> void* {
    void* p = w8 + off;
    off = (off + bytes + 255) & ~(size_t)255;
    return p;
  };
  int*    deg    = (int*)   alloc((size_t)N*4);
  int*    fill   = (int*)   alloc((size_t)N*4);
  int*    indptr = (int*)   alloc(((size_t)N+1)*4);
  int*    col    = (int*)   alloc((size_t)E*4);
  int*    bsum   = (int*)   alloc(2048);
  int*    boffs  = (int*)   alloc(2048);
  float*  h1     = (float*) alloc((size_t)N*64*4);
  float*  h2     = (float*) alloc((size_t)N*64*4);
  float*  h3     = (float*) alloc((size_t)N*64*4);
  float*  alpha  = (float*) alloc((size_t)3*N*4);
  float*  vbuf   = (float*) alloc((size_t)N*4);
  double* part   = (double*)alloc(256*8);
  float*  Wpf    = (float*) alloc((size_t)384*160*4);
  float*  Wpb    = (float*) alloc((size_t)384*160*4);
  float4* Bpf    = (float4*)alloc((size_t)96*16);
  float4* Bpb    = (float4*)alloc((size_t)96*16);
  float*  P      = (float*) alloc((size_t)N*192*4);   // phase-shared region
  if (off > ws_size) return;
  float* zbuf = P;                      // GIN phase: z tile [N,128]
  float* mid  = P + (size_t)N*128;      // GIN phase: MLP intermediate [N,64]
  float* hb   = P;                      // LSTM phase: h transposed [96][N]
  float* cb   = P + (size_t)N*96;       // LSTM phase: c transposed [96][N]

  const size_t lds64  = 64  * 102 * 4;
  const size_t lds128 = 128 * 102 * 4;

  hipMemsetAsync(deg,  0, (size_t)N*4, stream);
  hipMemsetAsync(fill, 0, (size_t)N*4, stream);

  int gE = (E + 255) / 256;
  int nb1 = (N + 255) / 256;
  int gG = (N + 63) / 64;
  int gL = (N + 127) / 128;

  // weight prepack (independent of CSR)
  k_packW<<<240, 256, 0, stream>>>(Wih_f, Whh_f, Wpf);
  k_packW<<<240, 256, 0, stream>>>(Wih_b, Whh_b, Wpb);
  k_packB<<<1, 128, 0, stream>>>(bih_f, bhh_f, Bpf);
  k_packB<<<1, 128, 0, stream>>>(bih_b, bhh_b, Bpb);

  k_deg  <<<gE, 256, 0, stream>>>(dst, deg, E);
  k_scan1<<<nb1, 256, 0, stream>>>(deg, indptr, bsum, N);
  k_scan2<<<1, 512, 0, stream>>>(bsum, boffs, indptr, nb1, N);
  k_scan3<<<nb1, 256, 0, stream>>>(indptr, boffs, N);
  k_fill <<<gE, 256, 0, stream>>>(src, dst, indptr, fill, col, E);

  // ---- GIN layer 0 (F=128) ----
  k_agg<128><<<(N+7)/8, 256, 0, stream>>>(x, indptr, col, zbuf, N);
  k_gemm<<<gG, TPB, lds128, stream>>>(zbuf, W0a, b0a, mid, 128, 64, 1, N);
  k_gemm<<<gG, TPB, lds64,  stream>>>(mid,  W0b, b0b, h1,  64,  64, 1, N);
  // ---- GIN layer 1 ----
  k_agg<64><<<(N+15)/16, 256, 0, stream>>>(h1, indptr, col, zbuf, N);
  k_gemm<<<gG, TPB, lds64, stream>>>(zbuf, W1a, b1a, mid, 64, 64, 1, N);
  k_gemm<<<gG, TPB, lds64, stream>>>(mid,  W1b, b1b, h2,  64, 64, 1, N);
  // ---- GIN layer 2 ----
  k_agg<64><<<(N+15)/16, 256, 0, stream>>>(h2, indptr, col, zbuf, N);
  k_gemm<<<gG, TPB, lds64, stream>>>(zbuf, W2a, b2a, mid, 64, 64, 1, N);
  k_gemm<<<gG, TPB, lds64, stream>>>(mid,  W2b, b2b, h3,  64, 64, 1, N);

  // ---- LSTM forward (t = 0,1,2): each forward step initializes its alpha slice ----
  k_lstm2<1><<<gL, 256, 0, stream>>>(h1, hb, cb, Wpf, Bpf, Watt, batt, alpha,              1, 0, N);
  k_lstm2<0><<<gL, 256, 0, stream>>>(h2, hb, cb, Wpf, Bpf, Watt, batt, alpha + (size_t)N,  1, 0, N);
  k_lstm2<0><<<gL, 256, 0, stream>>>(h3, hb, cb, Wpf, Bpf, Watt, batt, alpha + (size_t)2*N,1, 0, N);
  // ---- LSTM backward (t = 2,1,0): accumulate ----
  k_lstm2<1><<<gL, 256, 0, stream>>>(h3, hb, cb, Wpb, Bpb, Watt, batt, alpha + (size_t)2*N,0, 96, N);
  k_lstm2<0><<<gL, 256, 0, stream>>>(h2, hb, cb, Wpb, Bpb, Watt, batt, alpha + (size_t)N,  0, 96, N);
  k_lstm2<0><<<gL, 256, 0, stream>>>(h1, hb, cb, Wpb, Bpb, Watt, batt, alpha,              0, 96, N);

  // ---- JK attention + linear + fc1 + leaky ----
  k_jk<<<(N+3)/4, 256, 0, stream>>>(alpha, h1, h2, h3, Wlin, blin, Wfc1, bfc1, vbuf, N);

  // ---- final dot ----
  k_final1<<<256, 256, 0, stream>>>(Wfc2, vbuf, part, N);
  k_final2<<<1, 256, 0, stream>>>(part, bfc2, out);
}

// Round 3
// 2190.483 us; speedup vs baseline: 1.8839x; 1.8839x over previous
//
#include <hip/hip_runtime.h>
#include <stdint.h>

#define TPB 128

__device__ __forceinline__ float sigf(float x){
  return __builtin_amdgcn_rcpf(1.0f + __expf(-x));
}
__device__ __forceinline__ float tanh_f(float x){
  return 1.0f - 2.0f*__builtin_amdgcn_rcpf(1.0f + __expf(2.0f*x));
}

// ---------------- CSR build ----------------
__global__ void k_deg(const int* __restrict__ dst, int* __restrict__ deg, int E){
  int i = blockIdx.x*256 + threadIdx.x;
  if (i < E) atomicAdd(&deg[dst[i]], 1);
}

__global__ __launch_bounds__(256) void k_scan1(const int* __restrict__ deg, int* __restrict__ indptr,
                                               int* __restrict__ bsum, int N){
  __shared__ int s[256];
  int tid = threadIdx.x;
  int i = blockIdx.x*256 + tid;
  int v = (i < N) ? deg[i] : 0;
  s[tid] = v; __syncthreads();
  for (int off=1; off<256; off<<=1){
    int t = (tid>=off) ? s[tid-off] : 0;
    __syncthreads();
    s[tid] += t;
    __syncthreads();
  }
  if (i < N) indptr[i] = s[tid] - v;      // block-local exclusive
  if (tid == 255) bsum[blockIdx.x] = s[255];
}

__global__ __launch_bounds__(512) void k_scan2(const int* __restrict__ bsum, int* __restrict__ boffs,
                                               int* __restrict__ indptr, int nb, int N){
  __shared__ int s[512];
  int tid = threadIdx.x;
  int v = (tid < nb) ? bsum[tid] : 0;
  s[tid] = v; __syncthreads();
  for (int off=1; off<512; off<<=1){
    int t = (tid>=off) ? s[tid-off] : 0;
    __syncthreads();
    s[tid] += t;
    __syncthreads();
  }
  boffs[tid] = s[tid] - v;
  if (tid == nb-1) indptr[N] = s[tid];
}

__global__ __launch_bounds__(256) void k_scan3(int* __restrict__ indptr, const int* __restrict__ boffs, int N){
  int i = blockIdx.x*256 + threadIdx.x;
  if (i < N) indptr[i] += boffs[blockIdx.x];
}

__global__ void k_fill(const int* __restrict__ src, const int* __restrict__ dst,
                       const int* __restrict__ indptr, int* __restrict__ fill,
                       int* __restrict__ col, int E){
  int i = blockIdx.x*256 + threadIdx.x;
  if (i < E){
    int d = dst[i];
    int r = atomicAdd(&fill[d], 1);
    col[indptr[d] + r] = src[i];
  }
}

// ---------------- aggregation: z[n] = h[n] + sum_{neighbors} h[src] ----------------
template<int F>
__global__ __launch_bounds__(256) void k_agg(const float* __restrict__ h, const int* __restrict__ indptr,
                                             const int* __restrict__ col, float* __restrict__ z, int N){
  constexpr int TPN = F/4;          // threads per node
  constexpr int NPB = 256/TPN;      // nodes per block
  int n = blockIdx.x*NPB + threadIdx.x/TPN;
  int lane = threadIdx.x % TPN;
  if (n >= N) return;
  const float4* hv = (const float4*)h;
  float4 acc = hv[(size_t)n*TPN + lane];
  int s = indptr[n], e = indptr[n+1];
  for (int p = s; p < e; ++p){
    int c = col[p];
    float4 x = hv[(size_t)c*TPN + lane];
    acc.x += x.x; acc.y += x.y; acc.z += x.z; acc.w += x.w;
  }
  ((float4*)z)[(size_t)n*TPN + lane] = acc;
}

// ---------------- generic f32 GEMM: out[n][j] = act(sum_k A[n][k]*W[j][k] + b[j]) ----------------
__global__ __launch_bounds__(TPB) void k_gemm(const float* __restrict__ A, const float* __restrict__ W,
                                              const float* __restrict__ bias, float* __restrict__ out,
                                              int K, int JC, int act, int N){
  extern __shared__ float sm[];
  float* As = sm;                       // [K][68]
  float* Ws = sm + (size_t)K*68;        // [K][34]
  const int tid = threadIdx.x;
  const int tx = tid & 15, ty = tid >> 4;
  const int nb = blockIdx.x * 64;
  const int kq = K >> 2;
  for (int it = 0, idx = tid; it < (kq >> 1); ++it, idx += TPB){
    int nl = idx & 63, kk = idx >> 6;
    int k4 = kk << 2;
    int n = nb + nl;
    float4 v = make_float4(0.f,0.f,0.f,0.f);
    if (n < N) v = *(const float4*)(A + (size_t)n*K + k4);
    As[(size_t)(k4+0)*68 + nl] = v.x;
    As[(size_t)(k4+1)*68 + nl] = v.y;
    As[(size_t)(k4+2)*68 + nl] = v.z;
    As[(size_t)(k4+3)*68 + nl] = v.w;
  }
  const int ncc = JC >> 5;
  for (int cc = 0; cc < ncc; ++cc){
    __syncthreads();
    for (int it = 0, idx = tid; it < (kq >> 2); ++it, idx += TPB){
      int cl = idx & 31, kk = idx >> 5;
      int k4 = kk << 2;
      int j = (cc << 5) + cl;
      float4 v = *(const float4*)(W + (size_t)j*K + k4);
      Ws[(size_t)(k4+0)*34 + cl] = v.x;
      Ws[(size_t)(k4+1)*34 + cl] = v.y;
      Ws[(size_t)(k4+2)*34 + cl] = v.z;
      Ws[(size_t)(k4+3)*34 + cl] = v.w;
    }
    __syncthreads();
    float4 acc0 = make_float4(0,0,0,0), acc1 = acc0, acc2 = acc0, acc3 = acc0;
    #pragma unroll 4
    for (int k = 0; k < K; ++k){
      float4 a = *(const float4*)(As + (size_t)k*68 + (tx<<2));
      float2 w01 = *(const float2*)(Ws + (size_t)k*34 + (ty<<2));
      float2 w23 = *(const float2*)(Ws + (size_t)k*34 + (ty<<2) + 2);
      acc0.x = fmaf(a.x, w01.x, acc0.x); acc0.y = fmaf(a.x, w01.y, acc0.y);
      acc0.z = fmaf(a.x, w23.x, acc0.z); acc0.w = fmaf(a.x, w23.y, acc0.w);
      acc1.x = fmaf(a.y, w01.x, acc1.x); acc1.y = fmaf(a.y, w01.y, acc1.y);
      acc1.z = fmaf(a.y, w23.x, acc1.z); acc1.w = fmaf(a.y, w23.y, acc1.w);
      acc2.x = fmaf(a.z, w01.x, acc2.x); acc2.y = fmaf(a.z, w01.y, acc2.y);
      acc2.z = fmaf(a.z, w23.x, acc2.z); acc2.w = fmaf(a.z, w23.y, acc2.w);
      acc3.x = fmaf(a.w, w01.x, acc3.x); acc3.y = fmaf(a.w, w01.y, acc3.y);
      acc3.z = fmaf(a.w, w23.x, acc3.z); acc3.w = fmaf(a.w, w23.y, acc3.w);
    }
    int j0 = (cc << 5) + (ty << 2);
    float4 b4 = make_float4(0,0,0,0);
    if (bias) b4 = *(const float4*)(bias + j0);
    float4 r[4] = {acc0, acc1, acc2, acc3};
    #pragma unroll
    for (int i = 0; i < 4; ++i){
      int n = nb + (tx<<2) + i;
      if (n < N){
        float4 o;
        o.x = r[i].x + b4.x; o.y = r[i].y + b4.y; o.z = r[i].z + b4.z; o.w = r[i].w + b4.w;
        if (act){
          o.x = fmaxf(o.x, 0.f); o.y = fmaxf(o.y, 0.f);
          o.z = fmaxf(o.z, 0.f); o.w = fmaxf(o.w, 0.f);
        }
        *(float4*)(out + (size_t)n*JC + j0) = o;
      }
    }
  }
}

// ---------------- LSTM weight/bias prepack (K-quarter-split layouts) ----------------
// Wq40 layout: idx = ((q*24 + jc)*16 + r)*40 + kk ; r = jl*4+g ; j = jc*4+jl ;
//   orig row = g*96+j ; orig k = q*40+kk ; from [Wih | Whh]
__global__ __launch_bounds__(256) void k_packW40(const float* __restrict__ Wih, const float* __restrict__ Whh,
                                                 float* __restrict__ Wq){
  int idx = blockIdx.x*256 + threadIdx.x;
  if (idx >= 4*24*16*40) return;
  int kk = idx % 40; int t = idx / 40;
  int r = t & 15; int t2 = t >> 4;
  int jc = t2 % 24; int q = t2 / 24;
  int j = jc*4 + (r>>2); int g = r & 3;
  int row = g*96 + j;
  int ko = q*40 + kk;
  Wq[idx] = (ko < 64) ? Wih[row*64 + ko] : Whh[row*96 + (ko-64)];
}

// Wq16 layout (K=64 first step, Wih only): idx = ((q*24+jc)*16 + r)*16 + kk ; orig k = q*16+kk
__global__ __launch_bounds__(256) void k_packW16(const float* __restrict__ Wih, float* __restrict__ Wq){
  int idx = blockIdx.x*256 + threadIdx.x;
  if (idx >= 4*24*16*16) return;
  int kk = idx & 15; int t = idx >> 4;
  int r = t & 15; int t2 = t >> 4;
  int jc = t2 % 24; int q = t2 / 24;
  int j = jc*4 + (r>>2); int g = r & 3;
  int row = g*96 + j;
  Wq[idx] = Wih[row*64 + (q*16 + kk)];
}

__global__ __launch_bounds__(128) void k_packB(const float* __restrict__ bih, const float* __restrict__ bhh,
                                               float4* __restrict__ Bp){
  int j = blockIdx.x*128 + threadIdx.x;
  if (j >= 96) return;
  Bp[j] = make_float4(bih[j]+bhh[j], bih[96+j]+bhh[96+j],
                      bih[192+j]+bhh[192+j], bih[288+j]+bhh[288+j]);
}

// ---------------- fused per-direction LSTM (3 timesteps in one kernel) ----------------
// Block: 64 nodes (lane = node), 4 waves = 4 K-quarters (phs).
// Weights streamed via uniform scalar loads from the packed quarter layouts.
// Gate partials exchanged via sEx (12KB, 2 barriers/chunk); h kept in LDS hX[96][64];
// c in global cbuf[96][N] (runtime j index -> memory, not registers).
template<int KH, int FIRST>
__device__ __forceinline__ float lstm_step_chunks(
    const float (&x)[40], const float* __restrict__ Wq,
    const float4* __restrict__ Bp, const float* __restrict__ WattW,
    float* __restrict__ cbuf, int n, int N, bool ok,
    int phs, int lane,
    float (*sEx)[3][64], float (*hX)[64])
{
  float aAcc = 0.f;
  for (int jc = 0; jc < 24; ++jc){
    const float* wr = Wq + (size_t)((phs*24 + jc)*16)*KH;
    float acc[16];
    #pragma unroll
    for (int r=0;r<16;++r) acc[r]=0.f;
    #pragma unroll
    for (int kb=0; kb<KH; kb+=8){
      #pragma unroll
      for (int r=0;r<16;++r){
        #pragma unroll
        for (int k=0;k<8;++k)
          acc[r] = fmaf(x[kb+k], wr[r*KH + kb + k], acc[r]);
      }
    }
    // exchange the 12 rows owned by other waves (slot-compressed [16][3][64])
    #pragma unroll
    for (int r=0;r<16;++r){
      const int jl = r>>2;
      if (jl != phs){
        int slot = phs - (phs > jl ? 1 : 0);
        sEx[r][slot][lane] = acc[r];
      }
    }
    __syncthreads();
    // own 4 rows: compile-time acc indices via uniform branch
    float o0,o1,o2,o3;
    if      (phs==0){o0=acc[0]; o1=acc[1]; o2=acc[2]; o3=acc[3];}
    else if (phs==1){o0=acc[4]; o1=acc[5]; o2=acc[6]; o3=acc[7];}
    else if (phs==2){o0=acc[8]; o1=acc[9]; o2=acc[10];o3=acc[11];}
    else            {o0=acc[12];o1=acc[13];o2=acc[14];o3=acc[15];}
    const int j  = jc*4 + phs;
    const int r0 = phs*4;
    float4 b = Bp[j];
    float gi = o0 + sEx[r0+0][0][lane] + sEx[r0+0][1][lane] + sEx[r0+0][2][lane] + b.x;
    float gf = o1 + sEx[r0+1][0][lane] + sEx[r0+1][1][lane] + sEx[r0+1][2][lane] + b.y;
    float gg = o2 + sEx[r0+2][0][lane] + sEx[r0+2][1][lane] + sEx[r0+2][2][lane] + b.z;
    float go = o3 + sEx[r0+3][0][lane] + sEx[r0+3][1][lane] + sEx[r0+3][2][lane] + b.w;
    float cp = 0.f;
    if (!FIRST && ok) cp = cbuf[(size_t)j*N + n];
    float cc = sigf(gf)*cp + sigf(gi)*tanh_f(gg);
    float hh = sigf(go)*tanh_f(cc);
    if (ok) cbuf[(size_t)j*N + n] = cc;
    hX[j][lane] = hh;
    aAcc = fmaf(hh, WattW[j], aAcc);
    __syncthreads();
  }
  return aAcc;
}

__device__ __forceinline__ void load_x_first(float (&x)[40], const float* __restrict__ seq,
                                             int n, bool ok, int phs){
  if (ok){
    const float4* s4 = (const float4*)(seq + (size_t)n*64 + phs*16);
    #pragma unroll
    for (int i=0;i<4;++i){ float4 v=s4[i]; x[4*i]=v.x; x[4*i+1]=v.y; x[4*i+2]=v.z; x[4*i+3]=v.w; }
  } else {
    #pragma unroll
    for (int i=0;i<16;++i) x[i]=0.f;
  }
}

__device__ __forceinline__ void load_x_full(float (&x)[40], const float* __restrict__ seq,
                                            int n, bool ok, int phs, int lane, float (*hX)[64]){
  if (phs == 0){
    if (ok){
      const float4* s4 = (const float4*)(seq + (size_t)n*64);
      #pragma unroll
      for (int i=0;i<10;++i){ float4 v=s4[i]; x[4*i]=v.x; x[4*i+1]=v.y; x[4*i+2]=v.z; x[4*i+3]=v.w; }
    } else {
      #pragma unroll
      for (int i=0;i<40;++i) x[i]=0.f;
    }
  } else if (phs == 1){
    if (ok){
      const float4* s4 = (const float4*)(seq + (size_t)n*64 + 40);
      #pragma unroll
      for (int i=0;i<6;++i){ float4 v=s4[i]; x[4*i]=v.x; x[4*i+1]=v.y; x[4*i+2]=v.z; x[4*i+3]=v.w; }
    } else {
      #pragma unroll
      for (int i=0;i<24;++i) x[i]=0.f;
    }
    #pragma unroll
    for (int i=0;i<16;++i) x[24+i] = hX[i][lane];
  } else if (phs == 2){
    #pragma unroll
    for (int i=0;i<40;++i) x[i] = hX[16+i][lane];
  } else {
    #pragma unroll
    for (int i=0;i<40;++i) x[i] = hX[56+i][lane];
  }
}

__global__ __launch_bounds__(256,4) void k_lstm_dir(
    const float* __restrict__ sA, const float* __restrict__ sB, const float* __restrict__ sC,
    const float* __restrict__ Wq16, const float* __restrict__ Wq40,
    const float4* __restrict__ Bp, const float* __restrict__ Watt, const float* __restrict__ batt,
    float* __restrict__ cbuf,
    float* __restrict__ aA, float* __restrict__ aB, float* __restrict__ aC,
    int initA, int woff, int N)
{
  __shared__ float sEx[16][3][64];   // 12 KB; reused as alpha-partials at the end
  __shared__ float hX[96][64];       // 24.5 KB
  const int tid  = threadIdx.x;
  const int lane = tid & 63;
  const int phs  = __builtin_amdgcn_readfirstlane(tid >> 6);
  const int n = blockIdx.x*64 + lane;
  const bool ok = n < N;
  const float* WattW = Watt + woff;

  float x[40];
  float a0, a1, a2;

  load_x_first(x, sA, n, ok, phs);
  a0 = lstm_step_chunks<16,1>(x, Wq16, Bp, WattW, cbuf, n, N, ok, phs, lane, sEx, hX);
  load_x_full(x, sB, n, ok, phs, lane, hX);
  a1 = lstm_step_chunks<40,0>(x, Wq40, Bp, WattW, cbuf, n, N, ok, phs, lane, sEx, hX);
  load_x_full(x, sC, n, ok, phs, lane, hX);
  a2 = lstm_step_chunks<40,0>(x, Wq40, Bp, WattW, cbuf, n, N, ok, phs, lane, sEx, hX);

  // alpha reduce across the 4 waves (reuse sEx storage; last loop barrier protects)
  float* sAl = &sEx[0][0][0];        // need 3*4*64 = 768 floats
  sAl[(0*4+phs)*64 + lane] = a0;
  sAl[(1*4+phs)*64 + lane] = a1;
  sAl[(2*4+phs)*64 + lane] = a2;
  __syncthreads();
  if (phs < 3 && ok){
    float s = sAl[(phs*4+0)*64+lane] + sAl[(phs*4+1)*64+lane]
            + sAl[(phs*4+2)*64+lane] + sAl[(phs*4+3)*64+lane];
    float* ap = (phs==0) ? aA : (phs==1) ? aB : aC;
    if (initA) ap[n] = batt[0] + s;
    else       ap[n] += s;
  }
}

// ---------------- JK softmax + xjk + Wlin + Wfc1 + leaky ----------------
__global__ __launch_bounds__(256) void k_jk(const float* __restrict__ alpha,
                                            const float* __restrict__ h1, const float* __restrict__ h2,
                                            const float* __restrict__ h3,
                                            const float* __restrict__ Wlin, const float* __restrict__ blin,
                                            const float* __restrict__ Wfc1, const float* __restrict__ bfc1,
                                            float* __restrict__ vout, int N){
  __shared__ float sWl[64*65];
  __shared__ float sX[4][64];
  __shared__ float sR[4][64];
  int tid = threadIdx.x;
  for (int idx = tid; idx < 1024; idx += 256){
    int j = idx >> 4;
    int c4 = (idx & 15) << 2;
    float4 v = *(const float4*)(Wlin + (size_t)j*64 + c4);
    sWl[j*65 + c4+0] = v.x; sWl[j*65 + c4+1] = v.y;
    sWl[j*65 + c4+2] = v.z; sWl[j*65 + c4+3] = v.w;
  }
  int ln = tid >> 6, j = tid & 63;
  int n = blockIdx.x*4 + ln;
  bool ok = n < N;
  float xj = 0.f;
  if (ok){
    float a0 = alpha[n], a1 = alpha[(size_t)N + n], a2 = alpha[(size_t)2*N + n];
    float m = fmaxf(a0, fmaxf(a1, a2));
    float e0 = __expf(a0-m), e1 = __expf(a1-m), e2 = __expf(a2-m);
    float inv = __builtin_amdgcn_rcpf(e0+e1+e2);
    float w0 = e0*inv, w1 = e1*inv, w2 = e2*inv;
    xj = w0*h1[(size_t)n*64 + j] + w1*h2[(size_t)n*64 + j] + w2*h3[(size_t)n*64 + j];
  }
  sX[ln][j] = xj;
  __syncthreads();
  float acc = blin[j];
  #pragma unroll 8
  for (int c = 0; c < 64; ++c) acc = fmaf(sX[ln][c], sWl[j*65 + c], acc);
  sR[ln][j] = acc * Wfc1[j];
  __syncthreads();
  #pragma unroll
  for (int off = 32; off > 0; off >>= 1){
    if (j < off) sR[ln][j] += sR[ln][j + off];
    __syncthreads();
  }
  if (j == 0 && ok){
    float vv = sR[ln][0] + bfc1[0];
    vout[n] = vv >= 0.f ? vv : 0.01f*vv;
  }
}

// ---------------- final dot (deterministic two-stage, f64 accum) ----------------
__global__ __launch_bounds__(256) void k_final1(const float* __restrict__ w, const float* __restrict__ v,
                                                double* __restrict__ part, int N){
  __shared__ double sd[256];
  int tid = threadIdx.x;
  double a = 0.0;
  for (int i = blockIdx.x*256 + tid; i < N; i += 256*256)
    a += (double)(w[i] * v[i]);
  sd[tid] = a; __syncthreads();
  for (int off = 128; off > 0; off >>= 1){
    if (tid < off) sd[tid] += sd[tid + off];
    __syncthreads();
  }
  if (tid == 0) part[blockIdx.x] = sd[0];
}

__global__ __launch_bounds__(256) void k_final2(const double* __restrict__ part, const float* __restrict__ bfc2,
                                                float* __restrict__ out){
  __shared__ double sd[256];
  int tid = threadIdx.x;
  sd[tid] = part[tid]; __syncthreads();
  for (int off = 128; off > 0; off >>= 1){
    if (tid < off) sd[tid] += sd[tid + off];
    __syncthreads();
  }
  if (tid == 0) out[0] = (float)(sd[0] + (double)bfc2[0]);
}

// ---------------- host ----------------
extern "C" void kernel_launch(void* const* d_in, const int* in_sizes, int n_in,
                              void* d_out, int out_size, void* d_ws, size_t ws_size,
                              hipStream_t stream){
  const float* x    = (const float*)d_in[0];
  const int*   ei   = (const int*)d_in[1];
  const float* W0a  = (const float*)d_in[2];
  const float* b0a  = (const float*)d_in[3];
  const float* W0b  = (const float*)d_in[4];
  const float* b0b  = (const float*)d_in[5];
  const float* W1a  = (const float*)d_in[6];
  const float* b1a  = (const float*)d_in[7];
  const float* W1b  = (const float*)d_in[8];
  const float* b1b  = (const float*)d_in[9];
  const float* W2a  = (const float*)d_in[10];
  const float* b2a  = (const float*)d_in[11];
  const float* W2b  = (const float*)d_in[12];
  const float* b2b  = (const float*)d_in[13];
  const float* Wih_f = (const float*)d_in[14];
  const float* Whh_f = (const float*)d_in[15];
  const float* bih_f = (const float*)d_in[16];
  const float* bhh_f = (const float*)d_in[17];
  const float* Wih_b = (const float*)d_in[18];
  const float* Whh_b = (const float*)d_in[19];
  const float* bih_b = (const float*)d_in[20];
  const float* bhh_b = (const float*)d_in[21];
  const float* Watt = (const float*)d_in[22];
  const float* batt = (const float*)d_in[23];
  const float* Wlin = (const float*)d_in[24];
  const float* blin = (const float*)d_in[25];
  const float* Wfc1 = (const float*)d_in[26];
  const float* bfc1 = (const float*)d_in[27];
  const float* Wfc2 = (const float*)d_in[28];
  const float* bfc2 = (const float*)d_in[29];
  float* out = (float*)d_out;

  const int N = in_sizes[0] / 128;
  const int E = in_sizes[1] / 2;
  const int* src = ei;
  const int* dst = ei + E;

  uint8_t* w8 = (uint8_t*)d_ws;
  size_t off = 0;
  auto alloc = [&](size_t bytes) -> void* {
    void* p = w8 + off;
    off = (off + bytes + 255) & ~(size_t)255;
    return p;
  };
  int*    deg    = (int*)   alloc((size_t)N*4);
  int*    fill   = (int*)   alloc((size_t)N*4);
  int*    indptr = (int*)   alloc(((size_t)N+1)*4);
  int*    col    = (int*)   alloc((size_t)E*4);
  int*    bsum   = (int*)   alloc(2048);
  int*    boffs  = (int*)   alloc(2048);
  float*  h1     = (float*) alloc((size_t)N*64*4);
  float*  h2     = (float*) alloc((size_t)N*64*4);
  float*  h3     = (float*) alloc((size_t)N*64*4);
  float*  alpha  = (float*) alloc((size_t)3*N*4);
  float*  vbuf   = (float*) alloc((size_t)N*4);
  double* part   = (double*)alloc(256*8);
  float*  Wq16f  = (float*) alloc((size_t)4*24*16*16*4);
  float*  Wq40f  = (float*) alloc((size_t)4*24*16*40*4);
  float*  Wq16b  = (float*) alloc((size_t)4*24*16*16*4);
  float*  Wq40b  = (float*) alloc((size_t)4*24*16*40*4);
  float4* Bpf    = (float4*)alloc((size_t)96*16);
  float4* Bpb    = (float4*)alloc((size_t)96*16);
  float*  P      = (float*) alloc((size_t)N*192*4);   // phase-shared region
  if (off > ws_size) return;
  float* zbuf = P;                      // GIN phase: z tile [N,128]
  float* mid  = P + (size_t)N*128;      // GIN phase: MLP intermediate [N,64]
  float* cb   = P;                      // LSTM phase: c transposed [96][N]

  const size_t lds64  = 64  * 102 * 4;
  const size_t lds128 = 128 * 102 * 4;

  hipMemsetAsync(deg,  0, (size_t)N*4, stream);
  hipMemsetAsync(fill, 0, (size_t)N*4, stream);

  int gE = (E + 255) / 256;
  int nb1 = (N + 255) / 256;
  int gG = (N + 63) / 64;

  // weight prepack (independent of CSR)
  k_packW40<<<240, 256, 0, stream>>>(Wih_f, Whh_f, Wq40f);
  k_packW40<<<240, 256, 0, stream>>>(Wih_b, Whh_b, Wq40b);
  k_packW16<<<96, 256, 0, stream>>>(Wih_f, Wq16f);
  k_packW16<<<96, 256, 0, stream>>>(Wih_b, Wq16b);
  k_packB<<<1, 128, 0, stream>>>(bih_f, bhh_f, Bpf);
  k_packB<<<1, 128, 0, stream>>>(bih_b, bhh_b, Bpb);

  k_deg  <<<gE, 256, 0, stream>>>(dst, deg, E);
  k_scan1<<<nb1, 256, 0, stream>>>(deg, indptr, bsum, N);
  k_scan2<<<1, 512, 0, stream>>>(bsum, boffs, indptr, nb1, N);
  k_scan3<<<nb1, 256, 0, stream>>>(indptr, boffs, N);
  k_fill <<<gE, 256, 0, stream>>>(src, dst, indptr, fill, col, E);

  // ---- GIN layer 0 (F=128) ----
  k_agg<128><<<(N+7)/8, 256, 0, stream>>>(x, indptr, col, zbuf, N);
  k_gemm<<<gG, TPB, lds128, stream>>>(zbuf, W0a, b0a, mid, 128, 64, 1, N);
  k_gemm<<<gG, TPB, lds64,  stream>>>(mid,  W0b, b0b, h1,  64,  64, 1, N);
  // ---- GIN layer 1 ----
  k_agg<64><<<(N+15)/16, 256, 0, stream>>>(h1, indptr, col, zbuf, N);
  k_gemm<<<gG, TPB, lds64, stream>>>(zbuf, W1a, b1a, mid, 64, 64, 1, N);
  k_gemm<<<gG, TPB, lds64, stream>>>(mid,  W1b, b1b, h2,  64, 64, 1, N);
  // ---- GIN layer 2 ----
  k_agg<64><<<(N+15)/16, 256, 0, stream>>>(h2, indptr, col, zbuf, N);
  k_gemm<<<gG, TPB, lds64, stream>>>(zbuf, W2a, b2a, mid, 64, 64, 1, N);
  k_gemm<<<gG, TPB, lds64, stream>>>(mid,  W2b, b2b, h3,  64, 64, 1, N);

  // ---- LSTM: one fused kernel per direction ----
  k_lstm_dir<<<gG, 256, 0, stream>>>(h1, h2, h3, Wq16f, Wq40f, Bpf, Watt, batt, cb,
                                     alpha, alpha + (size_t)N, alpha + (size_t)2*N, 1, 0, N);
  k_lstm_dir<<<gG, 256, 0, stream>>>(h3, h2, h1, Wq16b, Wq40b, Bpb, Watt, batt, cb,
                                     alpha + (size_t)2*N, alpha + (size_t)N, alpha, 0, 96, N);

  // ---- JK attention + linear + fc1 + leaky ----
  k_jk<<<(N+3)/4, 256, 0, stream>>>(alpha, h1, h2, h3, Wlin, blin, Wfc1, bfc1, vbuf, N);

  // ---- final dot ----
  k_final1<<<256, 256, 0, stream>>>(Wfc2, vbuf, part, N);
  k_final2<<<1, 256, 0, stream>>>(part, bfc2, out);
}

// Round 4
// 1067.635 us; speedup vs baseline: 3.8652x; 2.0517x over previous
//
#include <hip/hip_runtime.h>
#include <stdint.h>

#define TPB 128
typedef unsigned short u16;
typedef unsigned int u32;
using short8 = __attribute__((ext_vector_type(8))) short;
using f32x16 = __attribute__((ext_vector_type(16))) float;

__device__ __forceinline__ float sigf(float x){
  return __builtin_amdgcn_rcpf(1.0f + __expf(-x));
}
__device__ __forceinline__ float tanh_f(float x){
  return 1.0f - 2.0f*__builtin_amdgcn_rcpf(1.0f + __expf(2.0f*x));
}
__device__ __forceinline__ u16 f2bf(float f){
  u32 u = __float_as_uint(f);
  u += 0x7FFFu + ((u>>16)&1u);
  return (u16)(u>>16);
}
__device__ __forceinline__ float bf2f(u16 h){ return __uint_as_float(((u32)h)<<16); }

// ---------------- CSR build ----------------
__global__ void k_deg(const int* __restrict__ dst, int* __restrict__ deg, int E){
  int i = blockIdx.x*256 + threadIdx.x;
  if (i < E) atomicAdd(&deg[dst[i]], 1);
}

__global__ __launch_bounds__(256) void k_scan1(const int* __restrict__ deg, int* __restrict__ indptr,
                                               int* __restrict__ bsum, int N){
  __shared__ int s[256];
  int tid = threadIdx.x;
  int i = blockIdx.x*256 + tid;
  int v = (i < N) ? deg[i] : 0;
  s[tid] = v; __syncthreads();
  for (int off=1; off<256; off<<=1){
    int t = (tid>=off) ? s[tid-off] : 0;
    __syncthreads();
    s[tid] += t;
    __syncthreads();
  }
  if (i < N) indptr[i] = s[tid] - v;      // block-local exclusive
  if (tid == 255) bsum[blockIdx.x] = s[255];
}

__global__ __launch_bounds__(512) void k_scan2(const int* __restrict__ bsum, int* __restrict__ boffs,
                                               int* __restrict__ indptr, int nb, int N){
  __shared__ int s[512];
  int tid = threadIdx.x;
  int v = (tid < nb) ? bsum[tid] : 0;
  s[tid] = v; __syncthreads();
  for (int off=1; off<512; off<<=1){
    int t = (tid>=off) ? s[tid-off] : 0;
    __syncthreads();
    s[tid] += t;
    __syncthreads();
  }
  boffs[tid] = s[tid] - v;
  if (tid == nb-1) indptr[N] = s[tid];
}

__global__ __launch_bounds__(256) void k_scan3(int* __restrict__ indptr, const int* __restrict__ boffs, int N){
  int i = blockIdx.x*256 + threadIdx.x;
  if (i < N) indptr[i] += boffs[blockIdx.x];
}

__global__ void k_fill(const int* __restrict__ src, const int* __restrict__ dst,
                       const int* __restrict__ indptr, int* __restrict__ fill,
                       int* __restrict__ col, int E){
  int i = blockIdx.x*256 + threadIdx.x;
  if (i < E){
    int d = dst[i];
    int r = atomicAdd(&fill[d], 1);
    col[indptr[d] + r] = src[i];
  }
}

// ---------------- aggregation: z[n] = h[n] + sum_{neighbors} h[src] ----------------
template<int F>
__global__ __launch_bounds__(256) void k_agg(const float* __restrict__ h, const int* __restrict__ indptr,
                                             const int* __restrict__ col, float* __restrict__ z, int N){
  constexpr int TPN = F/4;          // threads per node
  constexpr int NPB = 256/TPN;      // nodes per block
  int n = blockIdx.x*NPB + threadIdx.x/TPN;
  int lane = threadIdx.x % TPN;
  if (n >= N) return;
  const float4* hv = (const float4*)h;
  float4 acc = hv[(size_t)n*TPN + lane];
  int s = indptr[n], e = indptr[n+1];
  for (int p = s; p < e; ++p){
    int c = col[p];
    float4 x = hv[(size_t)c*TPN + lane];
    acc.x += x.x; acc.y += x.y; acc.z += x.z; acc.w += x.w;
  }
  ((float4*)z)[(size_t)n*TPN + lane] = acc;
}

// ---------------- generic f32 GEMM: out[n][j] = act(sum_k A[n][k]*W[j][k] + b[j]) ----------------
__global__ __launch_bounds__(TPB) void k_gemm(const float* __restrict__ A, const float* __restrict__ W,
                                              const float* __restrict__ bias, float* __restrict__ out,
                                              int K, int JC, int act, int N){
  extern __shared__ float sm[];
  float* As = sm;                       // [K][68]
  float* Ws = sm + (size_t)K*68;        // [K][34]
  const int tid = threadIdx.x;
  const int tx = tid & 15, ty = tid >> 4;
  const int nb = blockIdx.x * 64;
  const int kq = K >> 2;
  for (int it = 0, idx = tid; it < (kq >> 1); ++it, idx += TPB){
    int nl = idx & 63, kk = idx >> 6;
    int k4 = kk << 2;
    int n = nb + nl;
    float4 v = make_float4(0.f,0.f,0.f,0.f);
    if (n < N) v = *(const float4*)(A + (size_t)n*K + k4);
    As[(size_t)(k4+0)*68 + nl] = v.x;
    As[(size_t)(k4+1)*68 + nl] = v.y;
    As[(size_t)(k4+2)*68 + nl] = v.z;
    As[(size_t)(k4+3)*68 + nl] = v.w;
  }
  const int ncc = JC >> 5;
  for (int cc = 0; cc < ncc; ++cc){
    __syncthreads();
    for (int it = 0, idx = tid; it < (kq >> 2); ++it, idx += TPB){
      int cl = idx & 31, kk = idx >> 5;
      int k4 = kk << 2;
      int j = (cc << 5) + cl;
      float4 v = *(const float4*)(W + (size_t)j*K + k4);
      Ws[(size_t)(k4+0)*34 + cl] = v.x;
      Ws[(size_t)(k4+1)*34 + cl] = v.y;
      Ws[(size_t)(k4+2)*34 + cl] = v.z;
      Ws[(size_t)(k4+3)*34 + cl] = v.w;
    }
    __syncthreads();
    float4 acc0 = make_float4(0,0,0,0), acc1 = acc0, acc2 = acc0, acc3 = acc0;
    #pragma unroll 4
    for (int k = 0; k < K; ++k){
      float4 a = *(const float4*)(As + (size_t)k*68 + (tx<<2));
      float2 w01 = *(const float2*)(Ws + (size_t)k*34 + (ty<<2));
      float2 w23 = *(const float2*)(Ws + (size_t)k*34 + (ty<<2) + 2);
      acc0.x = fmaf(a.x, w01.x, acc0.x); acc0.y = fmaf(a.x, w01.y, acc0.y);
      acc0.z = fmaf(a.x, w23.x, acc0.z); acc0.w = fmaf(a.x, w23.y, acc0.w);
      acc1.x = fmaf(a.y, w01.x, acc1.x); acc1.y = fmaf(a.y, w01.y, acc1.y);
      acc1.z = fmaf(a.y, w23.x, acc1.z); acc1.w = fmaf(a.y, w23.y, acc1.w);
      acc2.x = fmaf(a.z, w01.x, acc2.x); acc2.y = fmaf(a.z, w01.y, acc2.y);
      acc2.z = fmaf(a.z, w23.x, acc2.z); acc2.w = fmaf(a.z, w23.y, acc2.w);
      acc3.x = fmaf(a.w, w01.x, acc3.x); acc3.y = fmaf(a.w, w01.y, acc3.y);
      acc3.z = fmaf(a.w, w23.x, acc3.z); acc3.w = fmaf(a.w, w23.y, acc3.w);
    }
    int j0 = (cc << 5) + (ty << 2);
    float4 b4 = make_float4(0,0,0,0);
    if (bias) b4 = *(const float4*)(bias + j0);
    float4 r[4] = {acc0, acc1, acc2, acc3};
    #pragma unroll
    for (int i = 0; i < 4; ++i){
      int n = nb + (tx<<2) + i;
      if (n < N){
        float4 o;
        o.x = r[i].x + b4.x; o.y = r[i].y + b4.y; o.z = r[i].z + b4.z; o.w = r[i].w + b4.w;
        if (act){
          o.x = fmaxf(o.x, 0.f); o.y = fmaxf(o.y, 0.f);
          o.z = fmaxf(o.z, 0.f); o.w = fmaxf(o.w, 0.f);
        }
        *(float4*)(out + (size_t)n*JC + j0) = o;
      }
    }
  }
}

// ---------------- LSTM weight prepack: fragment-linear bf16 hi/lo planes ----------------
// Frag layout for mfma_f32_32x32x16_bf16 A-operand: lane l holds A[row=l&31][k=kt*16+(l>>5)*8+i].
// Row r = rt*32 + (l&31); r = 4*j + g (gate-interleaved); orig row = g*96 + j.
// Wp index = (((kt*12 + rt)*2 + p)*64 + l)*8 + i  (p: 0=hi, 1=lo residual)
__global__ __launch_bounds__(256) void k_packWfrag(const float* __restrict__ Wih, const float* __restrict__ Whh,
                                                   u16* __restrict__ Wp){
  int idx = blockIdx.x*256 + threadIdx.x;
  if (idx >= 10*12*2*64*8) return;
  int i  = idx & 7;
  int l  = (idx>>3) & 63;
  int p  = (idx>>9) & 1;
  int rt = (idx>>10) % 12;
  int kt = (idx>>10) / 12;
  int r  = rt*32 + (l & 31);
  int j  = r >> 2, g = r & 3;
  int row = g*96 + j;
  int k  = kt*16 + ((l>>5)<<3) + i;
  float v = (k < 64) ? Wih[row*64 + k] : Whh[row*96 + (k-64)];
  u16 h = f2bf(v);
  Wp[idx] = p ? f2bf(v - bf2f(h)) : h;
}

__global__ __launch_bounds__(128) void k_packB(const float* __restrict__ bih, const float* __restrict__ bhh,
                                               float4* __restrict__ Bp){
  int j = blockIdx.x*128 + threadIdx.x;
  if (j >= 96) return;
  Bp[j] = make_float4(bih[j]+bhh[j], bih[96+j]+bhh[96+j],
                      bih[192+j]+bhh[192+j], bih[288+j]+bhh[288+j]);
}

// ---------------- MFMA LSTM: one kernel per direction, 3 timesteps fused ----------------
// Block = 64 nodes, 4 waves. D-tiles 32x32: rows = packed gate-rows (384 = 12 row-tiles,
// wave w owns rt = 3w..3w+2), cols = nodes (2 node-tiles). X = [x(64) | h(96)] as bf16
// hi/lo planes in LDS [64][168]. W streamed frag-linear from L2 (double-buffered regs).
// c state in 24 static VGPRs; h round-trips through LDS; alpha reduced in-kernel.

__device__ __forceinline__ void stage_x(const float* __restrict__ seq,
                                        u16 (*Xhi)[168], u16 (*Xlo)[168],
                                        int blk, int N, int tid){
  int node = tid >> 2;
  int kq = (tid & 3) << 4;
  int n = blk*64 + node;
  float v[16];
  if (n < N){
    const float4* s4 = (const float4*)(seq + (size_t)n*64 + kq);
    #pragma unroll
    for (int i=0;i<4;++i){ float4 t = s4[i]; v[4*i]=t.x; v[4*i+1]=t.y; v[4*i+2]=t.z; v[4*i+3]=t.w; }
  } else {
    #pragma unroll
    for (int i=0;i<16;++i) v[i]=0.f;
  }
  u32 hw[8], lw[8];
  #pragma unroll
  for (int i=0;i<8;++i){
    u16 h0=f2bf(v[2*i]),   h1=f2bf(v[2*i+1]);
    u16 l0=f2bf(v[2*i]-bf2f(h0)), l1=f2bf(v[2*i+1]-bf2f(h1));
    hw[i]= (u32)h0 | ((u32)h1<<16);
    lw[i]= (u32)l0 | ((u32)l1<<16);
  }
  uint4* ph = (uint4*)&Xhi[node][kq];
  ph[0] = make_uint4(hw[0],hw[1],hw[2],hw[3]);
  ph[1] = make_uint4(hw[4],hw[5],hw[6],hw[7]);
  uint4* pl = (uint4*)&Xlo[node][kq];
  pl[0] = make_uint4(lw[0],lw[1],lw[2],lw[3]);
  pl[1] = make_uint4(lw[4],lw[5],lw[6],lw[7]);
}

template<int FIRST>
__device__ __forceinline__ void lstm_step(const u16* __restrict__ Wp,
    const float4* __restrict__ Bp, const float* __restrict__ WattW,
    u16 (*Xhi)[168], u16 (*Xlo)[168],
    float (&c)[24], float (&aP)[2], int w, int l)
{
  constexpr int NKT = FIRST ? 4 : 10;   // k-tiles of 16 (K=64 first step: h is zero)
  const int hi = l >> 5;
  f32x16 acc[6];
  #pragma unroll
  for (int t=0;t<6;++t)
    #pragma unroll
    for (int r=0;r<16;++r) acc[t][r] = 0.f;

  auto ldA = [&](int kt, int ti, int p)->short8{
    const u16* ptr = Wp + ((((size_t)kt*12 + (w*3+ti))*2 + p)<<9) + ((size_t)l<<3);
    return *(const short8*)ptr;
  };
  auto ldB = [&](u16 (*X)[168], int kt, int nt)->short8{
    return *(const short8*)&X[nt*32 + (l&31)][kt*16 + (hi<<3)];
  };
  auto MM = [&](short8 (&A)[3][2], short8 (&B)[2][2]){
    #pragma unroll
    for (int s=0;s<3;++s){
      #pragma unroll
      for (int ti=0; ti<3; ++ti){
        #pragma unroll
        for (int nt=0; nt<2; ++nt){
          short8 a = (s==2) ? A[ti][1] : A[ti][0];
          short8 b = (s==1) ? B[nt][1] : B[nt][0];
          acc[ti*2+nt] = __builtin_amdgcn_mfma_f32_32x32x16_bf16(a, b, acc[ti*2+nt], 0, 0, 0);
        }
      }
    }
  };

  short8 Aa[3][2], Ab[3][2];
  #pragma unroll
  for (int ti=0;ti<3;++ti){ Aa[ti][0]=ldA(0,ti,0); Aa[ti][1]=ldA(0,ti,1); }
  #pragma unroll
  for (int kt=0; kt<NKT; kt+=2){
    #pragma unroll
    for (int ti=0;ti<3;++ti){ Ab[ti][0]=ldA(kt+1,ti,0); Ab[ti][1]=ldA(kt+1,ti,1); }
    short8 B0[2][2];
    #pragma unroll
    for (int nt=0;nt<2;++nt){ B0[nt][0]=ldB(Xhi,kt,nt); B0[nt][1]=ldB(Xlo,kt,nt); }
    MM(Aa, B0);
    if (kt+2 < NKT){
      #pragma unroll
      for (int ti=0;ti<3;++ti){ Aa[ti][0]=ldA(kt+2,ti,0); Aa[ti][1]=ldA(kt+2,ti,1); }
    }
    short8 B1[2][2];
    #pragma unroll
    for (int nt=0;nt<2;++nt){ B1[nt][0]=ldB(Xhi,kt+1,nt); B1[nt][1]=ldB(Xlo,kt+1,nt); }
    MM(Ab, B1);
  }

  if (!FIRST) __syncthreads();   // all waves done reading X's h-rows before overwriting

  #pragma unroll
  for (int ti=0;ti<3;++ti){
    #pragma unroll
    for (int nt=0;nt<2;++nt){
      const int node = nt*32 + (l&31);
      #pragma unroll
      for (int rg=0; rg<4; ++rg){
        const int j = (w*3+ti)*8 + 2*rg + hi;
        float4 bv = Bp[j];
        float gi = acc[ti*2+nt][rg*4+0] + bv.x;
        float gf = acc[ti*2+nt][rg*4+1] + bv.y;
        float gg = acc[ti*2+nt][rg*4+2] + bv.z;
        float go = acc[ti*2+nt][rg*4+3] + bv.w;
        const int ci = ti*8 + nt*4 + rg;
        float cp = FIRST ? 0.f : c[ci];
        float cn = sigf(gf)*cp + sigf(gi)*tanh_f(gg);
        float hh = sigf(go)*tanh_f(cn);
        c[ci] = cn;
        aP[nt] = fmaf(hh, WattW[j], aP[nt]);
        u16 hb = f2bf(hh);
        Xhi[node][64+j] = hb;
        Xlo[node][64+j] = f2bf(hh - bf2f(hb));
      }
    }
  }
}

__global__ __launch_bounds__(256,2) void k_lstm_mfma(
    const float* __restrict__ sA, const float* __restrict__ sB, const float* __restrict__ sC,
    const u16* __restrict__ Wp, const float4* __restrict__ Bp,
    const float* __restrict__ Watt, const float* __restrict__ batt,
    float* __restrict__ aAp, float* __restrict__ aBp, float* __restrict__ aCp,
    int initA, int woff, int N)
{
  __shared__ u16 Xhi[64][168];
  __shared__ u16 Xlo[64][168];
  __shared__ float sAl[4][3][2][32];
  const int tid = threadIdx.x;
  const int l = tid & 63;
  const int w = __builtin_amdgcn_readfirstlane(tid >> 6);
  const int blk = blockIdx.x;
  const float* WattW = Watt + woff;
  float c[24];
  float a0[2] = {0.f,0.f}, a1[2] = {0.f,0.f}, a2[2] = {0.f,0.f};

  stage_x(sA, Xhi, Xlo, blk, N, tid);
  __syncthreads();
  lstm_step<1>(Wp, Bp, WattW, Xhi, Xlo, c, a0, w, l);
  __syncthreads();
  stage_x(sB, Xhi, Xlo, blk, N, tid);
  __syncthreads();
  lstm_step<0>(Wp, Bp, WattW, Xhi, Xlo, c, a1, w, l);
  __syncthreads();
  stage_x(sC, Xhi, Xlo, blk, N, tid);
  __syncthreads();
  lstm_step<0>(Wp, Bp, WattW, Xhi, Xlo, c, a2, w, l);

  // alpha reduce: fold lane-halves, then cross-wave via LDS
  a0[0] += __shfl_xor(a0[0], 32); a0[1] += __shfl_xor(a0[1], 32);
  a1[0] += __shfl_xor(a1[0], 32); a1[1] += __shfl_xor(a1[1], 32);
  a2[0] += __shfl_xor(a2[0], 32); a2[1] += __shfl_xor(a2[1], 32);
  if (l < 32){
    sAl[w][0][0][l] = a0[0]; sAl[w][0][1][l] = a0[1];
    sAl[w][1][0][l] = a1[0]; sAl[w][1][1][l] = a1[1];
    sAl[w][2][0][l] = a2[0]; sAl[w][2][1][l] = a2[1];
  }
  __syncthreads();
  if (w == 0){
    int nt = l >> 5, colp = l & 31;
    int n = blk*64 + nt*32 + colp;
    if (n < N){
      float s0=0.f, s1=0.f, s2=0.f;
      #pragma unroll
      for (int q=0;q<4;++q){
        s0 += sAl[q][0][nt][colp];
        s1 += sAl[q][1][nt][colp];
        s2 += sAl[q][2][nt][colp];
      }
      float b0 = batt[0];
      if (initA){ aAp[n] = b0 + s0; aBp[n] = b0 + s1; aCp[n] = b0 + s2; }
      else      { aAp[n] += s0;     aBp[n] += s1;     aCp[n] += s2;     }
    }
  }
}

// ---------------- JK softmax + xjk + Wlin + Wfc1 + leaky ----------------
__global__ __launch_bounds__(256) void k_jk(const float* __restrict__ alpha,
                                            const float* __restrict__ h1, const float* __restrict__ h2,
                                            const float* __restrict__ h3,
                                            const float* __restrict__ Wlin, const float* __restrict__ blin,
                                            const float* __restrict__ Wfc1, const float* __restrict__ bfc1,
                                            float* __restrict__ vout, int N){
  __shared__ float sWl[64*65];
  __shared__ float sX[4][64];
  __shared__ float sR[4][64];
  int tid = threadIdx.x;
  for (int idx = tid; idx < 1024; idx += 256){
    int j = idx >> 4;
    int c4 = (idx & 15) << 2;
    float4 v = *(const float4*)(Wlin + (size_t)j*64 + c4);
    sWl[j*65 + c4+0] = v.x; sWl[j*65 + c4+1] = v.y;
    sWl[j*65 + c4+2] = v.z; sWl[j*65 + c4+3] = v.w;
  }
  int ln = tid >> 6, j = tid & 63;
  int n = blockIdx.x*4 + ln;
  bool ok = n < N;
  float xj = 0.f;
  if (ok){
    float a0 = alpha[n], a1 = alpha[(size_t)N + n], a2 = alpha[(size_t)2*N + n];
    float m = fmaxf(a0, fmaxf(a1, a2));
    float e0 = __expf(a0-m), e1 = __expf(a1-m), e2 = __expf(a2-m);
    float inv = __builtin_amdgcn_rcpf(e0+e1+e2);
    float w0 = e0*inv, w1 = e1*inv, w2 = e2*inv;
    xj = w0*h1[(size_t)n*64 + j] + w1*h2[(size_t)n*64 + j] + w2*h3[(size_t)n*64 + j];
  }
  sX[ln][j] = xj;
  __syncthreads();
  float acc = blin[j];
  #pragma unroll 8
  for (int c = 0; c < 64; ++c) acc = fmaf(sX[ln][c], sWl[j*65 + c], acc);
  sR[ln][j] = acc * Wfc1[j];
  __syncthreads();
  #pragma unroll
  for (int off = 32; off > 0; off >>= 1){
    if (j < off) sR[ln][j] += sR[ln][j + off];
    __syncthreads();
  }
  if (j == 0 && ok){
    float vv = sR[ln][0] + bfc1[0];
    vout[n] = vv >= 0.f ? vv : 0.01f*vv;
  }
}

// ---------------- final dot (deterministic two-stage, f64 accum) ----------------
__global__ __launch_bounds__(256) void k_final1(const float* __restrict__ w, const float* __restrict__ v,
                                                double* __restrict__ part, int N){
  __shared__ double sd[256];
  int tid = threadIdx.x;
  double a = 0.0;
  for (int i = blockIdx.x*256 + tid; i < N; i += 256*256)
    a += (double)(w[i] * v[i]);
  sd[tid] = a; __syncthreads();
  for (int off = 128; off > 0; off >>= 1){
    if (tid < off) sd[tid] += sd[tid + off];
    __syncthreads();
  }
  if (tid == 0) part[blockIdx.x] = sd[0];
}

__global__ __launch_bounds__(256) void k_final2(const double* __restrict__ part, const float* __restrict__ bfc2,
                                                float* __restrict__ out){
  __shared__ double sd[256];
  int tid = threadIdx.x;
  sd[tid] = part[tid]; __syncthreads();
  for (int off = 128; off > 0; off >>= 1){
    if (tid < off) sd[tid] += sd[tid + off];
    __syncthreads();
  }
  if (tid == 0) out[0] = (float)(sd[0] + (double)bfc2[0]);
}

// ---------------- host ----------------
extern "C" void kernel_launch(void* const* d_in, const int* in_sizes, int n_in,
                              void* d_out, int out_size, void* d_ws, size_t ws_size,
                              hipStream_t stream){
  const float* x    = (const float*)d_in[0];
  const int*   ei   = (const int*)d_in[1];
  const float* W0a  = (const float*)d_in[2];
  const float* b0a  = (const float*)d_in[3];
  const float* W0b  = (const float*)d_in[4];
  const float* b0b  = (const float*)d_in[5];
  const float* W1a  = (const float*)d_in[6];
  const float* b1a  = (const float*)d_in[7];
  const float* W1b  = (const float*)d_in[8];
  const float* b1b  = (const float*)d_in[9];
  const float* W2a  = (const float*)d_in[10];
  const float* b2a  = (const float*)d_in[11];
  const float* W2b  = (const float*)d_in[12];
  const float* b2b  = (const float*)d_in[13];
  const float* Wih_f = (const float*)d_in[14];
  const float* Whh_f = (const float*)d_in[15];
  const float* bih_f = (const float*)d_in[16];
  const float* bhh_f = (const float*)d_in[17];
  const float* Wih_b = (const float*)d_in[18];
  const float* Whh_b = (const float*)d_in[19];
  const float* bih_b = (const float*)d_in[20];
  const float* bhh_b = (const float*)d_in[21];
  const float* Watt = (const float*)d_in[22];
  const float* batt = (const float*)d_in[23];
  const float* Wlin = (const float*)d_in[24];
  const float* blin = (const float*)d_in[25];
  const float* Wfc1 = (const float*)d_in[26];
  const float* bfc1 = (const float*)d_in[27];
  const float* Wfc2 = (const float*)d_in[28];
  const float* bfc2 = (const float*)d_in[29];
  float* out = (float*)d_out;

  const int N = in_sizes[0] / 128;
  const int E = in_sizes[1] / 2;
  const int* src = ei;
  const int* dst = ei + E;

  uint8_t* w8 = (uint8_t*)d_ws;
  size_t off = 0;
  auto alloc = [&](size_t bytes) -> void* {
    void* p = w8 + off;
    off = (off + bytes + 255) & ~(size_t)255;
    return p;
  };
  int*    deg    = (int*)   alloc((size_t)N*4);
  int*    fill   = (int*)   alloc((size_t)N*4);
  int*    indptr = (int*)   alloc(((size_t)N+1)*4);
  int*    col    = (int*)   alloc((size_t)E*4);
  int*    bsum   = (int*)   alloc(2048);
  int*    boffs  = (int*)   alloc(2048);
  float*  h1     = (float*) alloc((size_t)N*64*4);
  float*  h2     = (float*) alloc((size_t)N*64*4);
  float*  h3     = (float*) alloc((size_t)N*64*4);
  float*  alpha  = (float*) alloc((size_t)3*N*4);
  float*  vbuf   = (float*) alloc((size_t)N*4);
  double* part   = (double*)alloc(256*8);
  u16*    Wpf    = (u16*)   alloc((size_t)10*12*2*64*8*2);
  u16*    Wpb    = (u16*)   alloc((size_t)10*12*2*64*8*2);
  float4* Bpf    = (float4*)alloc((size_t)96*16);
  float4* Bpb    = (float4*)alloc((size_t)96*16);
  float*  P      = (float*) alloc((size_t)N*192*4);   // GIN phase scratch
  if (off > ws_size) return;
  float* zbuf = P;                      // GIN phase: z tile [N,128]
  float* mid  = P + (size_t)N*128;      // GIN phase: MLP intermediate [N,64]

  const size_t lds64  = 64  * 102 * 4;
  const size_t lds128 = 128 * 102 * 4;

  hipMemsetAsync(deg,  0, (size_t)N*4, stream);
  hipMemsetAsync(fill, 0, (size_t)N*4, stream);

  int gE = (E + 255) / 256;
  int nb1 = (N + 255) / 256;
  int gG = (N + 63) / 64;

  // weight prepack (independent of CSR)
  k_packWfrag<<<480, 256, 0, stream>>>(Wih_f, Whh_f, Wpf);
  k_packWfrag<<<480, 256, 0, stream>>>(Wih_b, Whh_b, Wpb);
  k_packB<<<1, 128, 0, stream>>>(bih_f, bhh_f, Bpf);
  k_packB<<<1, 128, 0, stream>>>(bih_b, bhh_b, Bpb);

  k_deg  <<<gE, 256, 0, stream>>>(dst, deg, E);
  k_scan1<<<nb1, 256, 0, stream>>>(deg, indptr, bsum, N);
  k_scan2<<<1, 512, 0, stream>>>(bsum, boffs, indptr, nb1, N);
  k_scan3<<<nb1, 256, 0, stream>>>(indptr, boffs, N);
  k_fill <<<gE, 256, 0, stream>>>(src, dst, indptr, fill, col, E);

  // ---- GIN layer 0 (F=128) ----
  k_agg<128><<<(N+7)/8, 256, 0, stream>>>(x, indptr, col, zbuf, N);
  k_gemm<<<gG, TPB, lds128, stream>>>(zbuf, W0a, b0a, mid, 128, 64, 1, N);
  k_gemm<<<gG, TPB, lds64,  stream>>>(mid,  W0b, b0b, h1,  64,  64, 1, N);
  // ---- GIN layer 1 ----
  k_agg<64><<<(N+15)/16, 256, 0, stream>>>(h1, indptr, col, zbuf, N);
  k_gemm<<<gG, TPB, lds64, stream>>>(zbuf, W1a, b1a, mid, 64, 64, 1, N);
  k_gemm<<<gG, TPB, lds64, stream>>>(mid,  W1b, b1b, h2,  64, 64, 1, N);
  // ---- GIN layer 2 ----
  k_agg<64><<<(N+15)/16, 256, 0, stream>>>(h2, indptr, col, zbuf, N);
  k_gemm<<<gG, TPB, lds64, stream>>>(zbuf, W2a, b2a, mid, 64, 64, 1, N);
  k_gemm<<<gG, TPB, lds64, stream>>>(mid,  W2b, b2b, h3,  64, 64, 1, N);

  // ---- LSTM: one MFMA kernel per direction ----
  k_lstm_mfma<<<gG, 256, 0, stream>>>(h1, h2, h3, Wpf, Bpf, Watt, batt,
                                      alpha, alpha + (size_t)N, alpha + (size_t)2*N, 1, 0, N);
  k_lstm_mfma<<<gG, 256, 0, stream>>>(h3, h2, h1, Wpb, Bpb, Watt, batt,
                                      alpha + (size_t)2*N, alpha + (size_t)N, alpha, 0, 96, N);

  // ---- JK attention + linear + fc1 + leaky ----
  k_jk<<<(N+3)/4, 256, 0, stream>>>(alpha, h1, h2, h3, Wlin, blin, Wfc1, bfc1, vbuf, N);

  // ---- final dot ----
  k_final1<<<256, 256, 0, stream>>>(Wfc2, vbuf, part, N);
  k_final2<<<1, 256, 0, stream>>>(part, bfc2, out);
}

// Round 5
// 1015.130 us; speedup vs baseline: 4.0651x; 1.0517x over previous
//
#include <hip/hip_runtime.h>
#include <stdint.h>

#define TPB 128
typedef unsigned short u16;
typedef unsigned int u32;
using short8 = __attribute__((ext_vector_type(8))) short;
using f32x16 = __attribute__((ext_vector_type(16))) float;

__device__ __forceinline__ float sigf(float x){
  return __builtin_amdgcn_rcpf(1.0f + __expf(-x));
}
__device__ __forceinline__ float tanh_f(float x){
  return 1.0f - 2.0f*__builtin_amdgcn_rcpf(1.0f + __expf(2.0f*x));
}
__device__ __forceinline__ u16 f2bf(float f){
  u32 u = __float_as_uint(f);
  u += 0x7FFFu + ((u>>16)&1u);
  return (u16)(u>>16);
}
__device__ __forceinline__ float bf2f(u16 h){ return __uint_as_float(((u32)h)<<16); }

// ---------------- CSR build ----------------
__global__ void k_deg(const int* __restrict__ dst, int* __restrict__ deg, int E){
  int i = blockIdx.x*256 + threadIdx.x;
  if (i < E) atomicAdd(&deg[dst[i]], 1);
}

__global__ __launch_bounds__(256) void k_scan1(const int* __restrict__ deg, int* __restrict__ indptr,
                                               int* __restrict__ bsum, int N){
  __shared__ int s[256];
  int tid = threadIdx.x;
  int i = blockIdx.x*256 + tid;
  int v = (i < N) ? deg[i] : 0;
  s[tid] = v; __syncthreads();
  for (int off=1; off<256; off<<=1){
    int t = (tid>=off) ? s[tid-off] : 0;
    __syncthreads();
    s[tid] += t;
    __syncthreads();
  }
  if (i < N) indptr[i] = s[tid] - v;      // block-local exclusive
  if (tid == 255) bsum[blockIdx.x] = s[255];
}

__global__ __launch_bounds__(512) void k_scan2(const int* __restrict__ bsum, int* __restrict__ boffs,
                                               int* __restrict__ indptr, int nb, int N){
  __shared__ int s[512];
  int tid = threadIdx.x;
  int v = (tid < nb) ? bsum[tid] : 0;
  s[tid] = v; __syncthreads();
  for (int off=1; off<512; off<<=1){
    int t = (tid>=off) ? s[tid-off] : 0;
    __syncthreads();
    s[tid] += t;
    __syncthreads();
  }
  boffs[tid] = s[tid] - v;
  if (tid == nb-1) indptr[N] = s[tid];
}

__global__ __launch_bounds__(256) void k_scan3(int* __restrict__ indptr, const int* __restrict__ boffs, int N){
  int i = blockIdx.x*256 + threadIdx.x;
  if (i < N) indptr[i] += boffs[blockIdx.x];
}

__global__ void k_fill(const int* __restrict__ src, const int* __restrict__ dst,
                       const int* __restrict__ indptr, int* __restrict__ fill,
                       int* __restrict__ col, int E){
  int i = blockIdx.x*256 + threadIdx.x;
  if (i < E){
    int d = dst[i];
    int r = atomicAdd(&fill[d], 1);
    col[indptr[d] + r] = src[i];
  }
}

// ---------------- aggregation: z[n] = relu( y[n] + sum_{nbr} y[src] + bias ) ----------------
template<int F>
__global__ __launch_bounds__(256) void k_agg(const float* __restrict__ y, const int* __restrict__ indptr,
                                             const int* __restrict__ col, const float* __restrict__ bias,
                                             float* __restrict__ z, int N){
  constexpr int TPN = F/4;          // threads per node
  constexpr int NPB = 256/TPN;      // nodes per block
  int n = blockIdx.x*NPB + threadIdx.x/TPN;
  int lane = threadIdx.x % TPN;
  if (n >= N) return;
  const float4* hv = (const float4*)y;
  float4 acc = hv[(size_t)n*TPN + lane];
  int s = indptr[n], e = indptr[n+1];
  for (int p = s; p < e; ++p){
    int c = col[p];
    float4 x = hv[(size_t)c*TPN + lane];
    acc.x += x.x; acc.y += x.y; acc.z += x.z; acc.w += x.w;
  }
  float4 b4 = ((const float4*)bias)[lane];
  acc.x = fmaxf(acc.x + b4.x, 0.f);
  acc.y = fmaxf(acc.y + b4.y, 0.f);
  acc.z = fmaxf(acc.z + b4.z, 0.f);
  acc.w = fmaxf(acc.w + b4.w, 0.f);
  ((float4*)z)[(size_t)n*TPN + lane] = acc;
}

// ---------------- generic f32 GEMM: out[n][j] = act(sum_k A[n][k]*W[j][k] + b[j]) ----------------
__global__ __launch_bounds__(TPB) void k_gemm(const float* __restrict__ A, const float* __restrict__ W,
                                              const float* __restrict__ bias, float* __restrict__ out,
                                              int K, int JC, int act, int N){
  extern __shared__ float sm[];
  float* As = sm;                       // [K][68]
  float* Ws = sm + (size_t)K*68;        // [K][34]
  const int tid = threadIdx.x;
  const int tx = tid & 15, ty = tid >> 4;
  const int nb = blockIdx.x * 64;
  const int kq = K >> 2;
  for (int it = 0, idx = tid; it < (kq >> 1); ++it, idx += TPB){
    int nl = idx & 63, kk = idx >> 6;
    int k4 = kk << 2;
    int n = nb + nl;
    float4 v = make_float4(0.f,0.f,0.f,0.f);
    if (n < N) v = *(const float4*)(A + (size_t)n*K + k4);
    As[(size_t)(k4+0)*68 + nl] = v.x;
    As[(size_t)(k4+1)*68 + nl] = v.y;
    As[(size_t)(k4+2)*68 + nl] = v.z;
    As[(size_t)(k4+3)*68 + nl] = v.w;
  }
  const int ncc = JC >> 5;
  for (int cc = 0; cc < ncc; ++cc){
    __syncthreads();
    for (int it = 0, idx = tid; it < (kq >> 2); ++it, idx += TPB){
      int cl = idx & 31, kk = idx >> 5;
      int k4 = kk << 2;
      int j = (cc << 5) + cl;
      float4 v = *(const float4*)(W + (size_t)j*K + k4);
      Ws[(size_t)(k4+0)*34 + cl] = v.x;
      Ws[(size_t)(k4+1)*34 + cl] = v.y;
      Ws[(size_t)(k4+2)*34 + cl] = v.z;
      Ws[(size_t)(k4+3)*34 + cl] = v.w;
    }
    __syncthreads();
    float4 acc0 = make_float4(0,0,0,0), acc1 = acc0, acc2 = acc0, acc3 = acc0;
    #pragma unroll 4
    for (int k = 0; k < K; ++k){
      float4 a = *(const float4*)(As + (size_t)k*68 + (tx<<2));
      float2 w01 = *(const float2*)(Ws + (size_t)k*34 + (ty<<2));
      float2 w23 = *(const float2*)(Ws + (size_t)k*34 + (ty<<2) + 2);
      acc0.x = fmaf(a.x, w01.x, acc0.x); acc0.y = fmaf(a.x, w01.y, acc0.y);
      acc0.z = fmaf(a.x, w23.x, acc0.z); acc0.w = fmaf(a.x, w23.y, acc0.w);
      acc1.x = fmaf(a.y, w01.x, acc1.x); acc1.y = fmaf(a.y, w01.y, acc1.y);
      acc1.z = fmaf(a.y, w23.x, acc1.z); acc1.w = fmaf(a.y, w23.y, acc1.w);
      acc2.x = fmaf(a.z, w01.x, acc2.x); acc2.y = fmaf(a.z, w01.y, acc2.y);
      acc2.z = fmaf(a.z, w23.x, acc2.z); acc2.w = fmaf(a.z, w23.y, acc2.w);
      acc3.x = fmaf(a.w, w01.x, acc3.x); acc3.y = fmaf(a.w, w01.y, acc3.y);
      acc3.z = fmaf(a.w, w23.x, acc3.z); acc3.w = fmaf(a.w, w23.y, acc3.w);
    }
    int j0 = (cc << 5) + (ty << 2);
    float4 b4 = make_float4(0,0,0,0);
    if (bias) b4 = *(const float4*)(bias + j0);
    float4 r[4] = {acc0, acc1, acc2, acc3};
    #pragma unroll
    for (int i = 0; i < 4; ++i){
      int n = nb + (tx<<2) + i;
      if (n < N){
        float4 o;
        o.x = r[i].x + b4.x; o.y = r[i].y + b4.y; o.z = r[i].z + b4.z; o.w = r[i].w + b4.w;
        if (act){
          o.x = fmaxf(o.x, 0.f); o.y = fmaxf(o.y, 0.f);
          o.z = fmaxf(o.z, 0.f); o.w = fmaxf(o.w, 0.f);
        }
        *(float4*)(out + (size_t)n*JC + j0) = o;
      }
    }
  }
}

// ---------------- LSTM weight prepack: fragment-linear bf16 hi/lo planes ----------------
// Frag layout for mfma_f32_32x32x16_bf16 A-operand: lane l holds A[row=l&31][k=kt*16+(l>>5)*8+i].
// Row r = rt*32 + (l&31); r = 4*j + g (gate-interleaved); orig row = g*96 + j.
// Wp index = (((kt*12 + rt)*2 + p)*64 + l)*8 + i  (p: 0=hi, 1=lo residual)
__global__ __launch_bounds__(256) void k_packWfrag(const float* __restrict__ Wih, const float* __restrict__ Whh,
                                                   u16* __restrict__ Wp){
  int idx = blockIdx.x*256 + threadIdx.x;
  if (idx >= 10*12*2*64*8) return;
  int i  = idx & 7;
  int l  = (idx>>3) & 63;
  int p  = (idx>>9) & 1;
  int rt = (idx>>10) % 12;
  int kt = (idx>>10) / 12;
  int r  = rt*32 + (l & 31);
  int j  = r >> 2, g = r & 3;
  int row = g*96 + j;
  int k  = kt*16 + ((l>>5)<<3) + i;
  float v = (k < 64) ? Wih[row*64 + k] : Whh[row*96 + (k-64)];
  u16 h = f2bf(v);
  Wp[idx] = p ? f2bf(v - bf2f(h)) : h;
}

__global__ __launch_bounds__(128) void k_packB(const float* __restrict__ bih, const float* __restrict__ bhh,
                                               float4* __restrict__ Bp){
  int j = blockIdx.x*128 + threadIdx.x;
  if (j >= 96) return;
  Bp[j] = make_float4(bih[j]+bhh[j], bih[96+j]+bhh[96+j],
                      bih[192+j]+bhh[192+j], bih[288+j]+bhh[288+j]);
}

// ---------------- MFMA LSTM v2: 512 threads, 8 waves, wave = (rtg 0..3) x (nt 0..1) ----------------
// Each wave: 3 row-tiles (rt = rtg*3+ti) x 1 node-tile -> acc 3x16 f32, c[12] in regs.
// X = [x(64) | h(96)] bf16 hi/lo planes in LDS [64][192] with 16B-chunk XOR swizzle
// (chunk ^= row&7) -> balanced banks. W streamed frag-linear from L2.

__device__ __forceinline__ void stage_x2(const float* __restrict__ seq,
                                         u16 (*Xhi)[192], u16 (*Xlo)[192],
                                         int blk, int N, int tid){
  int node = tid >> 3;         // 0..63
  int kc = tid & 7;            // 16B chunk 0..7 (k = kc*8 .. +7)
  int n = blk*64 + node;
  float v[8];
  if (n < N){
    const float4* s4 = (const float4*)(seq + (size_t)n*64 + kc*8);
    float4 a = s4[0], b = s4[1];
    v[0]=a.x; v[1]=a.y; v[2]=a.z; v[3]=a.w; v[4]=b.x; v[5]=b.y; v[6]=b.z; v[7]=b.w;
  } else {
    #pragma unroll
    for (int i=0;i<8;++i) v[i]=0.f;
  }
  u32 hw[4], lw[4];
  #pragma unroll
  for (int i=0;i<4;++i){
    u16 h0=f2bf(v[2*i]),   h1=f2bf(v[2*i+1]);
    u16 l0=f2bf(v[2*i]-bf2f(h0)), l1=f2bf(v[2*i+1]-bf2f(h1));
    hw[i]= (u32)h0 | ((u32)h1<<16);
    lw[i]= (u32)l0 | ((u32)l1<<16);
  }
  int sc = kc ^ (node & 7);
  *(uint4*)((char*)&Xhi[node][0] + (sc<<4)) = make_uint4(hw[0],hw[1],hw[2],hw[3]);
  *(uint4*)((char*)&Xlo[node][0] + (sc<<4)) = make_uint4(lw[0],lw[1],lw[2],lw[3]);
}

template<int FIRST>
__device__ __forceinline__ void lstm_step2(const u16* __restrict__ Wp,
    const float4* __restrict__ Bp, const float* __restrict__ WattW,
    u16 (*Xhi)[192], u16 (*Xlo)[192],
    float (&c)[12], float &aP, int rtg, int nt, int l)
{
  constexpr int NKT = FIRST ? 4 : 10;   // k-tiles of 16 (first step: h is zero, K=64)
  const int hi = l >> 5;
  const int row = nt*32 + (l & 31);
  f32x16 acc[3];
  #pragma unroll
  for (int t=0;t<3;++t)
    #pragma unroll
    for (int r=0;r<16;++r) acc[t][r] = 0.f;

  auto ldA = [&](int kt, int ti, int p)->short8{
    const u16* ptr = Wp + ((((size_t)kt*12 + (rtg*3+ti))*2 + p)<<9) + ((size_t)l<<3);
    return *(const short8*)ptr;
  };
  auto ldB = [&](u16 (*X)[192], int kt)->short8{
    int chunk = kt*2 + hi;
    int sw = (chunk & ~7) | ((chunk ^ row) & 7);
    return *(const short8*)((const char*)&X[row][0] + (sw<<4));
  };
  auto MM = [&](short8 (&A)[3][2], short8 (&B)[2]){
    #pragma unroll
    for (int ti=0;ti<3;++ti)
      acc[ti] = __builtin_amdgcn_mfma_f32_32x32x16_bf16(A[ti][0], B[0], acc[ti], 0, 0, 0);
    #pragma unroll
    for (int ti=0;ti<3;++ti)
      acc[ti] = __builtin_amdgcn_mfma_f32_32x32x16_bf16(A[ti][0], B[1], acc[ti], 0, 0, 0);
    #pragma unroll
    for (int ti=0;ti<3;++ti)
      acc[ti] = __builtin_amdgcn_mfma_f32_32x32x16_bf16(A[ti][1], B[0], acc[ti], 0, 0, 0);
  };

  short8 Aa[3][2], Ab[3][2];
  short8 Ba[2], Bb[2];
  #pragma unroll
  for (int ti=0;ti<3;++ti){ Aa[ti][0]=ldA(0,ti,0); Aa[ti][1]=ldA(0,ti,1); }
  Ba[0] = ldB(Xhi,0); Ba[1] = ldB(Xlo,0);
  #pragma unroll
  for (int kt=0; kt<NKT; kt+=2){
    #pragma unroll
    for (int ti=0;ti<3;++ti){ Ab[ti][0]=ldA(kt+1,ti,0); Ab[ti][1]=ldA(kt+1,ti,1); }
    Bb[0] = ldB(Xhi,kt+1); Bb[1] = ldB(Xlo,kt+1);
    MM(Aa, Ba);
    if (kt+2 < NKT){
      #pragma unroll
      for (int ti=0;ti<3;++ti){ Aa[ti][0]=ldA(kt+2,ti,0); Aa[ti][1]=ldA(kt+2,ti,1); }
      Ba[0] = ldB(Xhi,kt+2); Ba[1] = ldB(Xlo,kt+2);
    }
    MM(Ab, Bb);
  }

  if (!FIRST) __syncthreads();   // all waves done reading X h-rows before overwriting

  #pragma unroll
  for (int ti=0;ti<3;++ti){
    #pragma unroll
    for (int rg=0; rg<4; ++rg){
      const int j = (rtg*3+ti)*8 + 2*rg + hi;
      float4 bv = Bp[j];
      float gi = acc[ti][rg*4+0] + bv.x;
      float gf = acc[ti][rg*4+1] + bv.y;
      float gg = acc[ti][rg*4+2] + bv.z;
      float go = acc[ti][rg*4+3] + bv.w;
      const int ci = ti*4 + rg;
      float cp = FIRST ? 0.f : c[ci];
      float cn = sigf(gf)*cp + sigf(gi)*tanh_f(gg);
      float hh = sigf(go)*tanh_f(cn);
      c[ci] = cn;
      aP = fmaf(hh, WattW[j], aP);
      // h writeback (swizzled u16)
      u16 hb = f2bf(hh);
      u16 lb = f2bf(hh - bf2f(hb));
      int byte = 128 + 2*j;
      int chunk = byte >> 4;
      int off = byte & 15;
      int sw = ((chunk & ~7) | ((chunk ^ row) & 7));
      *(u16*)((char*)&Xhi[row][0] + (sw<<4) + off) = hb;
      *(u16*)((char*)&Xlo[row][0] + (sw<<4) + off) = lb;
    }
  }
}

__global__ __launch_bounds__(512,2) void k_lstm_mfma(
    const float* __restrict__ sA, const float* __restrict__ sB, const float* __restrict__ sC,
    const u16* __restrict__ Wp, const float4* __restrict__ Bp,
    const float* __restrict__ Watt, const float* __restrict__ batt,
    float* __restrict__ aAp, float* __restrict__ aBp, float* __restrict__ aCp,
    int initA, int woff, int N)
{
  __shared__ u16 Xhi[64][192];
  __shared__ u16 Xlo[64][192];
  __shared__ float sAl[8][3][32];
  const int tid = threadIdx.x;
  const int l = tid & 63;
  const int w = __builtin_amdgcn_readfirstlane(tid >> 6);
  const int rtg = w >> 1;
  const int nt = w & 1;
  const int blk = blockIdx.x;
  const float* WattW = Watt + woff;
  float c[12];
  float a0 = 0.f, a1 = 0.f, a2 = 0.f;

  stage_x2(sA, Xhi, Xlo, blk, N, tid);
  __syncthreads();
  lstm_step2<1>(Wp, Bp, WattW, Xhi, Xlo, c, a0, rtg, nt, l);
  __syncthreads();
  stage_x2(sB, Xhi, Xlo, blk, N, tid);
  __syncthreads();
  lstm_step2<0>(Wp, Bp, WattW, Xhi, Xlo, c, a1, rtg, nt, l);
  __syncthreads();
  stage_x2(sC, Xhi, Xlo, blk, N, tid);
  __syncthreads();
  lstm_step2<0>(Wp, Bp, WattW, Xhi, Xlo, c, a2, rtg, nt, l);

  // alpha reduce: lanes l and l^32 hold the same node (different gate halves)
  a0 += __shfl_xor(a0, 32);
  a1 += __shfl_xor(a1, 32);
  a2 += __shfl_xor(a2, 32);
  if (l < 32){
    sAl[w][0][l] = a0;
    sAl[w][1][l] = a1;
    sAl[w][2][l] = a2;
  }
  __syncthreads();
  if (tid < 192){
    int s = tid >> 6;
    int node = tid & 63;
    int nt2 = node >> 5, colp = node & 31;
    int n = blk*64 + node;
    if (n < N){
      float sum = sAl[nt2][s][colp] + sAl[2+nt2][s][colp]
                + sAl[4+nt2][s][colp] + sAl[6+nt2][s][colp];
      float* ap = (s==0) ? aAp : (s==1) ? aBp : aCp;
      if (initA) ap[n] = batt[0] + sum;
      else       ap[n] += sum;
    }
  }
}

// ---------------- JK softmax + xjk + Wlin + Wfc1 + leaky ----------------
__global__ __launch_bounds__(256) void k_jk(const float* __restrict__ alpha,
                                            const float* __restrict__ h1, const float* __restrict__ h2,
                                            const float* __restrict__ h3,
                                            const float* __restrict__ Wlin, const float* __restrict__ blin,
                                            const float* __restrict__ Wfc1, const float* __restrict__ bfc1,
                                            float* __restrict__ vout, int N){
  __shared__ float sWl[64*65];
  __shared__ float sX[4][64];
  __shared__ float sR[4][64];
  int tid = threadIdx.x;
  for (int idx = tid; idx < 1024; idx += 256){
    int j = idx >> 4;
    int c4 = (idx & 15) << 2;
    float4 v = *(const float4*)(Wlin + (size_t)j*64 + c4);
    sWl[j*65 + c4+0] = v.x; sWl[j*65 + c4+1] = v.y;
    sWl[j*65 + c4+2] = v.z; sWl[j*65 + c4+3] = v.w;
  }
  int ln = tid >> 6, j = tid & 63;
  int n = blockIdx.x*4 + ln;
  bool ok = n < N;
  float xj = 0.f;
  if (ok){
    float a0 = alpha[n], a1 = alpha[(size_t)N + n], a2 = alpha[(size_t)2*N + n];
    float m = fmaxf(a0, fmaxf(a1, a2));
    float e0 = __expf(a0-m), e1 = __expf(a1-m), e2 = __expf(a2-m);
    float inv = __builtin_amdgcn_rcpf(e0+e1+e2);
    float w0 = e0*inv, w1 = e1*inv, w2 = e2*inv;
    xj = w0*h1[(size_t)n*64 + j] + w1*h2[(size_t)n*64 + j] + w2*h3[(size_t)n*64 + j];
  }
  sX[ln][j] = xj;
  __syncthreads();
  float acc = blin[j];
  #pragma unroll 8
  for (int c = 0; c < 64; ++c) acc = fmaf(sX[ln][c], sWl[j*65 + c], acc);
  sR[ln][j] = acc * Wfc1[j];
  __syncthreads();
  #pragma unroll
  for (int off = 32; off > 0; off >>= 1){
    if (j < off) sR[ln][j] += sR[ln][j + off];
    __syncthreads();
  }
  if (j == 0 && ok){
    float vv = sR[ln][0] + bfc1[0];
    vout[n] = vv >= 0.f ? vv : 0.01f*vv;
  }
}

// ---------------- final dot (deterministic two-stage, f64 accum) ----------------
__global__ __launch_bounds__(256) void k_final1(const float* __restrict__ w, const float* __restrict__ v,
                                                double* __restrict__ part, int N){
  __shared__ double sd[256];
  int tid = threadIdx.x;
  double a = 0.0;
  for (int i = blockIdx.x*256 + tid; i < N; i += 256*256)
    a += (double)(w[i] * v[i]);
  sd[tid] = a; __syncthreads();
  for (int off = 128; off > 0; off >>= 1){
    if (tid < off) sd[tid] += sd[tid + off];
    __syncthreads();
  }
  if (tid == 0) part[blockIdx.x] = sd[0];
}

__global__ __launch_bounds__(256) void k_final2(const double* __restrict__ part, const float* __restrict__ bfc2,
                                                float* __restrict__ out){
  __shared__ double sd[256];
  int tid = threadIdx.x;
  sd[tid] = part[tid]; __syncthreads();
  for (int off = 128; off > 0; off >>= 1){
    if (tid < off) sd[tid] += sd[tid + off];
    __syncthreads();
  }
  if (tid == 0) out[0] = (float)(sd[0] + (double)bfc2[0]);
}

// ---------------- host ----------------
extern "C" void kernel_launch(void* const* d_in, const int* in_sizes, int n_in,
                              void* d_out, int out_size, void* d_ws, size_t ws_size,
                              hipStream_t stream){
  const float* x    = (const float*)d_in[0];
  const int*   ei   = (const int*)d_in[1];
  const float* W0a  = (const float*)d_in[2];
  const float* b0a  = (const float*)d_in[3];
  const float* W0b  = (const float*)d_in[4];
  const float* b0b  = (const float*)d_in[5];
  const float* W1a  = (const float*)d_in[6];
  const float* b1a  = (const float*)d_in[7];
  const float* W1b  = (const float*)d_in[8];
  const float* b1b  = (const float*)d_in[9];
  const float* W2a  = (const float*)d_in[10];
  const float* b2a  = (const float*)d_in[11];
  const float* W2b  = (const float*)d_in[12];
  const float* b2b  = (const float*)d_in[13];
  const float* Wih_f = (const float*)d_in[14];
  const float* Whh_f = (const float*)d_in[15];
  const float* bih_f = (const float*)d_in[16];
  const float* bhh_f = (const float*)d_in[17];
  const float* Wih_b = (const float*)d_in[18];
  const float* Whh_b = (const float*)d_in[19];
  const float* bih_b = (const float*)d_in[20];
  const float* bhh_b = (const float*)d_in[21];
  const float* Watt = (const float*)d_in[22];
  const float* batt = (const float*)d_in[23];
  const float* Wlin = (const float*)d_in[24];
  const float* blin = (const float*)d_in[25];
  const float* Wfc1 = (const float*)d_in[26];
  const float* bfc1 = (const float*)d_in[27];
  const float* Wfc2 = (const float*)d_in[28];
  const float* bfc2 = (const float*)d_in[29];
  float* out = (float*)d_out;

  const int N = in_sizes[0] / 128;
  const int E = in_sizes[1] / 2;
  const int* src = ei;
  const int* dst = ei + E;

  uint8_t* w8 = (uint8_t*)d_ws;
  size_t off = 0;
  auto alloc = [&](size_t bytes) -> void* {
    void* p = w8 + off;
    off = (off + bytes + 255) & ~(size_t)255;
    return p;
  };
  int*    deg    = (int*)   alloc((size_t)N*4);
  int*    fill   = (int*)   alloc((size_t)N*4);
  int*    indptr = (int*)   alloc(((size_t)N+1)*4);
  int*    col    = (int*)   alloc((size_t)E*4);
  int*    bsum   = (int*)   alloc(2048);
  int*    boffs  = (int*)   alloc(2048);
  float*  h1     = (float*) alloc((size_t)N*64*4);
  float*  h2     = (float*) alloc((size_t)N*64*4);
  float*  h3     = (float*) alloc((size_t)N*64*4);
  float*  alpha  = (float*) alloc((size_t)3*N*4);
  float*  vbuf   = (float*) alloc((size_t)N*4);
  double* part   = (double*)alloc(256*8);
  u16*    Wpf    = (u16*)   alloc((size_t)10*12*2*64*8*2);
  u16*    Wpb    = (u16*)   alloc((size_t)10*12*2*64*8*2);
  float4* Bpf    = (float4*)alloc((size_t)96*16);
  float4* Bpb    = (float4*)alloc((size_t)96*16);
  float*  P      = (float*) alloc((size_t)N*192*4);   // GIN phase scratch
  if (off > ws_size) return;
  float* ybuf = P;                      // transform output [N,64]
  float* zbuf = P + (size_t)N*64;       // agg+bias+relu output [N,64]

  const size_t lds64  = 64  * 102 * 4;
  const size_t lds128 = 128 * 102 * 4;

  hipMemsetAsync(deg,  0, (size_t)N*4, stream);
  hipMemsetAsync(fill, 0, (size_t)N*4, stream);

  int gE = (E + 255) / 256;
  int nb1 = (N + 255) / 256;
  int gG = (N + 63) / 64;
  int gA = (N + 15) / 16;

  // weight prepack (independent of CSR)
  k_packWfrag<<<480, 256, 0, stream>>>(Wih_f, Whh_f, Wpf);
  k_packWfrag<<<480, 256, 0, stream>>>(Wih_b, Whh_b, Wpb);
  k_packB<<<1, 128, 0, stream>>>(bih_f, bhh_f, Bpf);
  k_packB<<<1, 128, 0, stream>>>(bih_b, bhh_b, Bpb);

  k_deg  <<<gE, 256, 0, stream>>>(dst, deg, E);
  k_scan1<<<nb1, 256, 0, stream>>>(deg, indptr, bsum, N);
  k_scan2<<<1, 512, 0, stream>>>(bsum, boffs, indptr, nb1, N);
  k_scan3<<<nb1, 256, 0, stream>>>(indptr, boffs, N);
  k_fill <<<gE, 256, 0, stream>>>(src, dst, indptr, fill, col, E);

  // ---- GIN layer 0 (transform-first: (x+aggX)@W = y+aggY) ----
  k_gemm<<<gG, TPB, lds128, stream>>>(x, W0a, nullptr, ybuf, 128, 64, 0, N);
  k_agg<64><<<gA, 256, 0, stream>>>(ybuf, indptr, col, b0a, zbuf, N);
  k_gemm<<<gG, TPB, lds64, stream>>>(zbuf, W0b, b0b, h1, 64, 64, 1, N);
  // ---- GIN layer 1 ----
  k_gemm<<<gG, TPB, lds64, stream>>>(h1, W1a, nullptr, ybuf, 64, 64, 0, N);
  k_agg<64><<<gA, 256, 0, stream>>>(ybuf, indptr, col, b1a, zbuf, N);
  k_gemm<<<gG, TPB, lds64, stream>>>(zbuf, W1b, b1b, h2, 64, 64, 1, N);
  // ---- GIN layer 2 ----
  k_gemm<<<gG, TPB, lds64, stream>>>(h2, W2a, nullptr, ybuf, 64, 64, 0, N);
  k_agg<64><<<gA, 256, 0, stream>>>(ybuf, indptr, col, b2a, zbuf, N);
  k_gemm<<<gG, TPB, lds64, stream>>>(zbuf, W2b, b2b, h3, 64, 64, 1, N);

  // ---- LSTM: one MFMA kernel per direction ----
  k_lstm_mfma<<<gG, 512, 0, stream>>>(h1, h2, h3, Wpf, Bpf, Watt, batt,
                                      alpha, alpha + (size_t)N, alpha + (size_t)2*N, 1, 0, N);
  k_lstm_mfma<<<gG, 512, 0, stream>>>(h3, h2, h1, Wpb, Bpb, Watt, batt,
                                      alpha + (size_t)2*N, alpha + (size_t)N, alpha, 0, 96, N);

  // ---- JK attention + linear + fc1 + leaky ----
  k_jk<<<(N+3)/4, 256, 0, stream>>>(alpha, h1, h2, h3, Wlin, blin, Wfc1, bfc1, vbuf, N);

  // ---- final dot ----
  k_final1<<<256, 256, 0, stream>>>(Wfc2, vbuf, part, N);
  k_final2<<<1, 256, 0, stream>>>(part, bfc2, out);
}

// Round 6
// 909.111 us; speedup vs baseline: 4.5392x; 1.1166x over previous
//
#include <hip/hip_runtime.h>
#include <stdint.h>

#define TPB 128
typedef unsigned short u16;
typedef unsigned int u32;
using short8 = __attribute__((ext_vector_type(8))) short;
using f32x16 = __attribute__((ext_vector_type(16))) float;

__device__ __forceinline__ float sigf(float x){
  return __builtin_amdgcn_rcpf(1.0f + __expf(-x));
}
__device__ __forceinline__ float tanh_f(float x){
  return 1.0f - 2.0f*__builtin_amdgcn_rcpf(1.0f + __expf(2.0f*x));
}
__device__ __forceinline__ u16 f2bf(float f){
  u32 u = __float_as_uint(f);
  u += 0x7FFFu + ((u>>16)&1u);
  return (u16)(u>>16);
}
__device__ __forceinline__ float bf2f(u16 h){ return __uint_as_float(((u32)h)<<16); }

// ---------------- CSR build ----------------
__global__ void k_deg(const int* __restrict__ dst, int* __restrict__ deg, int E){
  int i = blockIdx.x*256 + threadIdx.x;
  if (i < E) atomicAdd(&deg[dst[i]], 1);
}

__global__ __launch_bounds__(256) void k_scan1(const int* __restrict__ deg, int* __restrict__ indptr,
                                               int* __restrict__ bsum, int N){
  __shared__ int s[256];
  int tid = threadIdx.x;
  int i = blockIdx.x*256 + tid;
  int v = (i < N) ? deg[i] : 0;
  s[tid] = v; __syncthreads();
  for (int off=1; off<256; off<<=1){
    int t = (tid>=off) ? s[tid-off] : 0;
    __syncthreads();
    s[tid] += t;
    __syncthreads();
  }
  if (i < N) indptr[i] = s[tid] - v;
  if (tid == 255) bsum[blockIdx.x] = s[255];
}

__global__ __launch_bounds__(512) void k_scan2(const int* __restrict__ bsum, int* __restrict__ boffs,
                                               int* __restrict__ indptr, int nb, int N){
  __shared__ int s[512];
  int tid = threadIdx.x;
  int v = (tid < nb) ? bsum[tid] : 0;
  s[tid] = v; __syncthreads();
  for (int off=1; off<512; off<<=1){
    int t = (tid>=off) ? s[tid-off] : 0;
    __syncthreads();
    s[tid] += t;
    __syncthreads();
  }
  boffs[tid] = s[tid] - v;
  if (tid == nb-1) indptr[N] = s[tid];
}

__global__ __launch_bounds__(256) void k_scan3(int* __restrict__ indptr, const int* __restrict__ boffs, int N){
  int i = blockIdx.x*256 + threadIdx.x;
  if (i < N) indptr[i] += boffs[blockIdx.x];
}

__global__ void k_fill(const int* __restrict__ src, const int* __restrict__ dst,
                       const int* __restrict__ indptr, int* __restrict__ fill,
                       int* __restrict__ col, int E){
  int i = blockIdx.x*256 + threadIdx.x;
  if (i < E){
    int d = dst[i];
    int r = atomicAdd(&fill[d], 1);
    col[indptr[d] + r] = src[i];
  }
}

// ---------------- aggregation: z[n] = relu( y[n] + sum_{nbr} y[src] + bias ) ----------------
template<int F>
__global__ __launch_bounds__(256) void k_agg(const float* __restrict__ y, const int* __restrict__ indptr,
                                             const int* __restrict__ col, const float* __restrict__ bias,
                                             float* __restrict__ z, int N){
  constexpr int TPN = F/4;
  constexpr int NPB = 256/TPN;
  int n = blockIdx.x*NPB + threadIdx.x/TPN;
  int lane = threadIdx.x % TPN;
  if (n >= N) return;
  const float4* hv = (const float4*)y;
  float4 acc = hv[(size_t)n*TPN + lane];
  int s = indptr[n], e = indptr[n+1];
  int p = s;
  for (; p + 8 <= e; p += 8){
    int c8[8];
    #pragma unroll
    for (int i=0;i<8;++i) c8[i] = col[p+i];
    #pragma unroll
    for (int i=0;i<8;++i){
      float4 x = hv[(size_t)c8[i]*TPN + lane];
      acc.x += x.x; acc.y += x.y; acc.z += x.z; acc.w += x.w;
    }
  }
  for (; p < e; ++p){
    float4 x = hv[(size_t)col[p]*TPN + lane];
    acc.x += x.x; acc.y += x.y; acc.z += x.z; acc.w += x.w;
  }
  float4 b4 = ((const float4*)bias)[lane];
  acc.x = fmaxf(acc.x + b4.x, 0.f);
  acc.y = fmaxf(acc.y + b4.y, 0.f);
  acc.z = fmaxf(acc.z + b4.z, 0.f);
  acc.w = fmaxf(acc.w + b4.w, 0.f);
  ((float4*)z)[(size_t)n*TPN + lane] = acc;
}

// ---------------- generic f32 GEMM: out[n][j] = act(sum_k A[n][k]*W[j][k] + b[j]) ----------------
__global__ __launch_bounds__(TPB) void k_gemm(const float* __restrict__ A, const float* __restrict__ W,
                                              const float* __restrict__ bias, float* __restrict__ out,
                                              int K, int JC, int act, int N){
  extern __shared__ float sm[];
  float* As = sm;                       // [K][68]
  float* Ws = sm + (size_t)K*68;        // [K][34]
  const int tid = threadIdx.x;
  const int tx = tid & 15, ty = tid >> 4;
  const int nb = blockIdx.x * 64;
  const int kq = K >> 2;
  for (int it = 0, idx = tid; it < (kq >> 1); ++it, idx += TPB){
    int nl = idx & 63, kk = idx >> 6;
    int k4 = kk << 2;
    int n = nb + nl;
    float4 v = make_float4(0.f,0.f,0.f,0.f);
    if (n < N) v = *(const float4*)(A + (size_t)n*K + k4);
    As[(size_t)(k4+0)*68 + nl] = v.x;
    As[(size_t)(k4+1)*68 + nl] = v.y;
    As[(size_t)(k4+2)*68 + nl] = v.z;
    As[(size_t)(k4+3)*68 + nl] = v.w;
  }
  const int ncc = JC >> 5;
  for (int cc = 0; cc < ncc; ++cc){
    __syncthreads();
    for (int it = 0, idx = tid; it < (kq >> 2); ++it, idx += TPB){
      int cl = idx & 31, kk = idx >> 5;
      int k4 = kk << 2;
      int j = (cc << 5) + cl;
      float4 v = *(const float4*)(W + (size_t)j*K + k4);
      Ws[(size_t)(k4+0)*34 + cl] = v.x;
      Ws[(size_t)(k4+1)*34 + cl] = v.y;
      Ws[(size_t)(k4+2)*34 + cl] = v.z;
      Ws[(size_t)(k4+3)*34 + cl] = v.w;
    }
    __syncthreads();
    float4 acc0 = make_float4(0,0,0,0), acc1 = acc0, acc2 = acc0, acc3 = acc0;
    #pragma unroll 4
    for (int k = 0; k < K; ++k){
      float4 a = *(const float4*)(As + (size_t)k*68 + (tx<<2));
      float2 w01 = *(const float2*)(Ws + (size_t)k*34 + (ty<<2));
      float2 w23 = *(const float2*)(Ws + (size_t)k*34 + (ty<<2) + 2);
      acc0.x = fmaf(a.x, w01.x, acc0.x); acc0.y = fmaf(a.x, w01.y, acc0.y);
      acc0.z = fmaf(a.x, w23.x, acc0.z); acc0.w = fmaf(a.x, w23.y, acc0.w);
      acc1.x = fmaf(a.y, w01.x, acc1.x); acc1.y = fmaf(a.y, w01.y, acc1.y);
      acc1.z = fmaf(a.y, w23.x, acc1.z); acc1.w = fmaf(a.y, w23.y, acc1.w);
      acc2.x = fmaf(a.z, w01.x, acc2.x); acc2.y = fmaf(a.z, w01.y, acc2.y);
      acc2.z = fmaf(a.z, w23.x, acc2.z); acc2.w = fmaf(a.z, w23.y, acc2.w);
      acc3.x = fmaf(a.w, w01.x, acc3.x); acc3.y = fmaf(a.w, w01.y, acc3.y);
      acc3.z = fmaf(a.w, w23.x, acc3.z); acc3.w = fmaf(a.w, w23.y, acc3.w);
    }
    int j0 = (cc << 5) + (ty << 2);
    float4 b4 = make_float4(0,0,0,0);
    if (bias) b4 = *(const float4*)(bias + j0);
    float4 r[4] = {acc0, acc1, acc2, acc3};
    #pragma unroll
    for (int i = 0; i < 4; ++i){
      int n = nb + (tx<<2) + i;
      if (n < N){
        float4 o;
        o.x = r[i].x + b4.x; o.y = r[i].y + b4.y; o.z = r[i].z + b4.z; o.w = r[i].w + b4.w;
        if (act){
          o.x = fmaxf(o.x, 0.f); o.y = fmaxf(o.y, 0.f);
          o.z = fmaxf(o.z, 0.f); o.w = fmaxf(o.w, 0.f);
        }
        *(float4*)(out + (size_t)n*JC + j0) = o;
      }
    }
  }
}

// ---------------- LSTM weight prepack: fragment-linear bf16 hi/lo planes ----------------
// Wp index = (((kt*12 + rt)*2 + p)*64 + l)*8 + i  (p: 0=hi, 1=lo residual)
__global__ __launch_bounds__(256) void k_packWfrag(const float* __restrict__ Wih, const float* __restrict__ Whh,
                                                   u16* __restrict__ Wp){
  int idx = blockIdx.x*256 + threadIdx.x;
  if (idx >= 10*12*2*64*8) return;
  int i  = idx & 7;
  int l  = (idx>>3) & 63;
  int p  = (idx>>9) & 1;
  int rt = (idx>>10) % 12;
  int kt = (idx>>10) / 12;
  int r  = rt*32 + (l & 31);
  int j  = r >> 2, g = r & 3;
  int row = g*96 + j;
  int k  = kt*16 + ((l>>5)<<3) + i;
  float v = (k < 64) ? Wih[row*64 + k] : Whh[row*96 + (k-64)];
  u16 h = f2bf(v);
  Wp[idx] = p ? f2bf(v - bf2f(h)) : h;
}

__global__ __launch_bounds__(128) void k_packB(const float* __restrict__ bih, const float* __restrict__ bhh,
                                               float4* __restrict__ Bp){
  int j = blockIdx.x*128 + threadIdx.x;
  if (j >= 96) return;
  Bp[j] = make_float4(bih[j]+bhh[j], bih[96+j]+bhh[96+j],
                      bih[192+j]+bhh[192+j], bih[288+j]+bhh[288+j]);
}

// ---------------- MFMA LSTM v3: merged directions, frag-linear LDS, no spill ----------------
// 512 thr, 8 waves: wave w -> (rtg = w>>1 in 0..3, nt = w&1). Wave owns 3 row-tiles x 1 node-tile.
// Xf[plane][nt][kt][lane][8] u16, chunk-XOR swizzled; h goes through f32 hF[96][64] then
// re-staged into Xf fragments next step. A (weights) frag-linear from L2, single-buffered.

__device__ __forceinline__ void xf_write8(u16* plane, int nt, int kt, int hi, int col,
                                          u32 w0, u32 w1, u32 w2, u32 w3){
  int X = ((nt*10 + kt)<<6) + (hi<<5) + col;
  int c = (kt<<1) + hi;
  int Xs = X ^ (c & 7);
  *(uint4*)(plane + (Xs<<3)) = make_uint4(w0,w1,w2,w3);
}

__device__ __forceinline__ void cvt8(const float v[8], u32 hw[4], u32 lw[4]){
  #pragma unroll
  for (int i=0;i<4;++i){
    u16 h0=f2bf(v[2*i]),   h1=f2bf(v[2*i+1]);
    u16 l0=f2bf(v[2*i]-bf2f(h0)), l1=f2bf(v[2*i+1]-bf2f(h1));
    hw[i]= (u32)h0 | ((u32)h1<<16);
    lw[i]= (u32)l0 | ((u32)l1<<16);
  }
}

__device__ __forceinline__ void stage_x3(const float* __restrict__ seq,
                                         u16* XfH, u16* XfL, int blk, int N, int tid){
  int node = tid >> 3;
  int kc = tid & 7;
  int n = blk*64 + node;
  float v[8];
  if (n < N){
    const float4* s4 = (const float4*)(seq + (size_t)n*64 + kc*8);
    float4 a = s4[0], b = s4[1];
    v[0]=a.x; v[1]=a.y; v[2]=a.z; v[3]=a.w; v[4]=b.x; v[5]=b.y; v[6]=b.z; v[7]=b.w;
  } else {
    #pragma unroll
    for (int i=0;i<8;++i) v[i]=0.f;
  }
  u32 hw[4], lw[4];
  cvt8(v, hw, lw);
  xf_write8(XfH, node>>5, kc>>1, kc&1, node&31, hw[0],hw[1],hw[2],hw[3]);
  xf_write8(XfL, node>>5, kc>>1, kc&1, node&31, lw[0],lw[1],lw[2],lw[3]);
}

__device__ __forceinline__ void restage_h(const float (*hF)[64],
                                          u16* XfH, u16* XfL, int tid){
  int node = tid & 63;
  int nt = node>>5, colp = node&31;
  for (int cc = tid>>6; cc < 12; cc += 8){
    int c = 8 + cc;
    int kt = c>>1, hi = c&1, j0 = cc*8;
    float v[8];
    #pragma unroll
    for (int i=0;i<8;++i) v[i] = hF[j0+i][node];
    u32 hw[4], lw[4];
    cvt8(v, hw, lw);
    xf_write8(XfH, nt, kt, hi, colp, hw[0],hw[1],hw[2],hw[3]);
    xf_write8(XfL, nt, kt, hi, colp, lw[0],lw[1],lw[2],lw[3]);
  }
}

template<int FIRST, int WRITEH>
__device__ __forceinline__ float lstm_step3(const u16* __restrict__ Wp,
    const float4* __restrict__ Bp, const float* __restrict__ WattW,
    const u16* XfH, const u16* XfL, float (*hF)[64],
    float (&c)[12], int rtg, int nt, int l)
{
  constexpr int NKT = FIRST ? 4 : 10;
  const int hi = l >> 5;
  const int col = l & 31;
  f32x16 acc[3];
  #pragma unroll
  for (int t=0;t<3;++t)
    #pragma unroll
    for (int r=0;r<16;++r) acc[t][r] = 0.f;

  const u16* wbase = Wp + (size_t)(rtg*3)*1024 + ((size_t)l<<3);
  for (int kt = 0; kt < NKT; ++kt){
    const u16* wk = wbase + (size_t)kt*12288;
    short8 A0h = *(const short8*)(wk);
    short8 A0l = *(const short8*)(wk + 512);
    short8 A1h = *(const short8*)(wk + 1024);
    short8 A1l = *(const short8*)(wk + 1536);
    short8 A2h = *(const short8*)(wk + 2048);
    short8 A2l = *(const short8*)(wk + 2560);
    int X = ((nt*10 + kt)<<6) + l;
    int cc = (kt<<1) + hi;
    int Xs = (X ^ (cc & 7)) << 3;
    short8 Bh = *(const short8*)(XfH + Xs);
    short8 Bl = *(const short8*)(XfL + Xs);
    acc[0] = __builtin_amdgcn_mfma_f32_32x32x16_bf16(A0h, Bh, acc[0], 0,0,0);
    acc[1] = __builtin_amdgcn_mfma_f32_32x32x16_bf16(A1h, Bh, acc[1], 0,0,0);
    acc[2] = __builtin_amdgcn_mfma_f32_32x32x16_bf16(A2h, Bh, acc[2], 0,0,0);
    acc[0] = __builtin_amdgcn_mfma_f32_32x32x16_bf16(A0h, Bl, acc[0], 0,0,0);
    acc[1] = __builtin_amdgcn_mfma_f32_32x32x16_bf16(A1h, Bl, acc[1], 0,0,0);
    acc[2] = __builtin_amdgcn_mfma_f32_32x32x16_bf16(A2h, Bl, acc[2], 0,0,0);
    acc[0] = __builtin_amdgcn_mfma_f32_32x32x16_bf16(A0l, Bh, acc[0], 0,0,0);
    acc[1] = __builtin_amdgcn_mfma_f32_32x32x16_bf16(A1l, Bh, acc[1], 0,0,0);
    acc[2] = __builtin_amdgcn_mfma_f32_32x32x16_bf16(A2l, Bh, acc[2], 0,0,0);
  }

  float aP = 0.f;
  #pragma unroll
  for (int ti=0;ti<3;++ti){
    #pragma unroll
    for (int rg=0; rg<4; ++rg){
      const int j = (rtg*3+ti)*8 + 2*rg + hi;
      float4 bv = Bp[j];
      float gi = acc[ti][rg*4+0] + bv.x;
      float gf = acc[ti][rg*4+1] + bv.y;
      float gg = acc[ti][rg*4+2] + bv.z;
      float go = acc[ti][rg*4+3] + bv.w;
      const int ci = ti*4 + rg;
      float cp = FIRST ? 0.f : c[ci];
      float cn = sigf(gf)*cp + sigf(gi)*tanh_f(gg);
      float hh = sigf(go)*tanh_f(cn);
      c[ci] = cn;
      aP = fmaf(hh, WattW[j], aP);
      if (WRITEH) hF[j][nt*32 + col] = hh;
    }
  }
  return aP;
}

__global__ __launch_bounds__(512,2) void k_lstm3(
    const float* __restrict__ h1, const float* __restrict__ h2, const float* __restrict__ h3,
    const u16* __restrict__ Wpf, const u16* __restrict__ Wpb,
    const float4* __restrict__ Bpf, const float4* __restrict__ Bpb,
    const float* __restrict__ Watt, const float* __restrict__ batt,
    float* __restrict__ aF, float* __restrict__ aB, int gG, int N)
{
  __shared__ u16 XfH[10240];
  __shared__ u16 XfL[10240];
  __shared__ float hF[96][64];
  __shared__ float sAl[8][3][32];
  const int tid = threadIdx.x;
  const int l = tid & 63;
  const int w = __builtin_amdgcn_readfirstlane(tid >> 6);
  const int rtg = w >> 1;
  const int nt = w & 1;
  const int dir = (blockIdx.x >= gG) ? 1 : 0;
  const int blk = blockIdx.x - dir*gG;
  const float* sA = dir ? h3 : h1;
  const float* sC = dir ? h1 : h3;
  const u16* Wp = dir ? Wpb : Wpf;
  const float4* Bp = dir ? Bpb : Bpf;
  const float* WattW = Watt + dir*96;
  float* aD = dir ? aB : aF;
  float c[12];
  float a0, a1, a2;

  stage_x3(sA, XfH, XfL, blk, N, tid);
  __syncthreads();
  a0 = lstm_step3<1,1>(Wp, Bp, WattW, XfH, XfL, hF, c, rtg, nt, l);
  __syncthreads();
  stage_x3(h2, XfH, XfL, blk, N, tid);
  restage_h(hF, XfH, XfL, tid);
  __syncthreads();
  a1 = lstm_step3<0,1>(Wp, Bp, WattW, XfH, XfL, hF, c, rtg, nt, l);
  __syncthreads();
  stage_x3(sC, XfH, XfL, blk, N, tid);
  restage_h(hF, XfH, XfL, tid);
  __syncthreads();
  a2 = lstm_step3<0,0>(Wp, Bp, WattW, XfH, XfL, hF, c, rtg, nt, l);

  // alpha reduce: lanes l and l^32 hold complementary gate halves of same node
  a0 += __shfl_xor(a0, 32);
  a1 += __shfl_xor(a1, 32);
  a2 += __shfl_xor(a2, 32);
  if (l < 32){
    sAl[w][0][l] = a0;
    sAl[w][1][l] = a1;
    sAl[w][2][l] = a2;
  }
  __syncthreads();
  if (tid < 192){
    int s = tid >> 6;
    int node = tid & 63;
    int nt2 = node >> 5, colp = node & 31;
    int n = blk*64 + node;
    if (n < N){
      float sum = sAl[nt2][s][colp] + sAl[2+nt2][s][colp]
                + sAl[4+nt2][s][colp] + sAl[6+nt2][s][colp];
      int slice = dir ? (2 - s) : s;
      float v = dir ? sum : (batt[0] + sum);
      aD[(size_t)slice*N + n] = v;
    }
  }
}

// ---------------- JK softmax + xjk + Wlin + Wfc1 + leaky (16 nodes/block) ----------------
__global__ __launch_bounds__(256) void k_jk(const float* __restrict__ aF, const float* __restrict__ aB,
                                            const float* __restrict__ h1, const float* __restrict__ h2,
                                            const float* __restrict__ h3,
                                            const float* __restrict__ Wlin, const float* __restrict__ blin,
                                            const float* __restrict__ Wfc1, const float* __restrict__ bfc1,
                                            float* __restrict__ vout, int N){
  __shared__ float sWl[64*65];
  __shared__ float sX[4][64];
  int tid = threadIdx.x;
  for (int idx = tid; idx < 1024; idx += 256){
    int j = idx >> 4;
    int c4 = (idx & 15) << 2;
    float4 v = *(const float4*)(Wlin + (size_t)j*64 + c4);
    sWl[j*65 + c4+0] = v.x; sWl[j*65 + c4+1] = v.y;
    sWl[j*65 + c4+2] = v.z; sWl[j*65 + c4+3] = v.w;
  }
  __syncthreads();
  int ln = tid >> 6, j = tid & 63;
  float wf1 = Wfc1[j];
  float bl = blin[j];
  for (int ib = 0; ib < 4; ++ib){
    int n = blockIdx.x*16 + ib*4 + ln;
    bool ok = n < N;
    float xj = 0.f;
    if (ok){
      float a0 = aF[n] + aB[n];
      float a1 = aF[(size_t)N + n] + aB[(size_t)N + n];
      float a2 = aF[(size_t)2*N + n] + aB[(size_t)2*N + n];
      float m = fmaxf(a0, fmaxf(a1, a2));
      float e0 = __expf(a0-m), e1 = __expf(a1-m), e2 = __expf(a2-m);
      float inv = __builtin_amdgcn_rcpf(e0+e1+e2);
      float w0 = e0*inv, w1 = e1*inv, w2 = e2*inv;
      xj = w0*h1[(size_t)n*64 + j] + w1*h2[(size_t)n*64 + j] + w2*h3[(size_t)n*64 + j];
    }
    sX[ln][j] = xj;
    __syncthreads();
    float acc = bl;
    #pragma unroll 8
    for (int cc = 0; cc < 64; ++cc) acc = fmaf(sX[ln][cc], sWl[j*65 + cc], acc);
    float r = acc * wf1;
    #pragma unroll
    for (int off = 32; off > 0; off >>= 1) r += __shfl_down(r, off);
    if (j == 0 && ok){
      float vv = r + bfc1[0];
      vout[n] = vv >= 0.f ? vv : 0.01f*vv;
    }
    __syncthreads();
  }
}

// ---------------- final dot (deterministic two-stage, f64 accum) ----------------
__global__ __launch_bounds__(256) void k_final1(const float* __restrict__ w, const float* __restrict__ v,
                                                double* __restrict__ part, int N){
  __shared__ double sd[256];
  int tid = threadIdx.x;
  double a = 0.0;
  for (int i = blockIdx.x*256 + tid; i < N; i += 256*256)
    a += (double)(w[i] * v[i]);
  sd[tid] = a; __syncthreads();
  for (int off = 128; off > 0; off >>= 1){
    if (tid < off) sd[tid] += sd[tid + off];
    __syncthreads();
  }
  if (tid == 0) part[blockIdx.x] = sd[0];
}

__global__ __launch_bounds__(256) void k_final2(const double* __restrict__ part, const float* __restrict__ bfc2,
                                                float* __restrict__ out){
  __shared__ double sd[256];
  int tid = threadIdx.x;
  sd[tid] = part[tid]; __syncthreads();
  for (int off = 128; off > 0; off >>= 1){
    if (tid < off) sd[tid] += sd[tid + off];
    __syncthreads();
  }
  if (tid == 0) out[0] = (float)(sd[0] + (double)bfc2[0]);
}

// ---------------- host ----------------
extern "C" void kernel_launch(void* const* d_in, const int* in_sizes, int n_in,
                              void* d_out, int out_size, void* d_ws, size_t ws_size,
                              hipStream_t stream){
  const float* x    = (const float*)d_in[0];
  const int*   ei   = (const int*)d_in[1];
  const float* W0a  = (const float*)d_in[2];
  const float* b0a  = (const float*)d_in[3];
  const float* W0b  = (const float*)d_in[4];
  const float* b0b  = (const float*)d_in[5];
  const float* W1a  = (const float*)d_in[6];
  const float* b1a  = (const float*)d_in[7];
  const float* W1b  = (const float*)d_in[8];
  const float* b1b  = (const float*)d_in[9];
  const float* W2a  = (const float*)d_in[10];
  const float* b2a  = (const float*)d_in[11];
  const float* W2b  = (const float*)d_in[12];
  const float* b2b  = (const float*)d_in[13];
  const float* Wih_f = (const float*)d_in[14];
  const float* Whh_f = (const float*)d_in[15];
  const float* bih_f = (const float*)d_in[16];
  const float* bhh_f = (const float*)d_in[17];
  const float* Wih_b = (const float*)d_in[18];
  const float* Whh_b = (const float*)d_in[19];
  const float* bih_b = (const float*)d_in[20];
  const float* bhh_b = (const float*)d_in[21];
  const float* Watt = (const float*)d_in[22];
  const float* batt = (const float*)d_in[23];
  const float* Wlin = (const float*)d_in[24];
  const float* blin = (const float*)d_in[25];
  const float* Wfc1 = (const float*)d_in[26];
  const float* bfc1 = (const float*)d_in[27];
  const float* Wfc2 = (const float*)d_in[28];
  const float* bfc2 = (const float*)d_in[29];
  float* out = (float*)d_out;

  const int N = in_sizes[0] / 128;
  const int E = in_sizes[1] / 2;
  const int* src = ei;
  const int* dst = ei + E;

  uint8_t* w8 = (uint8_t*)d_ws;
  size_t off = 0;
  auto alloc = [&](size_t bytes) -> void* {
    void* p = w8 + off;
    off = (off + bytes + 255) & ~(size_t)255;
    return p;
  };
  int*    deg    = (int*)   alloc((size_t)N*4);
  int*    fill   = (int*)   alloc((size_t)N*4);
  int*    indptr = (int*)   alloc(((size_t)N+1)*4);
  int*    col    = (int*)   alloc((size_t)E*4);
  int*    bsum   = (int*)   alloc(2048);
  int*    boffs  = (int*)   alloc(2048);
  float*  h1     = (float*) alloc((size_t)N*64*4);
  float*  h2     = (float*) alloc((size_t)N*64*4);
  float*  h3     = (float*) alloc((size_t)N*64*4);
  float*  aF     = (float*) alloc((size_t)3*N*4);
  float*  aB     = (float*) alloc((size_t)3*N*4);
  float*  vbuf   = (float*) alloc((size_t)N*4);
  double* part   = (double*)alloc(256*8);
  u16*    Wpf    = (u16*)   alloc((size_t)10*12*2*64*8*2);
  u16*    Wpb    = (u16*)   alloc((size_t)10*12*2*64*8*2);
  float4* Bpf    = (float4*)alloc((size_t)96*16);
  float4* Bpb    = (float4*)alloc((size_t)96*16);
  float*  P      = (float*) alloc((size_t)N*192*4);   // GIN phase scratch
  if (off > ws_size) return;
  float* ybuf = P;                      // transform output [N,64]
  float* zbuf = P + (size_t)N*64;       // agg+bias+relu output [N,64]

  const size_t lds64  = 64  * 102 * 4;
  const size_t lds128 = 128 * 102 * 4;

  hipMemsetAsync(deg,  0, (size_t)N*4, stream);
  hipMemsetAsync(fill, 0, (size_t)N*4, stream);

  int gE = (E + 255) / 256;
  int nb1 = (N + 255) / 256;
  int gG = (N + 63) / 64;
  int gA = (N + 15) / 16;

  // weight prepack (independent of CSR)
  k_packWfrag<<<480, 256, 0, stream>>>(Wih_f, Whh_f, Wpf);
  k_packWfrag<<<480, 256, 0, stream>>>(Wih_b, Whh_b, Wpb);
  k_packB<<<1, 128, 0, stream>>>(bih_f, bhh_f, Bpf);
  k_packB<<<1, 128, 0, stream>>>(bih_b, bhh_b, Bpb);

  k_deg  <<<gE, 256, 0, stream>>>(dst, deg, E);
  k_scan1<<<nb1, 256, 0, stream>>>(deg, indptr, bsum, N);
  k_scan2<<<1, 512, 0, stream>>>(bsum, boffs, indptr, nb1, N);
  k_scan3<<<nb1, 256, 0, stream>>>(indptr, boffs, N);
  k_fill <<<gE, 256, 0, stream>>>(src, dst, indptr, fill, col, E);

  // ---- GIN layer 0 (transform-first: (x+aggX)@W = y+aggY) ----
  k_gemm<<<gG, TPB, lds128, stream>>>(x, W0a, nullptr, ybuf, 128, 64, 0, N);
  k_agg<64><<<gA, 256, 0, stream>>>(ybuf, indptr, col, b0a, zbuf, N);
  k_gemm<<<gG, TPB, lds64, stream>>>(zbuf, W0b, b0b, h1, 64, 64, 1, N);
  // ---- GIN layer 1 ----
  k_gemm<<<gG, TPB, lds64, stream>>>(h1, W1a, nullptr, ybuf, 64, 64, 0, N);
  k_agg<64><<<gA, 256, 0, stream>>>(ybuf, indptr, col, b1a, zbuf, N);
  k_gemm<<<gG, TPB, lds64, stream>>>(zbuf, W1b, b1b, h2, 64, 64, 1, N);
  // ---- GIN layer 2 ----
  k_gemm<<<gG, TPB, lds64, stream>>>(h2, W2a, nullptr, ybuf, 64, 64, 0, N);
  k_agg<64><<<gA, 256, 0, stream>>>(ybuf, indptr, col, b2a, zbuf, N);
  k_gemm<<<gG, TPB, lds64, stream>>>(zbuf, W2b, b2b, h3, 64, 64, 1, N);

  // ---- LSTM: both directions in one dispatch ----
  k_lstm3<<<2*gG, 512, 0, stream>>>(h1, h2, h3, Wpf, Wpb, Bpf, Bpb, Watt, batt,
                                    aF, aB, gG, N);

  // ---- JK attention + linear + fc1 + leaky ----
  k_jk<<<(N+15)/16, 256, 0, stream>>>(aF, aB, h1, h2, h3, Wlin, blin, Wfc1, bfc1, vbuf, N);

  // ---- final dot ----
  k_final1<<<256, 256, 0, stream>>>(Wfc2, vbuf, part, N);
  k_final2<<<1, 256, 0, stream>>>(part, bfc2, out);
}

// Round 8
// 903.877 us; speedup vs baseline: 4.5654x; 1.0058x over previous
//
#include <hip/hip_runtime.h>
#include <stdint.h>

#define TPB 128
typedef unsigned short u16;
typedef unsigned int u32;
using short8 = __attribute__((ext_vector_type(8))) short;
using f32x16 = __attribute__((ext_vector_type(16))) float;

__device__ __forceinline__ float sigf(float x){
  return __builtin_amdgcn_rcpf(1.0f + __expf(-x));
}
__device__ __forceinline__ float tanh_f(float x){
  return 1.0f - 2.0f*__builtin_amdgcn_rcpf(1.0f + __expf(2.0f*x));
}
__device__ __forceinline__ u16 f2bf(float f){
  u32 u = __float_as_uint(f);
  u += 0x7FFFu + ((u>>16)&1u);
  return (u16)(u>>16);
}
__device__ __forceinline__ float bf2f(u16 h){ return __uint_as_float(((u32)h)<<16); }

// ---------------- CSR build ----------------
__global__ void k_deg(const int* __restrict__ dst, int* __restrict__ deg, int E){
  int i = blockIdx.x*256 + threadIdx.x;
  if (i < E) atomicAdd(&deg[dst[i]], 1);
}

__global__ __launch_bounds__(256) void k_scan1(const int* __restrict__ deg, int* __restrict__ indptr,
                                               int* __restrict__ bsum, int N){
  __shared__ int s[256];
  int tid = threadIdx.x;
  int i = blockIdx.x*256 + tid;
  int v = (i < N) ? deg[i] : 0;
  s[tid] = v; __syncthreads();
  for (int off=1; off<256; off<<=1){
    int t = (tid>=off) ? s[tid-off] : 0;
    __syncthreads();
    s[tid] += t;
    __syncthreads();
  }
  if (i < N) indptr[i] = s[tid] - v;
  if (tid == 255) bsum[blockIdx.x] = s[255];
}

__global__ __launch_bounds__(512) void k_scan2(const int* __restrict__ bsum, int* __restrict__ boffs,
                                               int* __restrict__ indptr, int nb, int N){
  __shared__ int s[512];
  int tid = threadIdx.x;
  int v = (tid < nb) ? bsum[tid] : 0;
  s[tid] = v; __syncthreads();
  for (int off=1; off<512; off<<=1){
    int t = (tid>=off) ? s[tid-off] : 0;
    __syncthreads();
    s[tid] += t;
    __syncthreads();
  }
  boffs[tid] = s[tid] - v;
  if (tid == nb-1) indptr[N] = s[tid];
}

__global__ __launch_bounds__(256) void k_scan3(int* __restrict__ indptr, const int* __restrict__ boffs, int N){
  int i = blockIdx.x*256 + threadIdx.x;
  if (i < N) indptr[i] += boffs[blockIdx.x];
}

__global__ void k_fill(const int* __restrict__ src, const int* __restrict__ dst,
                       const int* __restrict__ indptr, int* __restrict__ fill,
                       int* __restrict__ col, int E){
  int i = blockIdx.x*256 + threadIdx.x;
  if (i < E){
    int d = dst[i];
    int r = atomicAdd(&fill[d], 1);
    col[indptr[d] + r] = src[i];
  }
}

// ---------------- aggregation: z[n] = relu( y[n] + sum_{nbr} y[src] + bias ) ----------------
template<int F>
__global__ __launch_bounds__(256) void k_agg(const float* __restrict__ y, const int* __restrict__ indptr,
                                             const int* __restrict__ col, const float* __restrict__ bias,
                                             float* __restrict__ z, int N){
  constexpr int TPN = F/4;
  constexpr int NPB = 256/TPN;
  int n = blockIdx.x*NPB + threadIdx.x/TPN;
  int lane = threadIdx.x % TPN;
  if (n >= N) return;
  const float4* hv = (const float4*)y;
  float4 acc = hv[(size_t)n*TPN + lane];
  int s = indptr[n], e = indptr[n+1];
  int p = s;
  for (; p + 8 <= e; p += 8){
    int c8[8];
    #pragma unroll
    for (int i=0;i<8;++i) c8[i] = col[p+i];
    #pragma unroll
    for (int i=0;i<8;++i){
      float4 x = hv[(size_t)c8[i]*TPN + lane];
      acc.x += x.x; acc.y += x.y; acc.z += x.z; acc.w += x.w;
    }
  }
  for (; p < e; ++p){
    float4 x = hv[(size_t)col[p]*TPN + lane];
    acc.x += x.x; acc.y += x.y; acc.z += x.z; acc.w += x.w;
  }
  float4 b4 = ((const float4*)bias)[lane];
  acc.x = fmaxf(acc.x + b4.x, 0.f);
  acc.y = fmaxf(acc.y + b4.y, 0.f);
  acc.z = fmaxf(acc.z + b4.z, 0.f);
  acc.w = fmaxf(acc.w + b4.w, 0.f);
  ((float4*)z)[(size_t)n*TPN + lane] = acc;
}

// ---------------- generic f32 GEMM ----------------
__global__ __launch_bounds__(TPB) void k_gemm(const float* __restrict__ A, const float* __restrict__ W,
                                              const float* __restrict__ bias, float* __restrict__ out,
                                              int K, int JC, int act, int N){
  extern __shared__ float sm[];
  float* As = sm;
  float* Ws = sm + (size_t)K*68;
  const int tid = threadIdx.x;
  const int tx = tid & 15, ty = tid >> 4;
  const int nb = blockIdx.x * 64;
  const int kq = K >> 2;
  for (int it = 0, idx = tid; it < (kq >> 1); ++it, idx += TPB){
    int nl = idx & 63, kk = idx >> 6;
    int k4 = kk << 2;
    int n = nb + nl;
    float4 v = make_float4(0.f,0.f,0.f,0.f);
    if (n < N) v = *(const float4*)(A + (size_t)n*K + k4);
    As[(size_t)(k4+0)*68 + nl] = v.x;
    As[(size_t)(k4+1)*68 + nl] = v.y;
    As[(size_t)(k4+2)*68 + nl] = v.z;
    As[(size_t)(k4+3)*68 + nl] = v.w;
  }
  const int ncc = JC >> 5;
  for (int cc = 0; cc < ncc; ++cc){
    __syncthreads();
    for (int it = 0, idx = tid; it < (kq >> 2); ++it, idx += TPB){
      int cl = idx & 31, kk = idx >> 5;
      int k4 = kk << 2;
      int j = (cc << 5) + cl;
      float4 v = *(const float4*)(W + (size_t)j*K + k4);
      Ws[(size_t)(k4+0)*34 + cl] = v.x;
      Ws[(size_t)(k4+1)*34 + cl] = v.y;
      Ws[(size_t)(k4+2)*34 + cl] = v.z;
      Ws[(size_t)(k4+3)*34 + cl] = v.w;
    }
    __syncthreads();
    float4 acc0 = make_float4(0,0,0,0), acc1 = acc0, acc2 = acc0, acc3 = acc0;
    #pragma unroll 4
    for (int k = 0; k < K; ++k){
      float4 a = *(const float4*)(As + (size_t)k*68 + (tx<<2));
      float2 w01 = *(const float2*)(Ws + (size_t)k*34 + (ty<<2));
      float2 w23 = *(const float2*)(Ws + (size_t)k*34 + (ty<<2) + 2);
      acc0.x = fmaf(a.x, w01.x, acc0.x); acc0.y = fmaf(a.x, w01.y, acc0.y);
      acc0.z = fmaf(a.x, w23.x, acc0.z); acc0.w = fmaf(a.x, w23.y, acc0.w);
      acc1.x = fmaf(a.y, w01.x, acc1.x); acc1.y = fmaf(a.y, w01.y, acc1.y);
      acc1.z = fmaf(a.y, w23.x, acc1.z); acc1.w = fmaf(a.y, w23.y, acc1.w);
      acc2.x = fmaf(a.z, w01.x, acc2.x); acc2.y = fmaf(a.z, w01.y, acc2.y);
      acc2.z = fmaf(a.z, w23.x, acc2.z); acc2.w = fmaf(a.z, w23.y, acc2.w);
      acc3.x = fmaf(a.w, w01.x, acc3.x); acc3.y = fmaf(a.w, w01.y, acc3.y);
      acc3.z = fmaf(a.w, w23.x, acc3.z); acc3.w = fmaf(a.w, w23.y, acc3.w);
    }
    int j0 = (cc << 5) + (ty << 2);
    float4 b4 = make_float4(0,0,0,0);
    if (bias) b4 = *(const float4*)(bias + j0);
    float4 r[4] = {acc0, acc1, acc2, acc3};
    #pragma unroll
    for (int i = 0; i < 4; ++i){
      int n = nb + (tx<<2) + i;
      if (n < N){
        float4 o;
        o.x = r[i].x + b4.x; o.y = r[i].y + b4.y; o.z = r[i].z + b4.z; o.w = r[i].w + b4.w;
        if (act){
          o.x = fmaxf(o.x, 0.f); o.y = fmaxf(o.y, 0.f);
          o.z = fmaxf(o.z, 0.f); o.w = fmaxf(o.w, 0.f);
        }
        *(float4*)(out + (size_t)n*JC + j0) = o;
      }
    }
  }
}

// ---------------- LSTM weight prepack: fragment-linear bf16 hi/lo planes ----------------
// Wp index = (((kt*12 + rt)*2 + p)*64 + l)*8 + i  (p: 0=hi, 1=lo residual)
__global__ __launch_bounds__(256) void k_packWfrag(const float* __restrict__ Wih, const float* __restrict__ Whh,
                                                   u16* __restrict__ Wp){
  int idx = blockIdx.x*256 + threadIdx.x;
  if (idx >= 10*12*2*64*8) return;
  int i  = idx & 7;
  int l  = (idx>>3) & 63;
  int p  = (idx>>9) & 1;
  int rt = (idx>>10) % 12;
  int kt = (idx>>10) / 12;
  int r  = rt*32 + (l & 31);
  int j  = r >> 2, g = r & 3;
  int row = g*96 + j;
  int k  = kt*16 + ((l>>5)<<3) + i;
  float v = (k < 64) ? Wih[row*64 + k] : Whh[row*96 + (k-64)];
  u16 h = f2bf(v);
  Wp[idx] = p ? f2bf(v - bf2f(h)) : h;
}

__global__ __launch_bounds__(128) void k_packB(const float* __restrict__ bih, const float* __restrict__ bhh,
                                               float4* __restrict__ Bp){
  int j = blockIdx.x*128 + threadIdx.x;
  if (j >= 96) return;
  Bp[j] = make_float4(bih[j]+bhh[j], bih[96+j]+bhh[96+j],
                      bih[192+j]+bhh[192+j], bih[288+j]+bhh[288+j]);
}

// ---------------- MFMA LSTM v4b: fused epilogue, h double-buffer, direct h writes ----------------
// Planes XH/XL (u16): x-part frags [nt(2)][kt(4)][slot(64)][8] at offset 0 (4096 u16),
// h-part frags [p(2)][nt(2)][kth(6)][slot(64)][8] at offset 4096 (12288 u16) -> total 16384.
// Slot low-3 bits XOR-swizzled by (ktGlobal*2 + hi).

__device__ __forceinline__ void ldx_regs(const float* __restrict__ seq, int blk, int N, int tid,
                                         float (&v)[8]){
  int node = tid >> 3;
  int kc = tid & 7;
  int n = blk*64 + node;
  if (n < N){
    const float4* s4 = (const float4*)(seq + (size_t)n*64 + kc*8);
    float4 a = s4[0], b = s4[1];
    v[0]=a.x; v[1]=a.y; v[2]=a.z; v[3]=a.w; v[4]=b.x; v[5]=b.y; v[6]=b.z; v[7]=b.w;
  } else {
    #pragma unroll
    for (int i=0;i<8;++i) v[i]=0.f;
  }
}

__device__ __forceinline__ void stage_from_regs(const float (&v)[8], u16* __restrict__ XH,
                                                u16* __restrict__ XL, int tid){
  int node = tid >> 3;
  int kc = tid & 7;           // kc = kt*2 + hi for the x-part
  u32 hw[4], lw[4];
  #pragma unroll
  for (int i=0;i<4;++i){
    u16 h0=f2bf(v[2*i]),   h1=f2bf(v[2*i+1]);
    u16 l0=f2bf(v[2*i]-bf2f(h0)), l1=f2bf(v[2*i+1]-bf2f(h1));
    hw[i]= (u32)h0 | ((u32)h1<<16);
    lw[i]= (u32)l0 | ((u32)l1<<16);
  }
  int slot = ((kc&1)<<5) | (node&31);
  int sl = slot ^ (kc&7);
  int addr = (((node>>5)*4 + (kc>>1))<<9) + (sl<<3);
  *(uint4*)(XH + addr) = make_uint4(hw[0],hw[1],hw[2],hw[3]);
  *(uint4*)(XL + addr) = make_uint4(lw[0],lw[1],lw[2],lw[3]);
}

template<int FIRST, int WRITEH, int HP, int WP>
__device__ __forceinline__ float lstm_step4(const u16* __restrict__ Wp,
    const float4* __restrict__ Bp, const float* __restrict__ WattW,
    u16* __restrict__ XH, u16* __restrict__ XL,
    float (&c)[12], int rtg, int nt, int l)
{
  constexpr int NKT = FIRST ? 4 : 10;
  const int hi = l >> 5;
  const int col = l & 31;
  f32x16 acc[3];
  #pragma unroll
  for (int t=0;t<3;++t)
    #pragma unroll
    for (int r=0;r<16;++r) acc[t][r] = 0.f;

  const u16* wbase = Wp + (size_t)(rtg*3)*1024 + ((size_t)l<<3);
  #pragma unroll
  for (int kt = 0; kt < NKT; ++kt){
    const u16* wk = wbase + (size_t)kt*12288;
    short8 A0h = *(const short8*)(wk);
    short8 A0l = *(const short8*)(wk + 512);
    short8 A1h = *(const short8*)(wk + 1024);
    short8 A1l = *(const short8*)(wk + 1536);
    short8 A2h = *(const short8*)(wk + 2048);
    short8 A2l = *(const short8*)(wk + 2560);
    int cc = (kt<<1) + hi;
    int sl = l ^ (cc & 7);
    int base = (kt < 4) ? (((nt<<2) + kt)<<9)
                        : (4096 + ((((HP<<1)+nt)*6 + (kt-4))<<9));
    short8 Bh = *(const short8*)(XH + base + (sl<<3));
    short8 Bl = *(const short8*)(XL + base + (sl<<3));
    __builtin_amdgcn_s_setprio(1);
    acc[0] = __builtin_amdgcn_mfma_f32_32x32x16_bf16(A0h, Bh, acc[0], 0,0,0);
    acc[1] = __builtin_amdgcn_mfma_f32_32x32x16_bf16(A1h, Bh, acc[1], 0,0,0);
    acc[2] = __builtin_amdgcn_mfma_f32_32x32x16_bf16(A2h, Bh, acc[2], 0,0,0);
    acc[0] = __builtin_amdgcn_mfma_f32_32x32x16_bf16(A0h, Bl, acc[0], 0,0,0);
    acc[1] = __builtin_amdgcn_mfma_f32_32x32x16_bf16(A1h, Bl, acc[1], 0,0,0);
    acc[2] = __builtin_amdgcn_mfma_f32_32x32x16_bf16(A2h, Bl, acc[2], 0,0,0);
    acc[0] = __builtin_amdgcn_mfma_f32_32x32x16_bf16(A0l, Bh, acc[0], 0,0,0);
    acc[1] = __builtin_amdgcn_mfma_f32_32x32x16_bf16(A1l, Bh, acc[1], 0,0,0);
    acc[2] = __builtin_amdgcn_mfma_f32_32x32x16_bf16(A2l, Bh, acc[2], 0,0,0);
    __builtin_amdgcn_s_setprio(0);
  }

  float aP = 0.f;
  #pragma unroll
  for (int ti=0;ti<3;++ti){
    #pragma unroll
    for (int rg=0; rg<4; ++rg){
      const int j = (rtg*3+ti)*8 + 2*rg + hi;
      float4 bv = Bp[j];
      float gi = acc[ti][rg*4+0] + bv.x;
      float gf = acc[ti][rg*4+1] + bv.y;
      float gg = acc[ti][rg*4+2] + bv.z;
      float go = acc[ti][rg*4+3] + bv.w;
      const int ci = ti*4 + rg;
      float cp = FIRST ? 0.f : c[ci];
      float cn = sigf(gf)*cp + sigf(gi)*tanh_f(gg);
      float hh = sigf(go)*tanh_f(cn);
      c[ci] = cn;
      aP = fmaf(hh, WattW[j], aP);
      if (WRITEH){
        u16 hb = f2bf(hh);
        u16 lb = f2bf(hh - bf2f(hb));
        const int k = 64 + j;
        const int ktG = k >> 4;
        const int kth = ktG - 4;
        const int hik = (k >> 3) & 1;
        const int elem = k & 7;
        const int c2 = ((ktG<<1) | hik) & 7;
        const int slot = (hik<<5) | col;
        const int sl = slot ^ c2;
        const int addr = 4096 + ((((WP<<1)+nt)*6 + kth)<<9) + (sl<<3) + elem;
        XH[addr] = hb;
        XL[addr] = lb;
      }
    }
  }
  return aP;
}

__global__ __launch_bounds__(512,2) void k_lstm4(
    const float* __restrict__ h1, const float* __restrict__ h2, const float* __restrict__ h3,
    const u16* __restrict__ Wpf, const u16* __restrict__ Wpb,
    const float4* __restrict__ Bpf, const float4* __restrict__ Bpb,
    const float* __restrict__ Watt, const float* __restrict__ batt,
    float* __restrict__ aF, float* __restrict__ aB, int gG, int N)
{
  __shared__ u16 XH[16384];
  __shared__ u16 XL[16384];
  __shared__ float sAl[8][3][32];
  const int tid = threadIdx.x;
  const int l = tid & 63;
  const int w = __builtin_amdgcn_readfirstlane(tid >> 6);
  const int rtg = w >> 1;
  const int nt = w & 1;
  const int dir = (blockIdx.x >= gG) ? 1 : 0;
  const int blk = blockIdx.x - dir*gG;
  const float* sA = dir ? h3 : h1;
  const float* sC = dir ? h1 : h3;
  const u16* Wp = dir ? Wpb : Wpf;
  const float4* Bp = dir ? Bpb : Bpf;
  const float* WattW = Watt + dir*96;
  float* aD = dir ? aB : aF;
  float c[12];
  float a0, a1, a2;
  float xv[8];

  // prologue: stage x0, pre-issue x1 loads
  ldx_regs(sA, blk, N, tid, xv);
  stage_from_regs(xv, XH, XL, tid);
  ldx_regs(h2, blk, N, tid, xv);
  __syncthreads();

  a0 = lstm_step4<1,1,0,0>(Wp, Bp, WattW, XH, XL, c, rtg, nt, l);
  __syncthreads();
  stage_from_regs(xv, XH, XL, tid);
  ldx_regs(sC, blk, N, tid, xv);
  __syncthreads();

  a1 = lstm_step4<0,1,0,1>(Wp, Bp, WattW, XH, XL, c, rtg, nt, l);
  __syncthreads();
  stage_from_regs(xv, XH, XL, tid);
  __syncthreads();

  a2 = lstm_step4<0,0,1,0>(Wp, Bp, WattW, XH, XL, c, rtg, nt, l);

  // alpha reduce: lanes l and l^32 hold complementary gate halves of same node
  a0 += __shfl_xor(a0, 32);
  a1 += __shfl_xor(a1, 32);
  a2 += __shfl_xor(a2, 32);
  if (l < 32){
    sAl[w][0][l] = a0;
    sAl[w][1][l] = a1;
    sAl[w][2][l] = a2;
  }
  __syncthreads();
  if (tid < 192){
    int s = tid >> 6;
    int node = tid & 63;
    int nt2 = node >> 5, colp = node & 31;
    int n = blk*64 + node;
    if (n < N){
      float sum = sAl[nt2][s][colp] + sAl[2+nt2][s][colp]
                + sAl[4+nt2][s][colp] + sAl[6+nt2][s][colp];
      int slice = dir ? (2 - s) : s;
      float v = dir ? sum : (batt[0] + sum);
      aD[(size_t)slice*N + n] = v;
    }
  }
}

// ---------------- JK softmax + xjk + Wlin + Wfc1 + leaky (16 nodes/block) ----------------
__global__ __launch_bounds__(256) void k_jk(const float* __restrict__ aF, const float* __restrict__ aB,
                                            const float* __restrict__ h1, const float* __restrict__ h2,
                                            const float* __restrict__ h3,
                                            const float* __restrict__ Wlin, const float* __restrict__ blin,
                                            const float* __restrict__ Wfc1, const float* __restrict__ bfc1,
                                            float* __restrict__ vout, int N){
  __shared__ float sWl[64*65];
  __shared__ float sX[4][64];
  int tid = threadIdx.x;
  for (int idx = tid; idx < 1024; idx += 256){
    int j = idx >> 4;
    int c4 = (idx & 15) << 2;
    float4 v = *(const float4*)(Wlin + (size_t)j*64 + c4);
    sWl[j*65 + c4+0] = v.x; sWl[j*65 + c4+1] = v.y;
    sWl[j*65 + c4+2] = v.z; sWl[j*65 + c4+3] = v.w;
  }
  __syncthreads();
  int ln = tid >> 6, j = tid & 63;
  float wf1 = Wfc1[j];
  float bl = blin[j];
  for (int ib = 0; ib < 4; ++ib){
    int n = blockIdx.x*16 + ib*4 + ln;
    bool ok = n < N;
    float xj = 0.f;
    if (ok){
      float a0 = aF[n] + aB[n];
      float a1 = aF[(size_t)N + n] + aB[(size_t)N + n];
      float a2 = aF[(size_t)2*N + n] + aB[(size_t)2*N + n];
      float m = fmaxf(a0, fmaxf(a1, a2));
      float e0 = __expf(a0-m), e1 = __expf(a1-m), e2 = __expf(a2-m);
      float inv = __builtin_amdgcn_rcpf(e0+e1+e2);
      float w0 = e0*inv, w1 = e1*inv, w2 = e2*inv;
      xj = w0*h1[(size_t)n*64 + j] + w1*h2[(size_t)n*64 + j] + w2*h3[(size_t)n*64 + j];
    }
    sX[ln][j] = xj;
    __syncthreads();
    float acc = bl;
    #pragma unroll 8
    for (int cc = 0; cc < 64; ++cc) acc = fmaf(sX[ln][cc], sWl[j*65 + cc], acc);
    float r = acc * wf1;
    #pragma unroll
    for (int off = 32; off > 0; off >>= 1) r += __shfl_down(r, off);
    if (j == 0 && ok){
      float vv = r + bfc1[0];
      vout[n] = vv >= 0.f ? vv : 0.01f*vv;
    }
    __syncthreads();
  }
}

// ---------------- final dot (deterministic two-stage, f64 accum) ----------------
__global__ __launch_bounds__(256) void k_final1(const float* __restrict__ w, const float* __restrict__ v,
                                                double* __restrict__ part, int N){
  __shared__ double sd[256];
  int tid = threadIdx.x;
  double a = 0.0;
  for (int i = blockIdx.x*256 + tid; i < N; i += 256*256)
    a += (double)(w[i] * v[i]);
  sd[tid] = a; __syncthreads();
  for (int off = 128; off > 0; off >>= 1){
    if (tid < off) sd[tid] += sd[tid + off];
    __syncthreads();
  }
  if (tid == 0) part[blockIdx.x] = sd[0];
}

__global__ __launch_bounds__(256) void k_final2(const double* __restrict__ part, const float* __restrict__ bfc2,
                                                float* __restrict__ out){
  __shared__ double sd[256];
  int tid = threadIdx.x;
  sd[tid] = part[tid]; __syncthreads();
  for (int off = 128; off > 0; off >>= 1){
    if (tid < off) sd[tid] += sd[tid + off];
    __syncthreads();
  }
  if (tid == 0) out[0] = (float)(sd[0] + (double)bfc2[0]);
}

// ---------------- host ----------------
extern "C" void kernel_launch(void* const* d_in, const int* in_sizes, int n_in,
                              void* d_out, int out_size, void* d_ws, size_t ws_size,
                              hipStream_t stream){
  const float* x    = (const float*)d_in[0];
  const int*   ei   = (const int*)d_in[1];
  const float* W0a  = (const float*)d_in[2];
  const float* b0a  = (const float*)d_in[3];
  const float* W0b  = (const float*)d_in[4];
  const float* b0b  = (const float*)d_in[5];
  const float* W1a  = (const float*)d_in[6];
  const float* b1a  = (const float*)d_in[7];
  const float* W1b  = (const float*)d_in[8];
  const float* b1b  = (const float*)d_in[9];
  const float* W2a  = (const float*)d_in[10];
  const float* b2a  = (const float*)d_in[11];
  const float* W2b  = (const float*)d_in[12];
  const float* b2b  = (const float*)d_in[13];
  const float* Wih_f = (const float*)d_in[14];
  const float* Whh_f = (const float*)d_in[15];
  const float* bih_f = (const float*)d_in[16];
  const float* bhh_f = (const float*)d_in[17];
  const float* Wih_b = (const float*)d_in[18];
  const float* Whh_b = (const float*)d_in[19];
  const float* bih_b = (const float*)d_in[20];
  const float* bhh_b = (const float*)d_in[21];
  const float* Watt = (const float*)d_in[22];
  const float* batt = (const float*)d_in[23];
  const float* Wlin = (const float*)d_in[24];
  const float* blin = (const float*)d_in[25];
  const float* Wfc1 = (const float*)d_in[26];
  const float* bfc1 = (const float*)d_in[27];
  const float* Wfc2 = (const float*)d_in[28];
  const float* bfc2 = (const float*)d_in[29];
  float* out = (float*)d_out;

  const int N = in_sizes[0] / 128;
  const int E = in_sizes[1] / 2;
  const int* src = ei;
  const int* dst = ei + E;

  uint8_t* w8 = (uint8_t*)d_ws;
  size_t off = 0;
  auto alloc = [&](size_t bytes) -> void* {
    void* p = w8 + off;
    off = (off + bytes + 255) & ~(size_t)255;
    return p;
  };
  int*    deg    = (int*)   alloc((size_t)N*4);
  int*    fill   = (int*)   alloc((size_t)N*4);
  int*    indptr = (int*)   alloc(((size_t)N+1)*4);
  int*    col    = (int*)   alloc((size_t)E*4);
  int*    bsum   = (int*)   alloc(2048);
  int*    boffs  = (int*)   alloc(2048);
  float*  h1     = (float*) alloc((size_t)N*64*4);
  float*  h2     = (float*) alloc((size_t)N*64*4);
  float*  h3     = (float*) alloc((size_t)N*64*4);
  float*  aF     = (float*) alloc((size_t)3*N*4);
  float*  aB     = (float*) alloc((size_t)3*N*4);
  float*  vbuf   = (float*) alloc((size_t)N*4);
  double* part   = (double*)alloc(256*8);
  u16*    Wpf    = (u16*)   alloc((size_t)10*12*2*64*8*2);
  u16*    Wpb    = (u16*)   alloc((size_t)10*12*2*64*8*2);
  float4* Bpf    = (float4*)alloc((size_t)96*16);
  float4* Bpb    = (float4*)alloc((size_t)96*16);
  float*  P      = (float*) alloc((size_t)N*192*4);
  if (off > ws_size) return;
  float* ybuf = P;
  float* zbuf = P + (size_t)N*64;

  const size_t lds64  = 64  * 102 * 4;
  const size_t lds128 = 128 * 102 * 4;

  hipMemsetAsync(deg,  0, (size_t)N*4, stream);
  hipMemsetAsync(fill, 0, (size_t)N*4, stream);

  int gE = (E + 255) / 256;
  int nb1 = (N + 255) / 256;
  int gG = (N + 63) / 64;
  int gA = (N + 15) / 16;

  // weight prepack (independent of CSR)
  k_packWfrag<<<480, 256, 0, stream>>>(Wih_f, Whh_f, Wpf);
  k_packWfrag<<<480, 256, 0, stream>>>(Wih_b, Whh_b, Wpb);
  k_packB<<<1, 128, 0, stream>>>(bih_f, bhh_f, Bpf);
  k_packB<<<1, 128, 0, stream>>>(bih_b, bhh_b, Bpb);

  k_deg  <<<gE, 256, 0, stream>>>(dst, deg, E);
  k_scan1<<<nb1, 256, 0, stream>>>(deg, indptr, bsum, N);
  k_scan2<<<1, 512, 0, stream>>>(bsum, boffs, indptr, nb1, N);
  k_scan3<<<nb1, 256, 0, stream>>>(indptr, boffs, N);
  k_fill <<<gE, 256, 0, stream>>>(src, dst, indptr, fill, col, E);

  // ---- GIN layer 0 (transform-first: (x+aggX)@W = y+aggY) ----
  k_gemm<<<gG, TPB, lds128, stream>>>(x, W0a, nullptr, ybuf, 128, 64, 0, N);
  k_agg<64><<<gA, 256, 0, stream>>>(ybuf, indptr, col, b0a, zbuf, N);
  k_gemm<<<gG, TPB, lds64, stream>>>(zbuf, W0b, b0b, h1, 64, 64, 1, N);
  // ---- GIN layer 1 ----
  k_gemm<<<gG, TPB, lds64, stream>>>(h1, W1a, nullptr, ybuf, 64, 64, 0, N);
  k_agg<64><<<gA, 256, 0, stream>>>(ybuf, indptr, col, b1a, zbuf, N);
  k_gemm<<<gG, TPB, lds64, stream>>>(zbuf, W1b, b1b, h2, 64, 64, 1, N);
  // ---- GIN layer 2 ----
  k_gemm<<<gG, TPB, lds64, stream>>>(h2, W2a, nullptr, ybuf, 64, 64, 0, N);
  k_agg<64><<<gA, 256, 0, stream>>>(ybuf, indptr, col, b2a, zbuf, N);
  k_gemm<<<gG, TPB, lds64, stream>>>(zbuf, W2b, b2b, h3, 64, 64, 1, N);

  // ---- LSTM: both directions in one dispatch ----
  k_lstm4<<<2*gG, 512, 0, stream>>>(h1, h2, h3, Wpf, Wpb, Bpf, Bpb, Watt, batt,
                                    aF, aB, gG, N);

  // ---- JK attention + linear + fc1 + leaky ----
  k_jk<<<(N+15)/16, 256, 0, stream>>>(aF, aB, h1, h2, h3, Wlin, blin, Wfc1, bfc1, vbuf, N);

  // ---- final dot ----
  k_final1<<<256, 256, 0, stream>>>(Wfc2, vbuf, part, N);
  k_final2<<<1, 256, 0, stream>>>(part, bfc2, out);
}

// Round 9
// 864.696 us; speedup vs baseline: 4.7723x; 1.0453x over previous
//
#include <hip/hip_runtime.h>
#include <stdint.h>

#define TPB 128
typedef unsigned short u16;
typedef unsigned int u32;
using short8 = __attribute__((ext_vector_type(8))) short;
using f32x16 = __attribute__((ext_vector_type(16))) float;

__device__ __forceinline__ float sigf(float x){
  return __builtin_amdgcn_rcpf(1.0f + __expf(-x));
}
__device__ __forceinline__ float tanh_f(float x){
  return 1.0f - 2.0f*__builtin_amdgcn_rcpf(1.0f + __expf(2.0f*x));
}
__device__ __forceinline__ u16 f2bf(float f){
  u32 u = __float_as_uint(f);
  u += 0x7FFFu + ((u>>16)&1u);
  return (u16)(u>>16);
}
__device__ __forceinline__ float bf2f(u16 h){ return __uint_as_float(((u32)h)<<16); }

// ---------------- CSR build ----------------
__global__ void k_deg(const int* __restrict__ dst, int* __restrict__ deg, int E){
  int i = blockIdx.x*256 + threadIdx.x;
  if (i < E) atomicAdd(&deg[dst[i]], 1);
}

__global__ __launch_bounds__(256) void k_scan1(const int* __restrict__ deg, int* __restrict__ indptr,
                                               int* __restrict__ bsum, int N){
  __shared__ int s[256];
  int tid = threadIdx.x;
  int i = blockIdx.x*256 + tid;
  int v = (i < N) ? deg[i] : 0;
  s[tid] = v; __syncthreads();
  for (int off=1; off<256; off<<=1){
    int t = (tid>=off) ? s[tid-off] : 0;
    __syncthreads();
    s[tid] += t;
    __syncthreads();
  }
  if (i < N) indptr[i] = s[tid] - v;
  if (tid == 255) bsum[blockIdx.x] = s[255];
}

__global__ __launch_bounds__(512) void k_scan2(const int* __restrict__ bsum, int* __restrict__ boffs,
                                               int* __restrict__ indptr, int nb, int N){
  __shared__ int s[512];
  int tid = threadIdx.x;
  int v = (tid < nb) ? bsum[tid] : 0;
  s[tid] = v; __syncthreads();
  for (int off=1; off<512; off<<=1){
    int t = (tid>=off) ? s[tid-off] : 0;
    __syncthreads();
    s[tid] += t;
    __syncthreads();
  }
  boffs[tid] = s[tid] - v;
  if (tid == nb-1) indptr[N] = s[tid];
}

__global__ __launch_bounds__(256) void k_scan3(int* __restrict__ indptr, const int* __restrict__ boffs, int N){
  int i = blockIdx.x*256 + threadIdx.x;
  if (i < N) indptr[i] += boffs[blockIdx.x];
}

__global__ void k_fill(const int* __restrict__ src, const int* __restrict__ dst,
                       const int* __restrict__ indptr, int* __restrict__ fill,
                       int* __restrict__ col, int E){
  int i = blockIdx.x*256 + threadIdx.x;
  if (i < E){
    int d = dst[i];
    int r = atomicAdd(&fill[d], 1);
    col[indptr[d] + r] = src[i];
  }
}

// ---------------- aggregation: z[n] = relu( y[n] + sum_{nbr} y[src] + bias ) ----------------
template<int F>
__global__ __launch_bounds__(256) void k_agg(const float* __restrict__ y, const int* __restrict__ indptr,
                                             const int* __restrict__ col, const float* __restrict__ bias,
                                             float* __restrict__ z, int N){
  constexpr int TPN = F/4;
  constexpr int NPB = 256/TPN;
  int n = blockIdx.x*NPB + threadIdx.x/TPN;
  int lane = threadIdx.x % TPN;
  if (n >= N) return;
  const float4* hv = (const float4*)y;
  float4 acc = hv[(size_t)n*TPN + lane];
  int s = indptr[n], e = indptr[n+1];
  int p = s;
  for (; p + 8 <= e; p += 8){
    int c8[8];
    #pragma unroll
    for (int i=0;i<8;++i) c8[i] = col[p+i];
    #pragma unroll
    for (int i=0;i<8;++i){
      float4 x = hv[(size_t)c8[i]*TPN + lane];
      acc.x += x.x; acc.y += x.y; acc.z += x.z; acc.w += x.w;
    }
  }
  for (; p < e; ++p){
    float4 x = hv[(size_t)col[p]*TPN + lane];
    acc.x += x.x; acc.y += x.y; acc.z += x.z; acc.w += x.w;
  }
  float4 b4 = ((const float4*)bias)[lane];
  acc.x = fmaxf(acc.x + b4.x, 0.f);
  acc.y = fmaxf(acc.y + b4.y, 0.f);
  acc.z = fmaxf(acc.z + b4.z, 0.f);
  acc.w = fmaxf(acc.w + b4.w, 0.f);
  ((float4*)z)[(size_t)n*TPN + lane] = acc;
}

// ---------------- generic f32 GEMM ----------------
__global__ __launch_bounds__(TPB) void k_gemm(const float* __restrict__ A, const float* __restrict__ W,
                                              const float* __restrict__ bias, float* __restrict__ out,
                                              int K, int JC, int act, int N){
  extern __shared__ float sm[];
  float* As = sm;
  float* Ws = sm + (size_t)K*68;
  const int tid = threadIdx.x;
  const int tx = tid & 15, ty = tid >> 4;
  const int nb = blockIdx.x * 64;
  const int kq = K >> 2;
  for (int it = 0, idx = tid; it < (kq >> 1); ++it, idx += TPB){
    int nl = idx & 63, kk = idx >> 6;
    int k4 = kk << 2;
    int n = nb + nl;
    float4 v = make_float4(0.f,0.f,0.f,0.f);
    if (n < N) v = *(const float4*)(A + (size_t)n*K + k4);
    As[(size_t)(k4+0)*68 + nl] = v.x;
    As[(size_t)(k4+1)*68 + nl] = v.y;
    As[(size_t)(k4+2)*68 + nl] = v.z;
    As[(size_t)(k4+3)*68 + nl] = v.w;
  }
  const int ncc = JC >> 5;
  for (int cc = 0; cc < ncc; ++cc){
    __syncthreads();
    for (int it = 0, idx = tid; it < (kq >> 2); ++it, idx += TPB){
      int cl = idx & 31, kk = idx >> 5;
      int k4 = kk << 2;
      int j = (cc << 5) + cl;
      float4 v = *(const float4*)(W + (size_t)j*K + k4);
      Ws[(size_t)(k4+0)*34 + cl] = v.x;
      Ws[(size_t)(k4+1)*34 + cl] = v.y;
      Ws[(size_t)(k4+2)*34 + cl] = v.z;
      Ws[(size_t)(k4+3)*34 + cl] = v.w;
    }
    __syncthreads();
    float4 acc0 = make_float4(0,0,0,0), acc1 = acc0, acc2 = acc0, acc3 = acc0;
    #pragma unroll 4
    for (int k = 0; k < K; ++k){
      float4 a = *(const float4*)(As + (size_t)k*68 + (tx<<2));
      float2 w01 = *(const float2*)(Ws + (size_t)k*34 + (ty<<2));
      float2 w23 = *(const float2*)(Ws + (size_t)k*34 + (ty<<2) + 2);
      acc0.x = fmaf(a.x, w01.x, acc0.x); acc0.y = fmaf(a.x, w01.y, acc0.y);
      acc0.z = fmaf(a.x, w23.x, acc0.z); acc0.w = fmaf(a.x, w23.y, acc0.w);
      acc1.x = fmaf(a.y, w01.x, acc1.x); acc1.y = fmaf(a.y, w01.y, acc1.y);
      acc1.z = fmaf(a.y, w23.x, acc1.z); acc1.w = fmaf(a.y, w23.y, acc1.w);
      acc2.x = fmaf(a.z, w01.x, acc2.x); acc2.y = fmaf(a.z, w01.y, acc2.y);
      acc2.z = fmaf(a.z, w23.x, acc2.z); acc2.w = fmaf(a.z, w23.y, acc2.w);
      acc3.x = fmaf(a.w, w01.x, acc3.x); acc3.y = fmaf(a.w, w01.y, acc3.y);
      acc3.z = fmaf(a.w, w23.x, acc3.z); acc3.w = fmaf(a.w, w23.y, acc3.w);
    }
    int j0 = (cc << 5) + (ty << 2);
    float4 b4 = make_float4(0,0,0,0);
    if (bias) b4 = *(const float4*)(bias + j0);
    float4 r[4] = {acc0, acc1, acc2, acc3};
    #pragma unroll
    for (int i = 0; i < 4; ++i){
      int n = nb + (tx<<2) + i;
      if (n < N){
        float4 o;
        o.x = r[i].x + b4.x; o.y = r[i].y + b4.y; o.z = r[i].z + b4.z; o.w = r[i].w + b4.w;
        if (act){
          o.x = fmaxf(o.x, 0.f); o.y = fmaxf(o.y, 0.f);
          o.z = fmaxf(o.z, 0.f); o.w = fmaxf(o.w, 0.f);
        }
        *(float4*)(out + (size_t)n*JC + j0) = o;
      }
    }
  }
}

// ---------------- LSTM weight prepack: fragment-linear bf16, SINGLE plane ----------------
// Wp index = ((kt*12 + rt)*64 + l)*8 + i
__global__ __launch_bounds__(256) void k_packW1(const float* __restrict__ Wih, const float* __restrict__ Whh,
                                                u16* __restrict__ Wp){
  int idx = blockIdx.x*256 + threadIdx.x;
  if (idx >= 10*12*64*8) return;
  int i  = idx & 7;
  int l  = (idx>>3) & 63;
  int rt = (idx>>9) % 12;
  int kt = (idx>>9) / 12;
  int r  = rt*32 + (l & 31);
  int j  = r >> 2, g = r & 3;
  int row = g*96 + j;
  int k  = kt*16 + ((l>>5)<<3) + i;
  float v = (k < 64) ? Wih[row*64 + k] : Whh[row*96 + (k-64)];
  Wp[idx] = f2bf(v);
}

__global__ __launch_bounds__(128) void k_packB(const float* __restrict__ bih, const float* __restrict__ bhh,
                                               float4* __restrict__ Bp){
  int j = blockIdx.x*128 + threadIdx.x;
  if (j >= 96) return;
  Bp[j] = make_float4(bih[j]+bhh[j], bih[96+j]+bhh[96+j],
                      bih[192+j]+bhh[192+j], bih[288+j]+bhh[288+j]);
}

// ---------------- MFMA LSTM v5: 256 thr / 4 waves / 32 nodes / W single-plane ----------------
// Wave w = rtg (0..3): owns row-tiles rt = 3w..3w+2, all 32 cols. acc 3x16.
// X planes XH/XL (u16): uniform [kt(0..9)][slot(64)][8], slot XOR-swizzled by (kt*2+hi)&7.
//   kt 0..3 = x-part, kt 4..9 = h-part (j = (kt-4)*16 + hi*8 + i). 5120 u16/plane.
// hF[96][32] f32 h-exchange (conflict-free rows); restaged to frags each step.
// A-frags streamed frag-linear from L2, 2-deep prefetch. c state in 12 VGPRs.

__device__ __forceinline__ void ldx_regs(const float* __restrict__ seq, int blk, int N, int tid,
                                         float (&v)[8]){
  int node = tid >> 3;         // 0..31
  int kc = tid & 7;
  int n = blk*32 + node;
  if (n < N){
    const float4* s4 = (const float4*)(seq + (size_t)n*64 + kc*8);
    float4 a = s4[0], b = s4[1];
    v[0]=a.x; v[1]=a.y; v[2]=a.z; v[3]=a.w; v[4]=b.x; v[5]=b.y; v[6]=b.z; v[7]=b.w;
  } else {
    #pragma unroll
    for (int i=0;i<8;++i) v[i]=0.f;
  }
}

__device__ __forceinline__ void cvt8p(const float (&v)[8], u32 (&hw)[4], u32 (&lw)[4]){
  #pragma unroll
  for (int i=0;i<4;++i){
    u16 h0=f2bf(v[2*i]),   h1=f2bf(v[2*i+1]);
    u16 l0=f2bf(v[2*i]-bf2f(h0)), l1=f2bf(v[2*i+1]-bf2f(h1));
    hw[i]= (u32)h0 | ((u32)h1<<16);
    lw[i]= (u32)l0 | ((u32)l1<<16);
  }
}

__device__ __forceinline__ void stage_from_regs(const float (&v)[8], u16* __restrict__ XH,
                                                u16* __restrict__ XL, int tid){
  int node = tid >> 3;
  int kc = tid & 7;            // kc = kt*2 + hi
  u32 hw[4], lw[4];
  cvt8p(v, hw, lw);
  int kt = kc >> 1, hi = kc & 1;
  int sl = (((hi<<5) | node) ^ (kc & 7));
  int addr = (kt<<9) + (sl<<3);
  *(uint4*)(XH + addr) = make_uint4(hw[0],hw[1],hw[2],hw[3]);
  *(uint4*)(XL + addr) = make_uint4(lw[0],lw[1],lw[2],lw[3]);
}

__device__ __forceinline__ void restage_h(const float (*hF)[32], u16* __restrict__ XH,
                                          u16* __restrict__ XL, int tid){
  int node = tid & 31;
  #pragma unroll
  for (int q = 0; q < 2; ++q){
    int cc = (tid >> 5) + q*8;
    if (cc < 12){
      int kth = cc >> 1, hi = cc & 1;
      int ktG = kth + 4;
      float v[8];
      #pragma unroll
      for (int i=0;i<8;++i) v[i] = hF[cc*8 + i][node];
      u32 hw[4], lw[4];
      cvt8p(v, hw, lw);
      int sl = (((hi<<5) | node) ^ ((2*ktG + hi) & 7));
      int addr = (ktG<<9) + (sl<<3);
      *(uint4*)(XH + addr) = make_uint4(hw[0],hw[1],hw[2],hw[3]);
      *(uint4*)(XL + addr) = make_uint4(lw[0],lw[1],lw[2],lw[3]);
    }
  }
}

template<int FIRST, int WRITEH>
__device__ __forceinline__ float lstm_step5(const u16* __restrict__ Wp,
    const float4* __restrict__ Bp, const float* __restrict__ WattW,
    const u16* __restrict__ XH, const u16* __restrict__ XL, float (*hF)[32],
    float (&c)[12], int rtg, int l)
{
  constexpr int NKT = FIRST ? 4 : 10;
  const int hi = l >> 5;
  const int col = l & 31;
  f32x16 acc[3];
  #pragma unroll
  for (int t=0;t<3;++t)
    #pragma unroll
    for (int r=0;r<16;++r) acc[t][r] = 0.f;

  const u16* wbase = Wp + (size_t)(rtg*3)*512 + ((size_t)l<<3);
  short8 A0[3], A1[3];
  #pragma unroll
  for (int ti=0;ti<3;++ti) A0[ti] = *(const short8*)(wbase + (size_t)ti*512);
  #pragma unroll
  for (int kt = 0; kt < NKT; ++kt){
    short8 (&Ac)[3] = (kt & 1) ? A1 : A0;
    short8 (&An)[3] = (kt & 1) ? A0 : A1;
    if (kt + 1 < NKT){
      const u16* wk = wbase + (size_t)(kt+1)*6144;
      #pragma unroll
      for (int ti=0;ti<3;++ti) An[ti] = *(const short8*)(wk + (size_t)ti*512);
    }
    int sl = l ^ (((kt<<1) + hi) & 7);
    int baddr = (kt<<9) + (sl<<3);
    short8 Bh = *(const short8*)(XH + baddr);
    short8 Bl = *(const short8*)(XL + baddr);
    __builtin_amdgcn_s_setprio(1);
    acc[0] = __builtin_amdgcn_mfma_f32_32x32x16_bf16(Ac[0], Bh, acc[0], 0,0,0);
    acc[1] = __builtin_amdgcn_mfma_f32_32x32x16_bf16(Ac[1], Bh, acc[1], 0,0,0);
    acc[2] = __builtin_amdgcn_mfma_f32_32x32x16_bf16(Ac[2], Bh, acc[2], 0,0,0);
    acc[0] = __builtin_amdgcn_mfma_f32_32x32x16_bf16(Ac[0], Bl, acc[0], 0,0,0);
    acc[1] = __builtin_amdgcn_mfma_f32_32x32x16_bf16(Ac[1], Bl, acc[1], 0,0,0);
    acc[2] = __builtin_amdgcn_mfma_f32_32x32x16_bf16(Ac[2], Bl, acc[2], 0,0,0);
    __builtin_amdgcn_s_setprio(0);
  }

  float aP = 0.f;
  #pragma unroll
  for (int ti=0;ti<3;++ti){
    #pragma unroll
    for (int rg=0; rg<4; ++rg){
      const int j = (rtg*3+ti)*8 + 2*rg + hi;
      float4 bv = Bp[j];
      float gi = acc[ti][rg*4+0] + bv.x;
      float gf = acc[ti][rg*4+1] + bv.y;
      float gg = acc[ti][rg*4+2] + bv.z;
      float go = acc[ti][rg*4+3] + bv.w;
      const int ci = ti*4 + rg;
      float cp = FIRST ? 0.f : c[ci];
      float cn = sigf(gf)*cp + sigf(gi)*tanh_f(gg);
      float hh = sigf(go)*tanh_f(cn);
      c[ci] = cn;
      aP = fmaf(hh, WattW[j], aP);
      if (WRITEH) hF[j][col] = hh;
    }
  }
  return aP;
}

__global__ __launch_bounds__(256,4) void k_lstm5(
    const float* __restrict__ h1, const float* __restrict__ h2, const float* __restrict__ h3,
    const u16* __restrict__ Wpf, const u16* __restrict__ Wpb,
    const float4* __restrict__ Bpf, const float4* __restrict__ Bpb,
    const float* __restrict__ Watt, const float* __restrict__ batt,
    float* __restrict__ aF, float* __restrict__ aB, int gL, int N)
{
  __shared__ u16 XH[5120];
  __shared__ u16 XL[5120];
  __shared__ float hF[96][32];
  __shared__ float sAl[4][3][32];
  const int tid = threadIdx.x;
  const int l = tid & 63;
  const int rtg = __builtin_amdgcn_readfirstlane(tid >> 6);
  const int dir = (blockIdx.x >= gL) ? 1 : 0;
  const int blk = blockIdx.x - dir*gL;
  const float* sA = dir ? h3 : h1;
  const float* sC = dir ? h1 : h3;
  const u16* Wp = dir ? Wpb : Wpf;
  const float4* Bp = dir ? Bpb : Bpf;
  const float* WattW = Watt + dir*96;
  float* aD = dir ? aB : aF;
  float c[12];
  float a0, a1, a2;
  float xv[8];

  // prologue: stage x0; pre-issue x1 loads
  ldx_regs(sA, blk, N, tid, xv);
  stage_from_regs(xv, XH, XL, tid);
  ldx_regs(h2, blk, N, tid, xv);
  __syncthreads();

  a0 = lstm_step5<1,1>(Wp, Bp, WattW, XH, XL, hF, c, rtg, l);
  __syncthreads();
  stage_from_regs(xv, XH, XL, tid);
  restage_h(hF, XH, XL, tid);
  ldx_regs(sC, blk, N, tid, xv);
  __syncthreads();

  a1 = lstm_step5<0,1>(Wp, Bp, WattW, XH, XL, hF, c, rtg, l);
  __syncthreads();
  stage_from_regs(xv, XH, XL, tid);
  restage_h(hF, XH, XL, tid);
  __syncthreads();

  a2 = lstm_step5<0,0>(Wp, Bp, WattW, XH, XL, hF, c, rtg, l);

  // alpha reduce: lanes l and l^32 hold complementary gate halves of same node
  a0 += __shfl_xor(a0, 32);
  a1 += __shfl_xor(a1, 32);
  a2 += __shfl_xor(a2, 32);
  if (l < 32){
    sAl[rtg][0][l] = a0;
    sAl[rtg][1][l] = a1;
    sAl[rtg][2][l] = a2;
  }
  __syncthreads();
  if (tid < 96){
    int s = tid >> 5;
    int node = tid & 31;
    int n = blk*32 + node;
    if (n < N){
      float sum = sAl[0][s][node] + sAl[1][s][node]
                + sAl[2][s][node] + sAl[3][s][node];
      int slice = dir ? (2 - s) : s;
      float v = dir ? sum : (batt[0] + sum);
      aD[(size_t)slice*N + n] = v;
    }
  }
}

// ---------------- JK softmax + xjk + Wlin + Wfc1 + leaky (16 nodes/block) ----------------
__global__ __launch_bounds__(256) void k_jk(const float* __restrict__ aF, const float* __restrict__ aB,
                                            const float* __restrict__ h1, const float* __restrict__ h2,
                                            const float* __restrict__ h3,
                                            const float* __restrict__ Wlin, const float* __restrict__ blin,
                                            const float* __restrict__ Wfc1, const float* __restrict__ bfc1,
                                            float* __restrict__ vout, int N){
  __shared__ float sWl[64*65];
  __shared__ float sX[4][64];
  int tid = threadIdx.x;
  for (int idx = tid; idx < 1024; idx += 256){
    int j = idx >> 4;
    int c4 = (idx & 15) << 2;
    float4 v = *(const float4*)(Wlin + (size_t)j*64 + c4);
    sWl[j*65 + c4+0] = v.x; sWl[j*65 + c4+1] = v.y;
    sWl[j*65 + c4+2] = v.z; sWl[j*65 + c4+3] = v.w;
  }
  __syncthreads();
  int ln = tid >> 6, j = tid & 63;
  float wf1 = Wfc1[j];
  float bl = blin[j];
  for (int ib = 0; ib < 4; ++ib){
    int n = blockIdx.x*16 + ib*4 + ln;
    bool ok = n < N;
    float xj = 0.f;
    if (ok){
      float a0 = aF[n] + aB[n];
      float a1 = aF[(size_t)N + n] + aB[(size_t)N + n];
      float a2 = aF[(size_t)2*N + n] + aB[(size_t)2*N + n];
      float m = fmaxf(a0, fmaxf(a1, a2));
      float e0 = __expf(a0-m), e1 = __expf(a1-m), e2 = __expf(a2-m);
      float inv = __builtin_amdgcn_rcpf(e0+e1+e2);
      float w0 = e0*inv, w1 = e1*inv, w2 = e2*inv;
      xj = w0*h1[(size_t)n*64 + j] + w1*h2[(size_t)n*64 + j] + w2*h3[(size_t)n*64 + j];
    }
    sX[ln][j] = xj;
    __syncthreads();
    float acc = bl;
    #pragma unroll 8
    for (int cc = 0; cc < 64; ++cc) acc = fmaf(sX[ln][cc], sWl[j*65 + cc], acc);
    float r = acc * wf1;
    #pragma unroll
    for (int off = 32; off > 0; off >>= 1) r += __shfl_down(r, off);
    if (j == 0 && ok){
      float vv = r + bfc1[0];
      vout[n] = vv >= 0.f ? vv : 0.01f*vv;
    }
    __syncthreads();
  }
}

// ---------------- final dot (deterministic two-stage, f64 accum) ----------------
__global__ __launch_bounds__(256) void k_final1(const float* __restrict__ w, const float* __restrict__ v,
                                                double* __restrict__ part, int N){
  __shared__ double sd[256];
  int tid = threadIdx.x;
  double a = 0.0;
  for (int i = blockIdx.x*256 + tid; i < N; i += 256*256)
    a += (double)(w[i] * v[i]);
  sd[tid] = a; __syncthreads();
  for (int off = 128; off > 0; off >>= 1){
    if (tid < off) sd[tid] += sd[tid + off];
    __syncthreads();
  }
  if (tid == 0) part[blockIdx.x] = sd[0];
}

__global__ __launch_bounds__(256) void k_final2(const double* __restrict__ part, const float* __restrict__ bfc2,
                                                float* __restrict__ out){
  __shared__ double sd[256];
  int tid = threadIdx.x;
  sd[tid] = part[tid]; __syncthreads();
  for (int off = 128; off > 0; off >>= 1){
    if (tid < off) sd[tid] += sd[tid + off];
    __syncthreads();
  }
  if (tid == 0) out[0] = (float)(sd[0] + (double)bfc2[0]);
}

// ---------------- host ----------------
extern "C" void kernel_launch(void* const* d_in, const int* in_sizes, int n_in,
                              void* d_out, int out_size, void* d_ws, size_t ws_size,
                              hipStream_t stream){
  const float* x    = (const float*)d_in[0];
  const int*   ei   = (const int*)d_in[1];
  const float* W0a  = (const float*)d_in[2];
  const float* b0a  = (const float*)d_in[3];
  const float* W0b  = (const float*)d_in[4];
  const float* b0b  = (const float*)d_in[5];
  const float* W1a  = (const float*)d_in[6];
  const float* b1a  = (const float*)d_in[7];
  const float* W1b  = (const float*)d_in[8];
  const float* b1b  = (const float*)d_in[9];
  const float* W2a  = (const float*)d_in[10];
  const float* b2a  = (const float*)d_in[11];
  const float* W2b  = (const float*)d_in[12];
  const float* b2b  = (const float*)d_in[13];
  const float* Wih_f = (const float*)d_in[14];
  const float* Whh_f = (const float*)d_in[15];
  const float* bih_f = (const float*)d_in[16];
  const float* bhh_f = (const float*)d_in[17];
  const float* Wih_b = (const float*)d_in[18];
  const float* Whh_b = (const float*)d_in[19];
  const float* bih_b = (const float*)d_in[20];
  const float* bhh_b = (const float*)d_in[21];
  const float* Watt = (const float*)d_in[22];
  const float* batt = (const float*)d_in[23];
  const float* Wlin = (const float*)d_in[24];
  const float* blin = (const float*)d_in[25];
  const float* Wfc1 = (const float*)d_in[26];
  const float* bfc1 = (const float*)d_in[27];
  const float* Wfc2 = (const float*)d_in[28];
  const float* bfc2 = (const float*)d_in[29];
  float* out = (float*)d_out;

  const int N = in_sizes[0] / 128;
  const int E = in_sizes[1] / 2;
  const int* src = ei;
  const int* dst = ei + E;

  uint8_t* w8 = (uint8_t*)d_ws;
  size_t off = 0;
  auto alloc = [&](size_t bytes) -> void* {
    void* p = w8 + off;
    off = (off + bytes + 255) & ~(size_t)255;
    return p;
  };
  int*    deg    = (int*)   alloc((size_t)N*4);
  int*    fill   = (int*)   alloc((size_t)N*4);
  int*    indptr = (int*)   alloc(((size_t)N+1)*4);
  int*    col    = (int*)   alloc((size_t)E*4);
  int*    bsum   = (int*)   alloc(2048);
  int*    boffs  = (int*)   alloc(2048);
  float*  h1     = (float*) alloc((size_t)N*64*4);
  float*  h2     = (float*) alloc((size_t)N*64*4);
  float*  h3     = (float*) alloc((size_t)N*64*4);
  float*  aF     = (float*) alloc((size_t)3*N*4);
  float*  aB     = (float*) alloc((size_t)3*N*4);
  float*  vbuf   = (float*) alloc((size_t)N*4);
  double* part   = (double*)alloc(256*8);
  u16*    Wpf    = (u16*)   alloc((size_t)10*12*64*8*2);
  u16*    Wpb    = (u16*)   alloc((size_t)10*12*64*8*2);
  float4* Bpf    = (float4*)alloc((size_t)96*16);
  float4* Bpb    = (float4*)alloc((size_t)96*16);
  float*  P      = (float*) alloc((size_t)N*192*4);
  if (off > ws_size) return;
  float* ybuf = P;
  float* zbuf = P + (size_t)N*64;

  const size_t lds64  = 64  * 102 * 4;
  const size_t lds128 = 128 * 102 * 4;

  hipMemsetAsync(deg,  0, (size_t)N*4, stream);
  hipMemsetAsync(fill, 0, (size_t)N*4, stream);

  int gE = (E + 255) / 256;
  int nb1 = (N + 255) / 256;
  int gG = (N + 63) / 64;
  int gA = (N + 15) / 16;
  int gL = (N + 31) / 32;

  // weight prepack (independent of CSR)
  k_packW1<<<240, 256, 0, stream>>>(Wih_f, Whh_f, Wpf);
  k_packW1<<<240, 256, 0, stream>>>(Wih_b, Whh_b, Wpb);
  k_packB<<<1, 128, 0, stream>>>(bih_f, bhh_f, Bpf);
  k_packB<<<1, 128, 0, stream>>>(bih_b, bhh_b, Bpb);

  k_deg  <<<gE, 256, 0, stream>>>(dst, deg, E);
  k_scan1<<<nb1, 256, 0, stream>>>(deg, indptr, bsum, N);
  k_scan2<<<1, 512, 0, stream>>>(bsum, boffs, indptr, nb1, N);
  k_scan3<<<nb1, 256, 0, stream>>>(indptr, boffs, N);
  k_fill <<<gE, 256, 0, stream>>>(src, dst, indptr, fill, col, E);

  // ---- GIN layer 0 (transform-first: (x+aggX)@W = y+aggY) ----
  k_gemm<<<gG, TPB, lds128, stream>>>(x, W0a, nullptr, ybuf, 128, 64, 0, N);
  k_agg<64><<<gA, 256, 0, stream>>>(ybuf, indptr, col, b0a, zbuf, N);
  k_gemm<<<gG, TPB, lds64, stream>>>(zbuf, W0b, b0b, h1, 64, 64, 1, N);
  // ---- GIN layer 1 ----
  k_gemm<<<gG, TPB, lds64, stream>>>(h1, W1a, nullptr, ybuf, 64, 64, 0, N);
  k_agg<64><<<gA, 256, 0, stream>>>(ybuf, indptr, col, b1a, zbuf, N);
  k_gemm<<<gG, TPB, lds64, stream>>>(zbuf, W1b, b1b, h2, 64, 64, 1, N);
  // ---- GIN layer 2 ----
  k_gemm<<<gG, TPB, lds64, stream>>>(h2, W2a, nullptr, ybuf, 64, 64, 0, N);
  k_agg<64><<<gA, 256, 0, stream>>>(ybuf, indptr, col, b2a, zbuf, N);
  k_gemm<<<gG, TPB, lds64, stream>>>(zbuf, W2b, b2b, h3, 64, 64, 1, N);

  // ---- LSTM: both directions in one dispatch ----
  k_lstm5<<<2*gL, 256, 0, stream>>>(h1, h2, h3, Wpf, Wpb, Bpf, Bpb, Watt, batt,
                                    aF, aB, gL, N);

  // ---- JK attention + linear + fc1 + leaky ----
  k_jk<<<(N+15)/16, 256, 0, stream>>>(aF, aB, h1, h2, h3, Wlin, blin, Wfc1, bfc1, vbuf, N);

  // ---- final dot ----
  k_final1<<<256, 256, 0, stream>>>(Wfc2, vbuf, part, N);
  k_final2<<<1, 256, 0, stream>>>(part, bfc2, out);
}

// Round 10
// 797.190 us; speedup vs baseline: 5.1764x; 1.0847x over previous
//
#include <hip/hip_runtime.h>
#include <stdint.h>

#define TPB 128
typedef unsigned short u16;
typedef unsigned int u32;
using short8 = __attribute__((ext_vector_type(8))) short;
using f32x16 = __attribute__((ext_vector_type(16))) float;

__device__ __forceinline__ float sigf(float x){
  return __builtin_amdgcn_rcpf(1.0f + __expf(-x));
}
__device__ __forceinline__ float tanh_f(float x){
  return 1.0f - 2.0f*__builtin_amdgcn_rcpf(1.0f + __expf(2.0f*x));
}
__device__ __forceinline__ u16 f2bf(float f){
  u32 u = __float_as_uint(f);
  u += 0x7FFFu + ((u>>16)&1u);
  return (u16)(u>>16);
}
__device__ __forceinline__ float bf2f(u16 h){ return __uint_as_float(((u32)h)<<16); }

// ---------------- CSR build ----------------
__global__ void k_deg(const int* __restrict__ dst, int* __restrict__ deg, int E){
  int i = blockIdx.x*256 + threadIdx.x;
  if (i < E) atomicAdd(&deg[dst[i]], 1);
}

__global__ __launch_bounds__(256) void k_scan1(const int* __restrict__ deg, int* __restrict__ indptr,
                                               int* __restrict__ bsum, int N){
  __shared__ int s[256];
  int tid = threadIdx.x;
  int i = blockIdx.x*256 + tid;
  int v = (i < N) ? deg[i] : 0;
  s[tid] = v; __syncthreads();
  for (int off=1; off<256; off<<=1){
    int t = (tid>=off) ? s[tid-off] : 0;
    __syncthreads();
    s[tid] += t;
    __syncthreads();
  }
  if (i < N) indptr[i] = s[tid] - v;
  if (tid == 255) bsum[blockIdx.x] = s[255];
}

__global__ __launch_bounds__(512) void k_scan2(const int* __restrict__ bsum, int* __restrict__ boffs,
                                               int* __restrict__ indptr, int nb, int N){
  __shared__ int s[512];
  int tid = threadIdx.x;
  int v = (tid < nb) ? bsum[tid] : 0;
  s[tid] = v; __syncthreads();
  for (int off=1; off<512; off<<=1){
    int t = (tid>=off) ? s[tid-off] : 0;
    __syncthreads();
    s[tid] += t;
    __syncthreads();
  }
  boffs[tid] = s[tid] - v;
  if (tid == nb-1) indptr[N] = s[tid];
}

__global__ __launch_bounds__(256) void k_scan3(int* __restrict__ indptr, const int* __restrict__ boffs, int N){
  int i = blockIdx.x*256 + threadIdx.x;
  if (i < N) indptr[i] += boffs[blockIdx.x];
}

__global__ void k_fill(const int* __restrict__ src, const int* __restrict__ dst,
                       const int* __restrict__ indptr, int* __restrict__ fill,
                       int* __restrict__ col, int E){
  int i = blockIdx.x*256 + threadIdx.x;
  if (i < E){
    int d = dst[i];
    int r = atomicAdd(&fill[d], 1);
    col[indptr[d] + r] = src[i];
  }
}

// ---------------- aggregation: z[n] = relu( y[n] + sum_{nbr} y[src] + bias ) ----------------
template<int F>
__global__ __launch_bounds__(256) void k_agg(const float* __restrict__ y, const int* __restrict__ indptr,
                                             const int* __restrict__ col, const float* __restrict__ bias,
                                             float* __restrict__ z, int N){
  constexpr int TPN = F/4;
  constexpr int NPB = 256/TPN;
  int n = blockIdx.x*NPB + threadIdx.x/TPN;
  int lane = threadIdx.x % TPN;
  if (n >= N) return;
  const float4* hv = (const float4*)y;
  float4 acc = hv[(size_t)n*TPN + lane];
  int s = indptr[n], e = indptr[n+1];
  int p = s;
  for (; p + 8 <= e; p += 8){
    int c8[8];
    #pragma unroll
    for (int i=0;i<8;++i) c8[i] = col[p+i];
    #pragma unroll
    for (int i=0;i<8;++i){
      float4 x = hv[(size_t)c8[i]*TPN + lane];
      acc.x += x.x; acc.y += x.y; acc.z += x.z; acc.w += x.w;
    }
  }
  for (; p < e; ++p){
    float4 x = hv[(size_t)col[p]*TPN + lane];
    acc.x += x.x; acc.y += x.y; acc.z += x.z; acc.w += x.w;
  }
  float4 b4 = ((const float4*)bias)[lane];
  acc.x = fmaxf(acc.x + b4.x, 0.f);
  acc.y = fmaxf(acc.y + b4.y, 0.f);
  acc.z = fmaxf(acc.z + b4.z, 0.f);
  acc.w = fmaxf(acc.w + b4.w, 0.f);
  ((float4*)z)[(size_t)n*TPN + lane] = acc;
}

// ---------------- generic f32 GEMM ----------------
__global__ __launch_bounds__(TPB) void k_gemm(const float* __restrict__ A, const float* __restrict__ W,
                                              const float* __restrict__ bias, float* __restrict__ out,
                                              int K, int JC, int act, int N){
  extern __shared__ float sm[];
  float* As = sm;
  float* Ws = sm + (size_t)K*68;
  const int tid = threadIdx.x;
  const int tx = tid & 15, ty = tid >> 4;
  const int nb = blockIdx.x * 64;
  const int kq = K >> 2;
  for (int it = 0, idx = tid; it < (kq >> 1); ++it, idx += TPB){
    int nl = idx & 63, kk = idx >> 6;
    int k4 = kk << 2;
    int n = nb + nl;
    float4 v = make_float4(0.f,0.f,0.f,0.f);
    if (n < N) v = *(const float4*)(A + (size_t)n*K + k4);
    As[(size_t)(k4+0)*68 + nl] = v.x;
    As[(size_t)(k4+1)*68 + nl] = v.y;
    As[(size_t)(k4+2)*68 + nl] = v.z;
    As[(size_t)(k4+3)*68 + nl] = v.w;
  }
  const int ncc = JC >> 5;
  for (int cc = 0; cc < ncc; ++cc){
    __syncthreads();
    for (int it = 0, idx = tid; it < (kq >> 2); ++it, idx += TPB){
      int cl = idx & 31, kk = idx >> 5;
      int k4 = kk << 2;
      int j = (cc << 5) + cl;
      float4 v = *(const float4*)(W + (size_t)j*K + k4);
      Ws[(size_t)(k4+0)*34 + cl] = v.x;
      Ws[(size_t)(k4+1)*34 + cl] = v.y;
      Ws[(size_t)(k4+2)*34 + cl] = v.z;
      Ws[(size_t)(k4+3)*34 + cl] = v.w;
    }
    __syncthreads();
    float4 acc0 = make_float4(0,0,0,0), acc1 = acc0, acc2 = acc0, acc3 = acc0;
    #pragma unroll 4
    for (int k = 0; k < K; ++k){
      float4 a = *(const float4*)(As + (size_t)k*68 + (tx<<2));
      float2 w01 = *(const float2*)(Ws + (size_t)k*34 + (ty<<2));
      float2 w23 = *(const float2*)(Ws + (size_t)k*34 + (ty<<2) + 2);
      acc0.x = fmaf(a.x, w01.x, acc0.x); acc0.y = fmaf(a.x, w01.y, acc0.y);
      acc0.z = fmaf(a.x, w23.x, acc0.z); acc0.w = fmaf(a.x, w23.y, acc0.w);
      acc1.x = fmaf(a.y, w01.x, acc1.x); acc1.y = fmaf(a.y, w01.y, acc1.y);
      acc1.z = fmaf(a.y, w23.x, acc1.z); acc1.w = fmaf(a.y, w23.y, acc1.w);
      acc2.x = fmaf(a.z, w01.x, acc2.x); acc2.y = fmaf(a.z, w01.y, acc2.y);
      acc2.z = fmaf(a.z, w23.x, acc2.z); acc2.w = fmaf(a.z, w23.y, acc2.w);
      acc3.x = fmaf(a.w, w01.x, acc3.x); acc3.y = fmaf(a.w, w01.y, acc3.y);
      acc3.z = fmaf(a.w, w23.x, acc3.z); acc3.w = fmaf(a.w, w23.y, acc3.w);
    }
    int j0 = (cc << 5) + (ty << 2);
    float4 b4 = make_float4(0,0,0,0);
    if (bias) b4 = *(const float4*)(bias + j0);
    float4 r[4] = {acc0, acc1, acc2, acc3};
    #pragma unroll
    for (int i = 0; i < 4; ++i){
      int n = nb + (tx<<2) + i;
      if (n < N){
        float4 o;
        o.x = r[i].x + b4.x; o.y = r[i].y + b4.y; o.z = r[i].z + b4.z; o.w = r[i].w + b4.w;
        if (act){
          o.x = fmaxf(o.x, 0.f); o.y = fmaxf(o.y, 0.f);
          o.z = fmaxf(o.z, 0.f); o.w = fmaxf(o.w, 0.f);
        }
        *(float4*)(out + (size_t)n*JC + j0) = o;
      }
    }
  }
}

// ---------------- LSTM weight prepack: fragment-linear bf16, SINGLE plane ----------------
// Wp index = ((kt*12 + rt)*64 + l)*8 + i
__global__ __launch_bounds__(256) void k_packW1(const float* __restrict__ Wih, const float* __restrict__ Whh,
                                                u16* __restrict__ Wp){
  int idx = blockIdx.x*256 + threadIdx.x;
  if (idx >= 10*12*64*8) return;
  int i  = idx & 7;
  int l  = (idx>>3) & 63;
  int rt = (idx>>9) % 12;
  int kt = (idx>>9) / 12;
  int r  = rt*32 + (l & 31);
  int j  = r >> 2, g = r & 3;
  int row = g*96 + j;
  int k  = kt*16 + ((l>>5)<<3) + i;
  float v = (k < 64) ? Wih[row*64 + k] : Whh[row*96 + (k-64)];
  Wp[idx] = f2bf(v);
}

__global__ __launch_bounds__(128) void k_packB(const float* __restrict__ bih, const float* __restrict__ bhh,
                                               float4* __restrict__ Bp){
  int j = blockIdx.x*128 + threadIdx.x;
  if (j >= 96) return;
  Bp[j] = make_float4(bih[j]+bhh[j], bih[96+j]+bhh[96+j],
                      bih[192+j]+bhh[192+j], bih[288+j]+bhh[288+j]);
}

// ---------------- MFMA LSTM v5b: 256 thr / 4 waves / 32 nodes / single-buffered A ----------------
// Wave w = rtg (0..3): owns row-tiles rt = 3w..3w+2, all 32 cols. acc 3x16.
// X planes XH/XL (u16): uniform [kt(0..9)][slot(64)][8], slot XOR-swizzled by (kt*2+hi)&7.
// hF[96][32] f32 h-exchange (conflict-free rows); restaged to frags each step.
// A-frags streamed frag-linear from L2 (single-buffered; TLP at 4 blocks/CU hides latency).

__device__ __forceinline__ void ldx_regs(const float* __restrict__ seq, int blk, int N, int tid,
                                         float (&v)[8]){
  int node = tid >> 3;         // 0..31
  int kc = tid & 7;
  int n = blk*32 + node;
  if (n < N){
    const float4* s4 = (const float4*)(seq + (size_t)n*64 + kc*8);
    float4 a = s4[0], b = s4[1];
    v[0]=a.x; v[1]=a.y; v[2]=a.z; v[3]=a.w; v[4]=b.x; v[5]=b.y; v[6]=b.z; v[7]=b.w;
  } else {
    #pragma unroll
    for (int i=0;i<8;++i) v[i]=0.f;
  }
}

__device__ __forceinline__ void cvt8p(const float (&v)[8], u32 (&hw)[4], u32 (&lw)[4]){
  #pragma unroll
  for (int i=0;i<4;++i){
    u16 h0=f2bf(v[2*i]),   h1=f2bf(v[2*i+1]);
    u16 l0=f2bf(v[2*i]-bf2f(h0)), l1=f2bf(v[2*i+1]-bf2f(h1));
    hw[i]= (u32)h0 | ((u32)h1<<16);
    lw[i]= (u32)l0 | ((u32)l1<<16);
  }
}

__device__ __forceinline__ void stage_from_regs(const float (&v)[8], u16* __restrict__ XH,
                                                u16* __restrict__ XL, int tid){
  int node = tid >> 3;
  int kc = tid & 7;            // kc = kt*2 + hi
  u32 hw[4], lw[4];
  cvt8p(v, hw, lw);
  int kt = kc >> 1, hi = kc & 1;
  int sl = (((hi<<5) | node) ^ (kc & 7));
  int addr = (kt<<9) + (sl<<3);
  *(uint4*)(XH + addr) = make_uint4(hw[0],hw[1],hw[2],hw[3]);
  *(uint4*)(XL + addr) = make_uint4(lw[0],lw[1],lw[2],lw[3]);
}

__device__ __forceinline__ void restage_h(const float (*hF)[32], u16* __restrict__ XH,
                                          u16* __restrict__ XL, int tid){
  int node = tid & 31;
  #pragma unroll
  for (int q = 0; q < 2; ++q){
    int cc = (tid >> 5) + q*8;
    if (cc < 12){
      int kth = cc >> 1, hi = cc & 1;
      int ktG = kth + 4;
      float v[8];
      #pragma unroll
      for (int i=0;i<8;++i) v[i] = hF[cc*8 + i][node];
      u32 hw[4], lw[4];
      cvt8p(v, hw, lw);
      int sl = (((hi<<5) | node) ^ ((2*ktG + hi) & 7));
      int addr = (ktG<<9) + (sl<<3);
      *(uint4*)(XH + addr) = make_uint4(hw[0],hw[1],hw[2],hw[3]);
      *(uint4*)(XL + addr) = make_uint4(lw[0],lw[1],lw[2],lw[3]);
    }
  }
}

template<int FIRST, int WRITEH>
__device__ __forceinline__ float lstm_step5(const u16* __restrict__ Wp,
    const float4* __restrict__ Bp, const float* __restrict__ WattW,
    const u16* __restrict__ XH, const u16* __restrict__ XL, float (*hF)[32],
    float (&c)[12], int rtg, int l)
{
  constexpr int NKT = FIRST ? 4 : 10;
  const int hi = l >> 5;
  const int col = l & 31;
  f32x16 acc[3];
  #pragma unroll
  for (int t=0;t<3;++t)
    #pragma unroll
    for (int r=0;r<16;++r) acc[t][r] = 0.f;

  const u16* wbase = Wp + (size_t)(rtg*3)*512 + ((size_t)l<<3);
  #pragma unroll
  for (int kt = 0; kt < NKT; ++kt){
    const u16* wk = wbase + (size_t)kt*6144;
    short8 A0 = *(const short8*)(wk);
    short8 A1 = *(const short8*)(wk + 512);
    short8 A2 = *(const short8*)(wk + 1024);
    int sl = l ^ (((kt<<1) + hi) & 7);
    int baddr = (kt<<9) + (sl<<3);
    short8 Bh = *(const short8*)(XH + baddr);
    short8 Bl = *(const short8*)(XL + baddr);
    __builtin_amdgcn_s_setprio(1);
    acc[0] = __builtin_amdgcn_mfma_f32_32x32x16_bf16(A0, Bh, acc[0], 0,0,0);
    acc[1] = __builtin_amdgcn_mfma_f32_32x32x16_bf16(A1, Bh, acc[1], 0,0,0);
    acc[2] = __builtin_amdgcn_mfma_f32_32x32x16_bf16(A2, Bh, acc[2], 0,0,0);
    acc[0] = __builtin_amdgcn_mfma_f32_32x32x16_bf16(A0, Bl, acc[0], 0,0,0);
    acc[1] = __builtin_amdgcn_mfma_f32_32x32x16_bf16(A1, Bl, acc[1], 0,0,0);
    acc[2] = __builtin_amdgcn_mfma_f32_32x32x16_bf16(A2, Bl, acc[2], 0,0,0);
    __builtin_amdgcn_s_setprio(0);
  }

  float aP = 0.f;
  #pragma unroll
  for (int ti=0;ti<3;++ti){
    #pragma unroll
    for (int rg=0; rg<4; ++rg){
      const int j = (rtg*3+ti)*8 + 2*rg + hi;
      float4 bv = Bp[j];
      float gi = acc[ti][rg*4+0] + bv.x;
      float gf = acc[ti][rg*4+1] + bv.y;
      float gg = acc[ti][rg*4+2] + bv.z;
      float go = acc[ti][rg*4+3] + bv.w;
      const int ci = ti*4 + rg;
      float cp = FIRST ? 0.f : c[ci];
      float cn = sigf(gf)*cp + sigf(gi)*tanh_f(gg);
      float hh = sigf(go)*tanh_f(cn);
      c[ci] = cn;
      aP = fmaf(hh, WattW[j], aP);
      if (WRITEH) hF[j][col] = hh;
    }
  }
  return aP;
}

__global__ __launch_bounds__(256,2) void k_lstm5(
    const float* __restrict__ h1, const float* __restrict__ h2, const float* __restrict__ h3,
    const u16* __restrict__ Wpf, const u16* __restrict__ Wpb,
    const float4* __restrict__ Bpf, const float4* __restrict__ Bpb,
    const float* __restrict__ Watt, const float* __restrict__ batt,
    float* __restrict__ aF, float* __restrict__ aB, int gL, int N)
{
  __shared__ u16 XH[5120];
  __shared__ u16 XL[5120];
  __shared__ float hF[96][32];
  __shared__ float sAl[4][3][32];
  const int tid = threadIdx.x;
  const int l = tid & 63;
  const int rtg = __builtin_amdgcn_readfirstlane(tid >> 6);
  const int dir = (blockIdx.x >= gL) ? 1 : 0;
  const int blk = blockIdx.x - dir*gL;
  const float* sA = dir ? h3 : h1;
  const float* sC = dir ? h1 : h3;
  const u16* Wp = dir ? Wpb : Wpf;
  const float4* Bp = dir ? Bpb : Bpf;
  const float* WattW = Watt + dir*96;
  float* aD = dir ? aB : aF;
  float c[12];
  float a0, a1, a2;
  float xv[8];

  // prologue: stage x0; pre-issue x1 loads
  ldx_regs(sA, blk, N, tid, xv);
  stage_from_regs(xv, XH, XL, tid);
  ldx_regs(h2, blk, N, tid, xv);
  __syncthreads();

  a0 = lstm_step5<1,1>(Wp, Bp, WattW, XH, XL, hF, c, rtg, l);
  __syncthreads();
  stage_from_regs(xv, XH, XL, tid);
  restage_h(hF, XH, XL, tid);
  ldx_regs(sC, blk, N, tid, xv);
  __syncthreads();

  a1 = lstm_step5<0,1>(Wp, Bp, WattW, XH, XL, hF, c, rtg, l);
  __syncthreads();
  stage_from_regs(xv, XH, XL, tid);
  restage_h(hF, XH, XL, tid);
  __syncthreads();

  a2 = lstm_step5<0,0>(Wp, Bp, WattW, XH, XL, hF, c, rtg, l);

  // alpha reduce: lanes l and l^32 hold complementary gate halves of same node
  a0 += __shfl_xor(a0, 32);
  a1 += __shfl_xor(a1, 32);
  a2 += __shfl_xor(a2, 32);
  if (l < 32){
    sAl[rtg][0][l] = a0;
    sAl[rtg][1][l] = a1;
    sAl[rtg][2][l] = a2;
  }
  __syncthreads();
  if (tid < 96){
    int s = tid >> 5;
    int node = tid & 31;
    int n = blk*32 + node;
    if (n < N){
      float sum = sAl[0][s][node] + sAl[1][s][node]
                + sAl[2][s][node] + sAl[3][s][node];
      int slice = dir ? (2 - s) : s;
      float v = dir ? sum : (batt[0] + sum);
      aD[(size_t)slice*N + n] = v;
    }
  }
}

// ---------------- JK softmax + xjk + Wlin + Wfc1 + leaky (16 nodes/block) ----------------
__global__ __launch_bounds__(256) void k_jk(const float* __restrict__ aF, const float* __restrict__ aB,
                                            const float* __restrict__ h1, const float* __restrict__ h2,
                                            const float* __restrict__ h3,
                                            const float* __restrict__ Wlin, const float* __restrict__ blin,
                                            const float* __restrict__ Wfc1, const float* __restrict__ bfc1,
                                            float* __restrict__ vout, int N){
  __shared__ float sWl[64*65];
  __shared__ float sX[4][64];
  int tid = threadIdx.x;
  for (int idx = tid; idx < 1024; idx += 256){
    int j = idx >> 4;
    int c4 = (idx & 15) << 2;
    float4 v = *(const float4*)(Wlin + (size_t)j*64 + c4);
    sWl[j*65 + c4+0] = v.x; sWl[j*65 + c4+1] = v.y;
    sWl[j*65 + c4+2] = v.z; sWl[j*65 + c4+3] = v.w;
  }
  __syncthreads();
  int ln = tid >> 6, j = tid & 63;
  float wf1 = Wfc1[j];
  float bl = blin[j];
  for (int ib = 0; ib < 4; ++ib){
    int n = blockIdx.x*16 + ib*4 + ln;
    bool ok = n < N;
    float xj = 0.f;
    if (ok){
      float a0 = aF[n] + aB[n];
      float a1 = aF[(size_t)N + n] + aB[(size_t)N + n];
      float a2 = aF[(size_t)2*N + n] + aB[(size_t)2*N + n];
      float m = fmaxf(a0, fmaxf(a1, a2));
      float e0 = __expf(a0-m), e1 = __expf(a1-m), e2 = __expf(a2-m);
      float inv = __builtin_amdgcn_rcpf(e0+e1+e2);
      float w0 = e0*inv, w1 = e1*inv, w2 = e2*inv;
      xj = w0*h1[(size_t)n*64 + j] + w1*h2[(size_t)n*64 + j] + w2*h3[(size_t)n*64 + j];
    }
    sX[ln][j] = xj;
    __syncthreads();
    float acc = bl;
    #pragma unroll 8
    for (int cc = 0; cc < 64; ++cc) acc = fmaf(sX[ln][cc], sWl[j*65 + cc], acc);
    float r = acc * wf1;
    #pragma unroll
    for (int off = 32; off > 0; off >>= 1) r += __shfl_down(r, off);
    if (j == 0 && ok){
      float vv = r + bfc1[0];
      vout[n] = vv >= 0.f ? vv : 0.01f*vv;
    }
    __syncthreads();
  }
}

// ---------------- final dot (deterministic two-stage, f64 accum) ----------------
__global__ __launch_bounds__(256) void k_final1(const float* __restrict__ w, const float* __restrict__ v,
                                                double* __restrict__ part, int N){
  __shared__ double sd[256];
  int tid = threadIdx.x;
  double a = 0.0;
  for (int i = blockIdx.x*256 + tid; i < N; i += 256*256)
    a += (double)(w[i] * v[i]);
  sd[tid] = a; __syncthreads();
  for (int off = 128; off > 0; off >>= 1){
    if (tid < off) sd[tid] += sd[tid + off];
    __syncthreads();
  }
  if (tid == 0) part[blockIdx.x] = sd[0];
}

__global__ __launch_bounds__(256) void k_final2(const double* __restrict__ part, const float* __restrict__ bfc2,
                                                float* __restrict__ out){
  __shared__ double sd[256];
  int tid = threadIdx.x;
  sd[tid] = part[tid]; __syncthreads();
  for (int off = 128; off > 0; off >>= 1){
    if (tid < off) sd[tid] += sd[tid + off];
    __syncthreads();
  }
  if (tid == 0) out[0] = (float)(sd[0] + (double)bfc2[0]);
}

// ---------------- host ----------------
extern "C" void kernel_launch(void* const* d_in, const int* in_sizes, int n_in,
                              void* d_out, int out_size, void* d_ws, size_t ws_size,
                              hipStream_t stream){
  const float* x    = (const float*)d_in[0];
  const int*   ei   = (const int*)d_in[1];
  const float* W0a  = (const float*)d_in[2];
  const float* b0a  = (const float*)d_in[3];
  const float* W0b  = (const float*)d_in[4];
  const float* b0b  = (const float*)d_in[5];
  const float* W1a  = (const float*)d_in[6];
  const float* b1a  = (const float*)d_in[7];
  const float* W1b  = (const float*)d_in[8];
  const float* b1b  = (const float*)d_in[9];
  const float* W2a  = (const float*)d_in[10];
  const float* b2a  = (const float*)d_in[11];
  const float* W2b  = (const float*)d_in[12];
  const float* b2b  = (const float*)d_in[13];
  const float* Wih_f = (const float*)d_in[14];
  const float* Whh_f = (const float*)d_in[15];
  const float* bih_f = (const float*)d_in[16];
  const float* bhh_f = (const float*)d_in[17];
  const float* Wih_b = (const float*)d_in[18];
  const float* Whh_b = (const float*)d_in[19];
  const float* bih_b = (const float*)d_in[20];
  const float* bhh_b = (const float*)d_in[21];
  const float* Watt = (const float*)d_in[22];
  const float* batt = (const float*)d_in[23];
  const float* Wlin = (const float*)d_in[24];
  const float* blin = (const float*)d_in[25];
  const float* Wfc1 = (const float*)d_in[26];
  const float* bfc1 = (const float*)d_in[27];
  const float* Wfc2 = (const float*)d_in[28];
  const float* bfc2 = (const float*)d_in[29];
  float* out = (float*)d_out;

  const int N = in_sizes[0] / 128;
  const int E = in_sizes[1] / 2;
  const int* src = ei;
  const int* dst = ei + E;

  uint8_t* w8 = (uint8_t*)d_ws;
  size_t off = 0;
  auto alloc = [&](size_t bytes) -> void* {
    void* p = w8 + off;
    off = (off + bytes + 255) & ~(size_t)255;
    return p;
  };
  int*    deg    = (int*)   alloc((size_t)N*4);
  int*    fill   = (int*)   alloc((size_t)N*4);
  int*    indptr = (int*)   alloc(((size_t)N+1)*4);
  int*    col    = (int*)   alloc((size_t)E*4);
  int*    bsum   = (int*)   alloc(2048);
  int*    boffs  = (int*)   alloc(2048);
  float*  h1     = (float*) alloc((size_t)N*64*4);
  float*  h2     = (float*) alloc((size_t)N*64*4);
  float*  h3     = (float*) alloc((size_t)N*64*4);
  float*  aF     = (float*) alloc((size_t)3*N*4);
  float*  aB     = (float*) alloc((size_t)3*N*4);
  float*  vbuf   = (float*) alloc((size_t)N*4);
  double* part   = (double*)alloc(256*8);
  u16*    Wpf    = (u16*)   alloc((size_t)10*12*64*8*2);
  u16*    Wpb    = (u16*)   alloc((size_t)10*12*64*8*2);
  float4* Bpf    = (float4*)alloc((size_t)96*16);
  float4* Bpb    = (float4*)alloc((size_t)96*16);
  float*  P      = (float*) alloc((size_t)N*192*4);
  if (off > ws_size) return;
  float* ybuf = P;
  float* zbuf = P + (size_t)N*64;

  const size_t lds64  = 64  * 102 * 4;
  const size_t lds128 = 128 * 102 * 4;

  hipMemsetAsync(deg,  0, (size_t)N*4, stream);
  hipMemsetAsync(fill, 0, (size_t)N*4, stream);

  int gE = (E + 255) / 256;
  int nb1 = (N + 255) / 256;
  int gG = (N + 63) / 64;
  int gA = (N + 15) / 16;
  int gL = (N + 31) / 32;

  // weight prepack (independent of CSR)
  k_packW1<<<240, 256, 0, stream>>>(Wih_f, Whh_f, Wpf);
  k_packW1<<<240, 256, 0, stream>>>(Wih_b, Whh_b, Wpb);
  k_packB<<<1, 128, 0, stream>>>(bih_f, bhh_f, Bpf);
  k_packB<<<1, 128, 0, stream>>>(bih_b, bhh_b, Bpb);

  k_deg  <<<gE, 256, 0, stream>>>(dst, deg, E);
  k_scan1<<<nb1, 256, 0, stream>>>(deg, indptr, bsum, N);
  k_scan2<<<1, 512, 0, stream>>>(bsum, boffs, indptr, nb1, N);
  k_scan3<<<nb1, 256, 0, stream>>>(indptr, boffs, N);
  k_fill <<<gE, 256, 0, stream>>>(src, dst, indptr, fill, col, E);

  // ---- GIN layer 0 (transform-first: (x+aggX)@W = y+aggY) ----
  k_gemm<<<gG, TPB, lds128, stream>>>(x, W0a, nullptr, ybuf, 128, 64, 0, N);
  k_agg<64><<<gA, 256, 0, stream>>>(ybuf, indptr, col, b0a, zbuf, N);
  k_gemm<<<gG, TPB, lds64, stream>>>(zbuf, W0b, b0b, h1, 64, 64, 1, N);
  // ---- GIN layer 1 ----
  k_gemm<<<gG, TPB, lds64, stream>>>(h1, W1a, nullptr, ybuf, 64, 64, 0, N);
  k_agg<64><<<gA, 256, 0, stream>>>(ybuf, indptr, col, b1a, zbuf, N);
  k_gemm<<<gG, TPB, lds64, stream>>>(zbuf, W1b, b1b, h2, 64, 64, 1, N);
  // ---- GIN layer 2 ----
  k_gemm<<<gG, TPB, lds64, stream>>>(h2, W2a, nullptr, ybuf, 64, 64, 0, N);
  k_agg<64><<<gA, 256, 0, stream>>>(ybuf, indptr, col, b2a, zbuf, N);
  k_gemm<<<gG, TPB, lds64, stream>>>(zbuf, W2b, b2b, h3, 64, 64, 1, N);

  // ---- LSTM: both directions in one dispatch ----
  k_lstm5<<<2*gL, 256, 0, stream>>>(h1, h2, h3, Wpf, Wpb, Bpf, Bpb, Watt, batt,
                                    aF, aB, gL, N);

  // ---- JK attention + linear + fc1 + leaky ----
  k_jk<<<(N+15)/16, 256, 0, stream>>>(aF, aB, h1, h2, h3, Wlin, blin, Wfc1, bfc1, vbuf, N);

  // ---- final dot ----
  k_final1<<<256, 256, 0, stream>>>(Wfc2, vbuf, part, N);
  k_final2<<<1, 256, 0, stream>>>(part, bfc2, out);
}